// Round 3
// baseline (537.680 us; speedup 1.0000x reference)
//
#include <hip/hip_runtime.h>
#include <hip/hip_bf16.h>
#include <math.h>

// Problem constants
#define N_NODES 30
#define E_BASE  82
#define E_TOT   112         // 82 edges + 30 self loops
#define B_GRAPH 1024
#define HID     256
#define NTOT    (B_GRAPH * N_NODES)   // 30720
#define MAXIN   32
#define N_EH    41
#define M_MLP   (B_GRAPH * N_EH)      // 41984

#define META_SRC  0
#define META_DST  E_TOT
#define META_CNT  (2 * E_TOT)
#define META_LIST 256
#define META_INTS 1216

typedef __attribute__((ext_vector_type(8))) short bf16x8;
typedef __attribute__((ext_vector_type(4))) short bf16x4;
typedef __attribute__((ext_vector_type(4))) float f32x4;
#define AS3 __attribute__((address_space(3)))
#define AS1 __attribute__((address_space(1)))

__device__ __forceinline__ void gload_lds16(const void* g, void* l) {
  __builtin_amdgcn_global_load_lds((const AS1 void*)g, (AS3 void*)l, 16, 0, 0);
}

// Bit-reinterpret ONLY — callers must pass raw bf16 bit patterns (short lanes
// of bf16x4/8 vectors). Never pass __hip_bfloat16 (would value-convert via
// float->short — the R3 NaN bug).
__device__ __forceinline__ float b2f(short s) {
  union { unsigned u; float f; } x;
  x.u = ((unsigned)(unsigned short)s) << 16;
  return x.f;
}

// ---------------------------------------------------------------------------
// Transpose-cast all weights fp32 [K,N] -> bf16 [N,K]; block 976 instead
// builds the base-graph CSR (merged to save a launch).
// ---------------------------------------------------------------------------
struct WtJob { const float* in; int K, N, tstart, ooff; };
struct WtArgs { WtJob j[10]; };

__global__ __launch_bounds__(256)
void transpose_weights(WtArgs args, __hip_bfloat16* __restrict__ out,
                       const int* __restrict__ ei, int* __restrict__ meta) {
  int b = blockIdx.x;
  if (b == 976) {   // build_graph job
    __shared__ int cnt[N_NODES];
    int tid = threadIdx.x;
    if (tid < N_NODES) cnt[tid] = 0;
    __syncthreads();
    if (tid < E_TOT) {
      int s, d;
      if (tid < E_BASE) { s = ei[tid]; d = ei[B_GRAPH * E_BASE + tid]; }
      else              { s = tid - E_BASE; d = s; }
      meta[META_SRC + tid] = s;
      meta[META_DST + tid] = d;
      int pos = atomicAdd(&cnt[d], 1);
      if (pos < MAXIN) meta[META_LIST + d * MAXIN + pos] = tid;
    }
    __syncthreads();
    if (tid < N_NODES) meta[META_CNT + tid] = cnt[tid];
    return;
  }
  int ji = 0;
  #pragma unroll
  for (int i = 1; i < 10; i++) if (b >= args.j[i].tstart) ji = i;
  WtJob jb = args.j[ji];
  int t = b - jb.tstart;
  int ntn = jb.N >> 5;
  int tk = t / ntn, tn = t - tk * ntn;
  int k0 = tk * 32, n0 = tn * 32;
  __shared__ float s[32][33];
  int tx = threadIdx.x & 31, ty = threadIdx.x >> 5;
  #pragma unroll
  for (int p = 0; p < 4; p++)
    s[ty + p * 8][tx] = jb.in[(size_t)(k0 + ty + p * 8) * jb.N + n0 + tx];
  __syncthreads();
  __hip_bfloat16* o = out + jb.ooff;
  #pragma unroll
  for (int p = 0; p < 4; p++) {
    int n = ty + p * 8;
    o[(size_t)(n0 + n) * jb.K + k0 + tx] = __float2bfloat16(s[tx][n]);
  }
}

// ---------------------------------------------------------------------------
// R15: FUSED per-graph GATv2 layer — GEMM(xl,xr) + alpha + agg in ONE kernel.
// Eliminates the xcat HBM round-trip entirely (was ~380 MB across 3 layers at
// an observed 2.6 TB/s effective = ~145 µs; R1/R2 falsified all attempts to
// make that stream faster — so remove it).
//
// One block per graph. Phases per head (6 barriers):
//   GEMM: xl_h = hn_g @ Wl_h^T + bl_h ; xr_h likewise. A (hn_g) staged once in
//         K-subtiled LDS [kk][32][32] (pre-swizzled global source keeps
//         global_load_lds dest linear, per m173; [30][256] linear layout would
//         be a 16-way bank conflict on MFMA A-frag ds_read_b128, per G4).
//         B fragments streamed per-lane from global — identical addresses for
//         all 1024 blocks -> L2-resident broadcast (Wl+Wr <= 1.5 MB).
//   alpha: proven gat_alpha body on LDS xl/xr (logits, segment max, exp,
//          atomicAdd denom, normalize) -> salpha in LDS.
//   agg:  proven gat_agg accumulation from LDS.
// Epilogue: mean over heads + bias + lrelu + residual (+ fused next-layer LN).
// Numerics identical to the unfused path: same bf16 rounding points (xl/xr
// rounded to bf16 before alpha/agg), same K-accumulation order, same softmax.
// ---------------------------------------------------------------------------
template<int DO_LN>
__global__ __launch_bounds__(256)
void gat_fused(const __hip_bfloat16* hnb_io,             // [NTOT][256] in (and out if DO_LN)
               const __hip_bfloat16* __restrict__ Wl,    // [H*256][256] bf16 (transposed)
               const __hip_bfloat16* __restrict__ Wr,
               const float* __restrict__ blv, const float* __restrict__ brv,
               const float* __restrict__ att, const float* __restrict__ bias,
               float* __restrict__ h,
               const float* __restrict__ lnG, const float* __restrict__ lnB,
               const int* __restrict__ meta, int H)
{
  __shared__ __hip_bfloat16 sHn[8 * 32 * 32];     // 16 KB, [kk][row][32] K-subtiled
  __shared__ __hip_bfloat16 sxl[N_NODES * HID];   // 15 KB
  __shared__ __hip_bfloat16 sxr[N_NODES * HID];   // 15 KB
  __shared__ float slog[E_TOT], salpha[E_TOT], smax[N_NODES], sden[N_NODES];
  __shared__ int ssrc[E_TOT], sdst[E_TOT], scnt[N_NODES], slist[N_NODES * MAXIN];

  const int tid = threadIdx.x;
  const int g = blockIdx.x;
  const size_t nodebase = (size_t)g * N_NODES;
  const int lane = tid & 63, wave = tid >> 6;
  const int mrow = lane & 15, quad = lane >> 4;
  const int n0 = wave * 64;                        // per-wave 64-col slice of head
  const int c4 = tid & 63, ng = tid >> 6;

  // ---- stage hn_g into K-subtiled LDS (pre-swizzled global source) ----
  {
    const __hip_bfloat16* src = hnb_io + nodebase * HID;
    #pragma unroll
    for (int p = 0; p < 4; p++) {
      int L = tid + p * 256;              // linear 16B-chunk index into sHn
      int kk = L >> 7, rem = L & 127;
      int row = rem >> 2, c16 = rem & 3;
      if (row >= N_NODES) row = 0;        // pad rows 30,31: duplicate row 0;
                                          // their MFMA outputs are never read
      gload_lds16(src + (size_t)(row * 32 + kk * 4 + c16) * 8, &sHn[(size_t)L * 8]);
    }
  }
  if (tid < E_TOT) { ssrc[tid] = meta[META_SRC + tid]; sdst[tid] = meta[META_DST + tid]; }
  if (tid < N_NODES) scnt[tid] = meta[META_CNT + tid];
  for (int i = tid; i < N_NODES * MAXIN; i += 256) slist[i] = meta[META_LIST + i];
  __syncthreads();

  float agg[8][4];
  #pragma unroll
  for (int ki = 0; ki < 8; ki++)
    #pragma unroll
    for (int j = 0; j < 4; j++) agg[ki][j] = 0.f;

  for (int hh = 0; hh < H; hh++) {
    // -------- GEMM phase: xl (mat 0) then xr (mat 1), 32 acc VGPR reused ----
    for (int mat = 0; mat < 2; mat++) {
      const __hip_bfloat16* W = (mat ? Wr : Wl) + ((size_t)hh * HID) * HID;
      const float* bb = mat ? brv : blv;
      __hip_bfloat16* sx = mat ? sxr : sxl;

      f32x4 acc[2][4];
      #pragma unroll
      for (int mi = 0; mi < 2; mi++)
        #pragma unroll
        for (int nj = 0; nj < 4; nj++) acc[mi][nj] = (f32x4){0.f, 0.f, 0.f, 0.f};

      #pragma unroll
      for (int kk = 0; kk < 8; kk++) {
        bf16x8 a0 = *(const bf16x8*)&sHn[kk * 1024 + mrow * 32 + quad * 8];
        bf16x8 a1 = *(const bf16x8*)&sHn[kk * 1024 + (16 + mrow) * 32 + quad * 8];
        bf16x8 bf[4];
        #pragma unroll
        for (int nj = 0; nj < 4; nj++)
          bf[nj] = *(const bf16x8*)&W[(size_t)(n0 + nj * 16 + mrow) * HID + kk * 32 + quad * 8];
        #pragma unroll
        for (int nj = 0; nj < 4; nj++) {
          acc[0][nj] = __builtin_amdgcn_mfma_f32_16x16x32_bf16(a0, bf[nj], acc[0][nj], 0, 0, 0);
          acc[1][nj] = __builtin_amdgcn_mfma_f32_16x16x32_bf16(a1, bf[nj], acc[1][nj], 0, 0, 0);
        }
      }

      // barrier (A): previous head's agg/alpha reads of sxl/sxr must complete
      // before this head's epilogue overwrites them (only needed once).
      if (mat == 0) __syncthreads();

      float bv[4];
      #pragma unroll
      for (int nj = 0; nj < 4; nj++) bv[nj] = bb[hh * HID + n0 + nj * 16 + mrow];
      #pragma unroll
      for (int mi = 0; mi < 2; mi++) {
        #pragma unroll
        for (int r = 0; r < 4; r++) {
          int row = mi * 16 + quad * 4 + r;
          if (row < N_NODES) {
            #pragma unroll
            for (int nj = 0; nj < 4; nj++)
              sx[row * HID + n0 + nj * 16 + mrow] = __float2bfloat16(acc[mi][nj][r] + bv[nj]);
          }
        }
      }
    }
    __syncthreads();   // (B) xl/xr ready

    // -------- alpha phase (proven gat_alpha body, LDS-local) --------
    {
      const int l32 = tid & 31, esub = (tid >> 5) & 1;
      const int c0 = l32 * 8;
      float attr[8];
      #pragma unroll
      for (int j = 0; j < 8; j++) attr[j] = att[hh * HID + c0 + j];
      if (tid < N_NODES) sden[tid] = 0.f;
      #pragma unroll
      for (int pass = 0; pass < 14; pass++) {
        int e = pass * 8 + wave * 2 + esub;
        bf16x8 a = *(const bf16x8*)&sxl[ssrc[e] * HID + c0];
        bf16x8 b = *(const bf16x8*)&sxr[sdst[e] * HID + c0];
        float sum = 0.f;
        #pragma unroll
        for (int j = 0; j < 8; j++) {
          float v = b2f(a[j]) + b2f(b[j]);
          v = v > 0.f ? v : 0.2f * v;
          sum += v * attr[j];
        }
        #pragma unroll
        for (int off = 16; off; off >>= 1) sum += __shfl_xor(sum, off);
        if (l32 == 0) slog[e] = sum;
      }
    }
    __syncthreads();   // (C) logits + sden zero done

    if (tid < N_NODES) {
      int cnt = scnt[tid];
      const int* lst = &slist[tid * MAXIN];
      float m = -1e30f;
      for (int i = 0; i < cnt; i++) m = fmaxf(m, slog[lst[i]]);
      smax[tid] = m;
    }
    __syncthreads();   // (D)
    if (tid < E_TOT) {
      float ex = expf(slog[tid] - smax[sdst[tid]]);
      slog[tid] = ex;
      atomicAdd(&sden[sdst[tid]], ex);
    }
    __syncthreads();   // (E)
    if (tid < E_TOT) salpha[tid] = slog[tid] / sden[sdst[tid]];
    __syncthreads();   // (F) alpha ready

    // -------- agg phase (proven gat_agg body, LDS-local) --------
    #pragma unroll
    for (int ki = 0; ki < 8; ki++) {
      int k = ng + ki * 4;
      if (k < N_NODES) {
        int cnt = scnt[k];
        const int* lst = &slist[k * MAXIN];
        for (int i = 0; i < cnt; i++) {
          int e = lst[i];                       // wave-uniform broadcast reads
          float al = salpha[e];
          bf16x4 v = *(const bf16x4*)&sxl[ssrc[e] * HID + c4 * 4];
          agg[ki][0] += al * b2f(v[0]);
          agg[ki][1] += al * b2f(v[1]);
          agg[ki][2] += al * b2f(v[2]);
          agg[ki][3] += al * b2f(v[3]);
        }
      }
    }
    // next head's barrier (A) protects sxl/sxr; no trailing barrier needed
  }

  // -------- finalize: mean/bias/lrelu + residual (+ fused LN) --------
  float4 hres[8];
  #pragma unroll
  for (int ki = 0; ki < 8; ki++) {
    int k = ng + ki * 4;
    if (k < N_NODES) hres[ki] = *(const float4*)&h[(nodebase + k) * HID + c4 * 4];
  }
  const float invH = 1.f / (float)H;
  const float4 bs = *(const float4*)&bias[c4 * 4];
  float4 gv, bv;
  if (DO_LN) {
    gv = *(const float4*)&lnG[c4 * 4];
    bv = *(const float4*)&lnB[c4 * 4];
  }
  __hip_bfloat16* hn_out = (__hip_bfloat16*)hnb_io;   // safe: own slice was read at start
  #pragma unroll
  for (int ki = 0; ki < 8; ki++) {
    int k = ng + ki * 4;
    if (k < N_NODES) {
      float o0 = agg[ki][0] * invH + bs.x; o0 = o0 > 0.f ? o0 : 0.01f * o0; o0 += hres[ki].x;
      float o1 = agg[ki][1] * invH + bs.y; o1 = o1 > 0.f ? o1 : 0.01f * o1; o1 += hres[ki].y;
      float o2 = agg[ki][2] * invH + bs.z; o2 = o2 > 0.f ? o2 : 0.01f * o2; o2 += hres[ki].z;
      float o3 = agg[ki][3] * invH + bs.w; o3 = o3 > 0.f ? o3 : 0.01f * o3; o3 += hres[ki].w;
      float4 o4 = {o0, o1, o2, o3};
      *(float4*)&h[(nodebase + k) * HID + c4 * 4] = o4;
      if (DO_LN) {
        float sum = o0 + o1 + o2 + o3;
        #pragma unroll
        for (int off = 32; off; off >>= 1) sum += __shfl_xor(sum, off);
        float mu = sum * (1.f / 256.f);
        float d0 = o0 - mu, d1 = o1 - mu, d2 = o2 - mu, d3 = o3 - mu;
        float vs = d0 * d0 + d1 * d1 + d2 * d2 + d3 * d3;
        #pragma unroll
        for (int off = 32; off; off >>= 1) vs += __shfl_xor(vs, off);
        float rs = rsqrtf(vs * (1.f / 256.f) + 1e-5f);
        __hip_bfloat16 t[4];
        t[0] = __float2bfloat16(d0 * rs * gv.x + bv.x);
        t[1] = __float2bfloat16(d1 * rs * gv.y + bv.y);
        t[2] = __float2bfloat16(d2 * rs * gv.z + bv.z);
        t[3] = __float2bfloat16(d3 * rs * gv.w + bv.w);
        *(bf16x4*)&hn_out[(nodebase + k) * HID + c4 * 4] = *(bf16x4*)t;
      }
    }
  }
}

// ---------------------------------------------------------------------------
// MFMA GEMM with fp32 A staged via in-register bf16 cast (fused cast): proj.
// (R0 version — row-major C output.)
// ---------------------------------------------------------------------------
template<int ACT, int OUTBF>
__global__ __launch_bounds__(256)
void gemm_mfma_f32a(const float* __restrict__ A, const __hip_bfloat16* __restrict__ Bt,
                    const float* __restrict__ bias, void* __restrict__ Cv,
                    int M, int K, int N)
{
  __shared__ __hip_bfloat16 sA[128 * 32];
  __shared__ __hip_bfloat16 sB[128 * 32];
  const int tid = threadIdx.x;
  const int lane = tid & 63;
  const int wave = tid >> 6;
  const int wx = wave & 1, wy = wave >> 1;
  const int bm = blockIdx.x, bn = blockIdx.y;
  const int mrow = lane & 15, quad = lane >> 4;

  const int r0 = tid >> 2, kc0 = (tid & 3) * 8;
  const float* Ag0 = A + (size_t)(bm * 128 + r0) * K + kc0;
  const float* Ag1 = A + (size_t)(bm * 128 + r0 + 64) * K + kc0;
  const __hip_bfloat16* Bg0 = Bt + (size_t)(bn * 128 + r0) * K + kc0;
  const __hip_bfloat16* Bg1 = Bt + (size_t)(bn * 128 + r0 + 64) * K + kc0;

  f32x4 acc[4][4];
  #pragma unroll
  for (int i = 0; i < 4; i++)
    #pragma unroll
    for (int j = 0; j < 4; j++)
      acc[i][j] = (f32x4){0.f, 0.f, 0.f, 0.f};

  for (int kt = 0; kt < K; kt += 32) {
    float4 a00 = *(const float4*)(Ag0 + kt);
    float4 a01 = *(const float4*)(Ag0 + kt + 4);
    float4 a10 = *(const float4*)(Ag1 + kt);
    float4 a11 = *(const float4*)(Ag1 + kt + 4);
    __syncthreads();
    {
      __hip_bfloat16 t[8];
      t[0] = __float2bfloat16(a00.x); t[1] = __float2bfloat16(a00.y);
      t[2] = __float2bfloat16(a00.z); t[3] = __float2bfloat16(a00.w);
      t[4] = __float2bfloat16(a01.x); t[5] = __float2bfloat16(a01.y);
      t[6] = __float2bfloat16(a01.z); t[7] = __float2bfloat16(a01.w);
      *(bf16x8*)&sA[tid * 8] = *(bf16x8*)t;
      t[0] = __float2bfloat16(a10.x); t[1] = __float2bfloat16(a10.y);
      t[2] = __float2bfloat16(a10.z); t[3] = __float2bfloat16(a10.w);
      t[4] = __float2bfloat16(a11.x); t[5] = __float2bfloat16(a11.y);
      t[6] = __float2bfloat16(a11.z); t[7] = __float2bfloat16(a11.w);
      *(bf16x8*)&sA[2048 + tid * 8] = *(bf16x8*)t;
    }
    gload_lds16(Bg0 + kt, &sB[tid * 8]);
    gload_lds16(Bg1 + kt, &sB[2048 + tid * 8]);
    __syncthreads();

    bf16x8 af[4], bfr[4];
    #pragma unroll
    for (int i = 0; i < 4; i++) {
      af[i]  = *(const bf16x8*)&sA[(wy * 64 + i * 16 + mrow) * 32 + quad * 8];
      bfr[i] = *(const bf16x8*)&sB[(wx * 64 + i * 16 + mrow) * 32 + quad * 8];
    }
    #pragma unroll
    for (int i = 0; i < 4; i++)
      #pragma unroll
      for (int j = 0; j < 4; j++)
        acc[i][j] = __builtin_amdgcn_mfma_f32_16x16x32_bf16(af[i], bfr[j], acc[i][j], 0, 0, 0);
  }

  #pragma unroll
  for (int i = 0; i < 4; i++) {
    #pragma unroll
    for (int r = 0; r < 4; r++) {
      size_t row = (size_t)bm * 128 + wy * 64 + i * 16 + quad * 4 + r;
      #pragma unroll
      for (int j = 0; j < 4; j++) {
        int col = bn * 128 + wx * 64 + j * 16 + mrow;
        float v = acc[i][j][r] + bias[col];
        if (ACT) v = v > 0.f ? v : 0.01f * v;
        if (OUTBF) ((__hip_bfloat16*)Cv)[row * N + col] = __float2bfloat16(v);
        else       ((float*)Cv)[row * N + col] = v;
      }
    }
  }
}

// ---------------------------------------------------------------------------
// MFMA GEMM with fused edge-pair gather from fp32 h:
// A-row r = concat(h[b,u], h[b,v]) with b=r/41, (u,v)=pairs[r%41]; K=512.
// C = lrelu(A @ Bt + bias), bf16 out. (R0 version.)
// ---------------------------------------------------------------------------
__global__ __launch_bounds__(256)
void gemm_mfma_pair(const float* __restrict__ h, const int* __restrict__ pairs,
                    const __hip_bfloat16* __restrict__ Bt, const float* __restrict__ bias,
                    __hip_bfloat16* __restrict__ C, int N)
{
  const int K = 512;
  __shared__ __hip_bfloat16 sA[128 * 32];
  __shared__ __hip_bfloat16 sB[128 * 32];
  const int tid = threadIdx.x;
  const int lane = tid & 63;
  const int wave = tid >> 6;
  const int wx = wave & 1, wy = wave >> 1;
  const int bm = blockIdx.x, bn = blockIdx.y;
  const int mrow = lane & 15, quad = lane >> 4;

  const float* pu[2]; const float* pv[2]; int sub[2];
  #pragma unroll
  for (int cI = 0; cI < 2; cI++) {
    int c = tid + cI * 256;
    int r0 = c >> 2; sub[cI] = (c & 3) * 8;
    int R = bm * 128 + r0;
    int b = R / N_EH, p = R - b * N_EH;
    int u = pairs[p * 2], v = pairs[p * 2 + 1];
    pu[cI] = h + ((size_t)b * N_NODES + u) * HID;
    pv[cI] = h + ((size_t)b * N_NODES + v) * HID;
  }

  const int r0 = tid >> 2, kc0 = (tid & 3) * 8;
  const __hip_bfloat16* Bg0 = Bt + (size_t)(bn * 128 + r0) * K + kc0;
  const __hip_bfloat16* Bg1 = Bt + (size_t)(bn * 128 + r0 + 64) * K + kc0;

  f32x4 acc[4][4];
  #pragma unroll
  for (int i = 0; i < 4; i++)
    #pragma unroll
    for (int j = 0; j < 4; j++)
      acc[i][j] = (f32x4){0.f, 0.f, 0.f, 0.f};

  for (int kt = 0; kt < K; kt += 32) {
    float4 av[2][2];
    #pragma unroll
    for (int cI = 0; cI < 2; cI++) {
      const float* src = (kt < 256 ? pu[cI] + kt : pv[cI] + kt - 256) + sub[cI];
      av[cI][0] = *(const float4*)src;
      av[cI][1] = *(const float4*)(src + 4);
    }
    __syncthreads();
    #pragma unroll
    for (int cI = 0; cI < 2; cI++) {
      __hip_bfloat16 t[8];
      t[0] = __float2bfloat16(av[cI][0].x); t[1] = __float2bfloat16(av[cI][0].y);
      t[2] = __float2bfloat16(av[cI][0].z); t[3] = __float2bfloat16(av[cI][0].w);
      t[4] = __float2bfloat16(av[cI][1].x); t[5] = __float2bfloat16(av[cI][1].y);
      t[6] = __float2bfloat16(av[cI][1].z); t[7] = __float2bfloat16(av[cI][1].w);
      *(bf16x8*)&sA[(tid + cI * 256) * 8] = *(bf16x8*)t;
    }
    gload_lds16(Bg0 + kt, &sB[tid * 8]);
    gload_lds16(Bg1 + kt, &sB[2048 + tid * 8]);
    __syncthreads();

    bf16x8 af[4], bfr[4];
    #pragma unroll
    for (int i = 0; i < 4; i++) {
      af[i]  = *(const bf16x8*)&sA[(wy * 64 + i * 16 + mrow) * 32 + quad * 8];
      bfr[i] = *(const bf16x8*)&sB[(wx * 64 + i * 16 + mrow) * 32 + quad * 8];
    }
    #pragma unroll
    for (int i = 0; i < 4; i++)
      #pragma unroll
      for (int j = 0; j < 4; j++)
        acc[i][j] = __builtin_amdgcn_mfma_f32_16x16x32_bf16(af[i], bfr[j], acc[i][j], 0, 0, 0);
  }

  #pragma unroll
  for (int i = 0; i < 4; i++) {
    #pragma unroll
    for (int r = 0; r < 4; r++) {
      size_t row = (size_t)bm * 128 + wy * 64 + i * 16 + quad * 4 + r;
      #pragma unroll
      for (int j = 0; j < 4; j++) {
        int col = bn * 128 + wx * 64 + j * 16 + mrow;
        float v = acc[i][j][r] + bias[col];
        v = v > 0.f ? v : 0.01f * v;
        C[row * N + col] = __float2bfloat16(v);
      }
    }
  }
}

// ---------------------------------------------------------------------------
// Fused MLP tail (R11 — proven win; R0 version).
// ---------------------------------------------------------------------------
#define O2P 136
__global__ __launch_bounds__(256)
void mlp_tail(const __hip_bfloat16* __restrict__ o1, const __hip_bfloat16* __restrict__ W1t,
              const float* __restrict__ b1, const __hip_bfloat16* __restrict__ W2t,
              const float* __restrict__ b2, const float* __restrict__ w3,
              const float* __restrict__ b3, float* __restrict__ out)
{
  __shared__ __hip_bfloat16 sA[128 * 32];
  __shared__ __hip_bfloat16 sB[128 * 32];
  __shared__ __hip_bfloat16 sO2[128 * O2P];
  __shared__ float spart[2][128];
  const int tid = threadIdx.x;
  const int lane = tid & 63;
  const int wave = tid >> 6;
  const int wx = wave & 1, wy = wave >> 1;
  const int bm = blockIdx.x;
  const int mrow = lane & 15, quad = lane >> 4;
  const int r0 = tid >> 2, kc0 = (tid & 3) * 8;

  const __hip_bfloat16* Ag0 = o1 + (size_t)(bm * 128 + r0) * 256 + kc0;
  const __hip_bfloat16* Ag1 = o1 + (size_t)(bm * 128 + r0 + 64) * 256 + kc0;
  const __hip_bfloat16* Bg0 = W1t + (size_t)r0 * 256 + kc0;
  const __hip_bfloat16* Bg1 = W1t + (size_t)(r0 + 64) * 256 + kc0;

  f32x4 acc[4][4];
  #pragma unroll
  for (int i = 0; i < 4; i++)
    #pragma unroll
    for (int j = 0; j < 4; j++)
      acc[i][j] = (f32x4){0.f, 0.f, 0.f, 0.f};

  for (int kt = 0; kt < 256; kt += 32) {
    __syncthreads();
    gload_lds16(Ag0 + kt, &sA[tid * 8]);
    gload_lds16(Ag1 + kt, &sA[2048 + tid * 8]);
    gload_lds16(Bg0 + kt, &sB[tid * 8]);
    gload_lds16(Bg1 + kt, &sB[2048 + tid * 8]);
    __syncthreads();

    bf16x8 af[4], bfr[4];
    #pragma unroll
    for (int i = 0; i < 4; i++) {
      af[i]  = *(const bf16x8*)&sA[(wy * 64 + i * 16 + mrow) * 32 + quad * 8];
      bfr[i] = *(const bf16x8*)&sB[(wx * 64 + i * 16 + mrow) * 32 + quad * 8];
    }
    #pragma unroll
    for (int i = 0; i < 4; i++)
      #pragma unroll
      for (int j = 0; j < 4; j++)
        acc[i][j] = __builtin_amdgcn_mfma_f32_16x16x32_bf16(af[i], bfr[j], acc[i][j], 0, 0, 0);
  }

  __syncthreads();
  #pragma unroll
  for (int i = 0; i < 4; i++) {
    #pragma unroll
    for (int r = 0; r < 4; r++) {
      int row = wy * 64 + i * 16 + quad * 4 + r;
      #pragma unroll
      for (int j = 0; j < 4; j++) {
        int col = wx * 64 + j * 16 + mrow;
        float v = acc[i][j][r] + b1[col];
        v = v > 0.f ? v : 0.01f * v;
        sO2[row * O2P + col] = __float2bfloat16(v);
      }
    }
  }

  f32x4 acc2[4][4];
  #pragma unroll
  for (int i = 0; i < 4; i++)
    #pragma unroll
    for (int j = 0; j < 4; j++)
      acc2[i][j] = (f32x4){0.f, 0.f, 0.f, 0.f};

  for (int kt = 0; kt < 128; kt += 32) {
    __syncthreads();
    gload_lds16(W2t + (size_t)r0 * 128 + kt + kc0, &sB[tid * 8]);
    gload_lds16(W2t + (size_t)(r0 + 64) * 128 + kt + kc0, &sB[2048 + tid * 8]);
    __syncthreads();

    bf16x8 af[4], bfr[4];
    #pragma unroll
    for (int i = 0; i < 4; i++) {
      af[i]  = *(const bf16x8*)&sO2[(wy * 64 + i * 16 + mrow) * O2P + kt + quad * 8];
      bfr[i] = *(const bf16x8*)&sB[(wx * 64 + i * 16 + mrow) * 32 + quad * 8];
    }
    #pragma unroll
    for (int i = 0; i < 4; i++)
      #pragma unroll
      for (int j = 0; j < 4; j++)
        acc2[i][j] = __builtin_amdgcn_mfma_f32_16x16x32_bf16(af[i], bfr[j], acc2[i][j], 0, 0, 0);
  }

  float w3v[4], b2v[4];
  #pragma unroll
  for (int j = 0; j < 4; j++) {
    int col = wx * 64 + j * 16 + mrow;
    w3v[j] = w3[col];
    b2v[j] = b2[col];
  }
  #pragma unroll
  for (int i = 0; i < 4; i++) {
    #pragma unroll
    for (int r = 0; r < 4; r++) {
      float s = 0.f;
      #pragma unroll
      for (int j = 0; j < 4; j++) {
        float v = acc2[i][j][r] + b2v[j];
        v = v > 0.f ? v : 0.01f * v;
        s += v * w3v[j];
      }
      #pragma unroll
      for (int off = 8; off; off >>= 1) s += __shfl_xor(s, off);
      if (mrow == 0) {
        int row = wy * 64 + i * 16 + quad * 4 + r;
        spart[wx][row] = s;
      }
    }
  }
  __syncthreads();
  if (tid < 128)
    out[(size_t)bm * 128 + tid] = spart[0][tid] + spart[1][tid] + b3[0];
}

// ---------------------------------------------------------------------------
// LayerNorm over HID=256; one wave per row; writes bf16. (Used once, after proj.)
// ---------------------------------------------------------------------------
__global__ __launch_bounds__(256)
void layernorm(const float* __restrict__ h, const float* __restrict__ g,
               const float* __restrict__ b, __hip_bfloat16* __restrict__ hn)
{
  const int wv = threadIdx.x >> 6, lane = threadIdx.x & 63;
  const size_t row = (size_t)blockIdx.x * 4 + wv;
  const float* hr = h + row * HID;
  float v[4];
  float sum = 0.f;
  #pragma unroll
  for (int j = 0; j < 4; j++) { v[j] = hr[lane + 64 * j]; sum += v[j]; }
  #pragma unroll
  for (int off = 32; off; off >>= 1) sum += __shfl_xor(sum, off);
  float mu = sum * (1.f / 256.f);
  float vs = 0.f;
  #pragma unroll
  for (int j = 0; j < 4; j++) { float d = v[j] - mu; vs += d * d; }
  #pragma unroll
  for (int off = 32; off; off >>= 1) vs += __shfl_xor(vs, off);
  float rs = rsqrtf(vs * (1.f / 256.f) + 1e-5f);
  __hip_bfloat16* outr = hn + row * HID;
  #pragma unroll
  for (int j = 0; j < 4; j++) {
    int c = lane + 64 * j;
    outr[c] = __float2bfloat16((v[j] - mu) * rs * g[c] + b[c]);
  }
}

// ---------------------------------------------------------------------------
extern "C" void kernel_launch(void* const* d_in, const int* in_sizes, int n_in,
                              void* d_out, int out_size, void* d_ws, size_t ws_size,
                              hipStream_t stream) {
  const float* x     = (const float*)d_in[0];
  const int*   ei    = (const int*)d_in[1];
  const int*   pairs = (const int*)d_in[2];
  const float* bp    = (const float*)d_in[4];
  const float *lng[3], *lnb[3], *bl[3], *br[3], *att[3], *bias[3];
  const float *WlF[3], *WrF[3];
  for (int l = 0; l < 3; l++) {
    int base = 5 + l * 8;
    lng[l]  = (const float*)d_in[base + 0];
    lnb[l]  = (const float*)d_in[base + 1];
    WlF[l]  = (const float*)d_in[base + 2];
    bl[l]   = (const float*)d_in[base + 3];
    WrF[l]  = (const float*)d_in[base + 4];
    br[l]   = (const float*)d_in[base + 5];
    att[l]  = (const float*)d_in[base + 6];
    bias[l] = (const float*)d_in[base + 7];
  }
  const float* WmF[4] = {(const float*)d_in[29], (const float*)d_in[31],
                         (const float*)d_in[33], (const float*)d_in[35]};
  const float* bm[4] = {(const float*)d_in[30], (const float*)d_in[32],
                        (const float*)d_in[34], (const float*)d_in[36]};

  // workspace layout (float offsets)
  float* ws  = (float*)d_ws;
  float* h   = ws;                                           // [0, 7864320)
  __hip_bfloat16* hnb = (__hip_bfloat16*)(ws + 7864320);     // 3,932,160 bf
  __hip_bfloat16* o1b = (__hip_bfloat16*)(ws + 11796480);    // 10,747,904 bf
  __hip_bfloat16* wbuf = (__hip_bfloat16*)(ws + 35733504);   // 999,424 bf
  int*   meta = (int*)(ws + 36233216);
  float* out = (float*)d_out;

  // bf16 transposed weight offsets
  const int oWp = 0, oWl0 = 32768, oWr0 = 229376, oWl1 = 425984, oWr1 = 557056;
  const int oWl2 = 688128, oWr2 = 753664, oWm0 = 819200, oWm1 = 950272, oWm2 = 983040;

  WtArgs wa;
  wa.j[0] = {(const float*)d_in[3], 128, 256,   0, oWp };
  wa.j[1] = {WlF[0],              256, 768,  32, oWl0};
  wa.j[2] = {WrF[0],              256, 768, 224, oWr0};
  wa.j[3] = {WlF[1],              256, 512, 416, oWl1};
  wa.j[4] = {WrF[1],              256, 512, 544, oWr1};
  wa.j[5] = {WlF[2],              256, 256, 672, oWl2};
  wa.j[6] = {WrF[2],              256, 256, 736, oWr2};
  wa.j[7] = {WmF[0],              512, 256, 800, oWm0};
  wa.j[8] = {WmF[1],              256, 128, 928, oWm1};
  wa.j[9] = {WmF[2],              128, 128, 960, oWm2};
  transpose_weights<<<977, 256, 0, stream>>>(wa, wbuf, ei, meta);  // block 976 = build_graph

  // h = x @ Wp + bp   (fp32 A staged with fused bf16 cast; fp32 out)
  gemm_mfma_f32a<0, 0><<<dim3(NTOT / 128, 2), 256, 0, stream>>>(x, wbuf + oWp, bp, h,
                                                                NTOT, 128, 256);

  layernorm<<<NTOT / 4, 256, 0, stream>>>(h, lng[0], lnb[0], hnb);

  // Fused GATv2 layers (R15): no xcat materialization.
  gat_fused<1><<<B_GRAPH, 256, 0, stream>>>(hnb, wbuf + oWl0, wbuf + oWr0, bl[0], br[0],
                                            att[0], bias[0], h, lng[1], lnb[1], meta, 3);
  gat_fused<1><<<B_GRAPH, 256, 0, stream>>>(hnb, wbuf + oWl1, wbuf + oWr1, bl[1], br[1],
                                            att[1], bias[1], h, lng[2], lnb[2], meta, 2);
  gat_fused<0><<<B_GRAPH, 256, 0, stream>>>(hnb, wbuf + oWl2, wbuf + oWr2, bl[2], br[2],
                                            att[2], bias[2], h, nullptr, nullptr, meta, 1);

  gemm_mfma_pair<<<dim3(M_MLP / 128, 2), 256, 0, stream>>>(h, pairs, wbuf + oWm0, bm[0], o1b, 256);
  mlp_tail<<<M_MLP / 128, 256, 0, stream>>>(o1b, wbuf + oWm1, bm[1], wbuf + oWm2, bm[2],
                                            WmF[3], bm[3], out);
}

// Round 4
// 472.758 us; speedup vs baseline: 1.1373x; 1.1373x over previous
//
#include <hip/hip_runtime.h>
#include <hip/hip_bf16.h>
#include <math.h>

// Problem constants
#define N_NODES 30
#define E_BASE  82
#define E_TOT   112         // 82 edges + 30 self loops
#define B_GRAPH 1024
#define HID     256
#define NTOT    (B_GRAPH * N_NODES)   // 30720
#define MAXIN   32
#define N_EH    41
#define M_MLP   (B_GRAPH * N_EH)      // 41984

#define META_SRC  0
#define META_DST  E_TOT
#define META_CNT  (2 * E_TOT)
#define META_LIST 256
#define META_INTS 1216

typedef __attribute__((ext_vector_type(8))) short bf16x8;
typedef __attribute__((ext_vector_type(4))) short bf16x4;
typedef __attribute__((ext_vector_type(4))) float f32x4;
#define AS3 __attribute__((address_space(3)))
#define AS1 __attribute__((address_space(1)))

__device__ __forceinline__ void gload_lds16(const void* g, void* l) {
  __builtin_amdgcn_global_load_lds((const AS1 void*)g, (AS3 void*)l, 16, 0, 0);
}

// Bit-reinterpret ONLY — callers must pass raw bf16 bit patterns (short lanes
// of bf16x4/8 vectors). Never pass __hip_bfloat16 (would value-convert via
// float->short — the R3 NaN bug).
__device__ __forceinline__ float b2f(short s) {
  union { unsigned u; float f; } x;
  x.u = ((unsigned)(unsigned short)s) << 16;
  return x.f;
}

// ---------------------------------------------------------------------------
// Transpose-cast all weights fp32 [K,N] -> bf16 [N,K]; block 976 instead
// builds the base-graph CSR (merged to save a launch).
// ---------------------------------------------------------------------------
struct WtJob { const float* in; int K, N, tstart, ooff; };
struct WtArgs { WtJob j[10]; };

__global__ __launch_bounds__(256)
void transpose_weights(WtArgs args, __hip_bfloat16* __restrict__ out,
                       const int* __restrict__ ei, int* __restrict__ meta) {
  int b = blockIdx.x;
  if (b == 976) {   // build_graph job
    __shared__ int cnt[N_NODES];
    int tid = threadIdx.x;
    if (tid < N_NODES) cnt[tid] = 0;
    __syncthreads();
    if (tid < E_TOT) {
      int s, d;
      if (tid < E_BASE) { s = ei[tid]; d = ei[B_GRAPH * E_BASE + tid]; }
      else              { s = tid - E_BASE; d = s; }
      meta[META_SRC + tid] = s;
      meta[META_DST + tid] = d;
      int pos = atomicAdd(&cnt[d], 1);
      if (pos < MAXIN) meta[META_LIST + d * MAXIN + pos] = tid;
    }
    __syncthreads();
    if (tid < N_NODES) meta[META_CNT + tid] = cnt[tid];
    return;
  }
  int ji = 0;
  #pragma unroll
  for (int i = 1; i < 10; i++) if (b >= args.j[i].tstart) ji = i;
  WtJob jb = args.j[ji];
  int t = b - jb.tstart;
  int ntn = jb.N >> 5;
  int tk = t / ntn, tn = t - tk * ntn;
  int k0 = tk * 32, n0 = tn * 32;
  __shared__ float s[32][33];
  int tx = threadIdx.x & 31, ty = threadIdx.x >> 5;
  #pragma unroll
  for (int p = 0; p < 4; p++)
    s[ty + p * 8][tx] = jb.in[(size_t)(k0 + ty + p * 8) * jb.N + n0 + tx];
  __syncthreads();
  __hip_bfloat16* o = out + jb.ooff;
  #pragma unroll
  for (int p = 0; p < 4; p++) {
    int n = ty + p * 8;
    o[(size_t)(n0 + n) * jb.K + k0 + tx] = __float2bfloat16(s[tx][n]);
  }
}

// ---------------------------------------------------------------------------
// bf16 MFMA GEMM (R9 fragment/epilogue; BK=64 per R12 — two [128][32] sub-tiles
// per barrier pair, halves barrier-drain count). EXACT R0 version — R13
// (operand-swap epilogue) and R14 (panelized C) both measured as regressions.
// C = act(A @ B + bias); A [M,K] bf16, Bt [N,K] bf16. K % 64 == 0.
// Split bias: col < N1 -> bias[col], else bias2[col-N1] (concat outputs).
// ---------------------------------------------------------------------------
template<int ACT, int OUTBF>
__global__ __launch_bounds__(256)
void gemm_mfma(const __hip_bfloat16* __restrict__ A, const __hip_bfloat16* __restrict__ Bt,
               const float* __restrict__ bias, const float* __restrict__ bias2,
               void* __restrict__ Cv, int M, int K, int N, int N1)
{
  __shared__ __hip_bfloat16 sA[2][128 * 32];
  __shared__ __hip_bfloat16 sB[2][128 * 32];
  const int tid = threadIdx.x;
  const int lane = tid & 63;
  const int wave = tid >> 6;
  const int wx = wave & 1, wy = wave >> 1;
  const int bm = blockIdx.x, bn = blockIdx.y;
  const int mrow = lane & 15, quad = lane >> 4;

  const int r0 = tid >> 2, kc0 = (tid & 3) * 8;
  const __hip_bfloat16* Ag0 = A + (size_t)(bm * 128 + r0) * K + kc0;
  const __hip_bfloat16* Ag1 = A + (size_t)(bm * 128 + r0 + 64) * K + kc0;
  const __hip_bfloat16* Bg0 = Bt + (size_t)(bn * 128 + r0) * K + kc0;
  const __hip_bfloat16* Bg1 = Bt + (size_t)(bn * 128 + r0 + 64) * K + kc0;

  f32x4 acc[4][4];
  #pragma unroll
  for (int i = 0; i < 4; i++)
    #pragma unroll
    for (int j = 0; j < 4; j++)
      acc[i][j] = (f32x4){0.f, 0.f, 0.f, 0.f};

  for (int kt = 0; kt < K; kt += 64) {
    __syncthreads();
    #pragma unroll
    for (int s = 0; s < 2; s++) {
      gload_lds16(Ag0 + kt + s * 32, &sA[s][tid * 8]);
      gload_lds16(Ag1 + kt + s * 32, &sA[s][2048 + tid * 8]);
      gload_lds16(Bg0 + kt + s * 32, &sB[s][tid * 8]);
      gload_lds16(Bg1 + kt + s * 32, &sB[s][2048 + tid * 8]);
    }
    __syncthreads();

    #pragma unroll
    for (int s = 0; s < 2; s++) {
      bf16x8 af[4], bfr[4];
      #pragma unroll
      for (int i = 0; i < 4; i++) {
        af[i]  = *(const bf16x8*)&sA[s][(wy * 64 + i * 16 + mrow) * 32 + quad * 8];
        bfr[i] = *(const bf16x8*)&sB[s][(wx * 64 + i * 16 + mrow) * 32 + quad * 8];
      }
      #pragma unroll
      for (int i = 0; i < 4; i++)
        #pragma unroll
        for (int j = 0; j < 4; j++)
          acc[i][j] = __builtin_amdgcn_mfma_f32_16x16x32_bf16(af[i], bfr[j], acc[i][j], 0, 0, 0);
    }
  }

  #pragma unroll
  for (int i = 0; i < 4; i++) {
    #pragma unroll
    for (int r = 0; r < 4; r++) {
      size_t row = (size_t)bm * 128 + wy * 64 + i * 16 + quad * 4 + r;
      #pragma unroll
      for (int j = 0; j < 4; j++) {
        int col = bn * 128 + wx * 64 + j * 16 + mrow;
        float bc = (col < N1) ? bias[col] : bias2[col - N1];
        float v = acc[i][j][r] + bc;
        if (ACT) v = v > 0.f ? v : 0.01f * v;
        if (OUTBF) ((__hip_bfloat16*)Cv)[row * N + col] = __float2bfloat16(v);
        else       ((float*)Cv)[row * N + col] = v;
      }
    }
  }
}

// ---------------------------------------------------------------------------
// MFMA GEMM with fp32 A staged via in-register bf16 cast (fused cast): proj.
// (EXACT R0 version.)
// ---------------------------------------------------------------------------
template<int ACT, int OUTBF>
__global__ __launch_bounds__(256)
void gemm_mfma_f32a(const float* __restrict__ A, const __hip_bfloat16* __restrict__ Bt,
                    const float* __restrict__ bias, void* __restrict__ Cv,
                    int M, int K, int N)
{
  __shared__ __hip_bfloat16 sA[128 * 32];
  __shared__ __hip_bfloat16 sB[128 * 32];
  const int tid = threadIdx.x;
  const int lane = tid & 63;
  const int wave = tid >> 6;
  const int wx = wave & 1, wy = wave >> 1;
  const int bm = blockIdx.x, bn = blockIdx.y;
  const int mrow = lane & 15, quad = lane >> 4;

  const int r0 = tid >> 2, kc0 = (tid & 3) * 8;
  const float* Ag0 = A + (size_t)(bm * 128 + r0) * K + kc0;
  const float* Ag1 = A + (size_t)(bm * 128 + r0 + 64) * K + kc0;
  const __hip_bfloat16* Bg0 = Bt + (size_t)(bn * 128 + r0) * K + kc0;
  const __hip_bfloat16* Bg1 = Bt + (size_t)(bn * 128 + r0 + 64) * K + kc0;

  f32x4 acc[4][4];
  #pragma unroll
  for (int i = 0; i < 4; i++)
    #pragma unroll
    for (int j = 0; j < 4; j++)
      acc[i][j] = (f32x4){0.f, 0.f, 0.f, 0.f};

  for (int kt = 0; kt < K; kt += 32) {
    float4 a00 = *(const float4*)(Ag0 + kt);
    float4 a01 = *(const float4*)(Ag0 + kt + 4);
    float4 a10 = *(const float4*)(Ag1 + kt);
    float4 a11 = *(const float4*)(Ag1 + kt + 4);
    __syncthreads();
    {
      __hip_bfloat16 t[8];
      t[0] = __float2bfloat16(a00.x); t[1] = __float2bfloat16(a00.y);
      t[2] = __float2bfloat16(a00.z); t[3] = __float2bfloat16(a00.w);
      t[4] = __float2bfloat16(a01.x); t[5] = __float2bfloat16(a01.y);
      t[6] = __float2bfloat16(a01.z); t[7] = __float2bfloat16(a01.w);
      *(bf16x8*)&sA[tid * 8] = *(bf16x8*)t;
      t[0] = __float2bfloat16(a10.x); t[1] = __float2bfloat16(a10.y);
      t[2] = __float2bfloat16(a10.z); t[3] = __float2bfloat16(a10.w);
      t[4] = __float2bfloat16(a11.x); t[5] = __float2bfloat16(a11.y);
      t[6] = __float2bfloat16(a11.z); t[7] = __float2bfloat16(a11.w);
      *(bf16x8*)&sA[2048 + tid * 8] = *(bf16x8*)t;
    }
    gload_lds16(Bg0 + kt, &sB[tid * 8]);
    gload_lds16(Bg1 + kt, &sB[2048 + tid * 8]);
    __syncthreads();

    bf16x8 af[4], bfr[4];
    #pragma unroll
    for (int i = 0; i < 4; i++) {
      af[i]  = *(const bf16x8*)&sA[(wy * 64 + i * 16 + mrow) * 32 + quad * 8];
      bfr[i] = *(const bf16x8*)&sB[(wx * 64 + i * 16 + mrow) * 32 + quad * 8];
    }
    #pragma unroll
    for (int i = 0; i < 4; i++)
      #pragma unroll
      for (int j = 0; j < 4; j++)
        acc[i][j] = __builtin_amdgcn_mfma_f32_16x16x32_bf16(af[i], bfr[j], acc[i][j], 0, 0, 0);
  }

  #pragma unroll
  for (int i = 0; i < 4; i++) {
    #pragma unroll
    for (int r = 0; r < 4; r++) {
      size_t row = (size_t)bm * 128 + wy * 64 + i * 16 + quad * 4 + r;
      #pragma unroll
      for (int j = 0; j < 4; j++) {
        int col = bn * 128 + wx * 64 + j * 16 + mrow;
        float v = acc[i][j][r] + bias[col];
        if (ACT) v = v > 0.f ? v : 0.01f * v;
        if (OUTBF) ((__hip_bfloat16*)Cv)[row * N + col] = __float2bfloat16(v);
        else       ((float*)Cv)[row * N + col] = v;
      }
    }
  }
}

// ---------------------------------------------------------------------------
// MFMA GEMM with fused edge-pair gather from fp32 h (EXACT R0 version).
// ---------------------------------------------------------------------------
__global__ __launch_bounds__(256)
void gemm_mfma_pair(const float* __restrict__ h, const int* __restrict__ pairs,
                    const __hip_bfloat16* __restrict__ Bt, const float* __restrict__ bias,
                    __hip_bfloat16* __restrict__ C, int N)
{
  const int K = 512;
  __shared__ __hip_bfloat16 sA[128 * 32];
  __shared__ __hip_bfloat16 sB[128 * 32];
  const int tid = threadIdx.x;
  const int lane = tid & 63;
  const int wave = tid >> 6;
  const int wx = wave & 1, wy = wave >> 1;
  const int bm = blockIdx.x, bn = blockIdx.y;
  const int mrow = lane & 15, quad = lane >> 4;

  const float* pu[2]; const float* pv[2]; int sub[2];
  #pragma unroll
  for (int cI = 0; cI < 2; cI++) {
    int c = tid + cI * 256;
    int r0 = c >> 2; sub[cI] = (c & 3) * 8;
    int R = bm * 128 + r0;
    int b = R / N_EH, p = R - b * N_EH;
    int u = pairs[p * 2], v = pairs[p * 2 + 1];
    pu[cI] = h + ((size_t)b * N_NODES + u) * HID;
    pv[cI] = h + ((size_t)b * N_NODES + v) * HID;
  }

  const int r0 = tid >> 2, kc0 = (tid & 3) * 8;
  const __hip_bfloat16* Bg0 = Bt + (size_t)(bn * 128 + r0) * K + kc0;
  const __hip_bfloat16* Bg1 = Bt + (size_t)(bn * 128 + r0 + 64) * K + kc0;

  f32x4 acc[4][4];
  #pragma unroll
  for (int i = 0; i < 4; i++)
    #pragma unroll
    for (int j = 0; j < 4; j++)
      acc[i][j] = (f32x4){0.f, 0.f, 0.f, 0.f};

  for (int kt = 0; kt < 512; kt += 32) {
    float4 av[2][2];
    #pragma unroll
    for (int cI = 0; cI < 2; cI++) {
      const float* src = (kt < 256 ? pu[cI] + kt : pv[cI] + kt - 256) + sub[cI];
      av[cI][0] = *(const float4*)src;
      av[cI][1] = *(const float4*)(src + 4);
    }
    __syncthreads();
    #pragma unroll
    for (int cI = 0; cI < 2; cI++) {
      __hip_bfloat16 t[8];
      t[0] = __float2bfloat16(av[cI][0].x); t[1] = __float2bfloat16(av[cI][0].y);
      t[2] = __float2bfloat16(av[cI][0].z); t[3] = __float2bfloat16(av[cI][0].w);
      t[4] = __float2bfloat16(av[cI][1].x); t[5] = __float2bfloat16(av[cI][1].y);
      t[6] = __float2bfloat16(av[cI][1].z); t[7] = __float2bfloat16(av[cI][1].w);
      *(bf16x8*)&sA[(tid + cI * 256) * 8] = *(bf16x8*)t;
    }
    gload_lds16(Bg0 + kt, &sB[tid * 8]);
    gload_lds16(Bg1 + kt, &sB[2048 + tid * 8]);
    __syncthreads();

    bf16x8 af[4], bfr[4];
    #pragma unroll
    for (int i = 0; i < 4; i++) {
      af[i]  = *(const bf16x8*)&sA[(wy * 64 + i * 16 + mrow) * 32 + quad * 8];
      bfr[i] = *(const bf16x8*)&sB[(wx * 64 + i * 16 + mrow) * 32 + quad * 8];
    }
    #pragma unroll
    for (int i = 0; i < 4; i++)
      #pragma unroll
      for (int j = 0; j < 4; j++)
        acc[i][j] = __builtin_amdgcn_mfma_f32_16x16x32_bf16(af[i], bfr[j], acc[i][j], 0, 0, 0);
  }

  #pragma unroll
  for (int i = 0; i < 4; i++) {
    #pragma unroll
    for (int r = 0; r < 4; r++) {
      size_t row = (size_t)bm * 128 + wy * 64 + i * 16 + quad * 4 + r;
      #pragma unroll
      for (int j = 0; j < 4; j++) {
        int col = bn * 128 + wx * 64 + j * 16 + mrow;
        float v = acc[i][j][r] + bias[col];
        v = v > 0.f ? v : 0.01f * v;
        C[row * N + col] = __float2bfloat16(v);
      }
    }
  }
}

// ---------------------------------------------------------------------------
// Fused MLP tail (R11 — proven win; EXACT R0 version).
// ---------------------------------------------------------------------------
#define O2P 136
__global__ __launch_bounds__(256)
void mlp_tail(const __hip_bfloat16* __restrict__ o1, const __hip_bfloat16* __restrict__ W1t,
              const float* __restrict__ b1, const __hip_bfloat16* __restrict__ W2t,
              const float* __restrict__ b2, const float* __restrict__ w3,
              const float* __restrict__ b3, float* __restrict__ out)
{
  __shared__ __hip_bfloat16 sA[128 * 32];
  __shared__ __hip_bfloat16 sB[128 * 32];
  __shared__ __hip_bfloat16 sO2[128 * O2P];
  __shared__ float spart[2][128];
  const int tid = threadIdx.x;
  const int lane = tid & 63;
  const int wave = tid >> 6;
  const int wx = wave & 1, wy = wave >> 1;
  const int bm = blockIdx.x;
  const int mrow = lane & 15, quad = lane >> 4;
  const int r0 = tid >> 2, kc0 = (tid & 3) * 8;

  const __hip_bfloat16* Ag0 = o1 + (size_t)(bm * 128 + r0) * 256 + kc0;
  const __hip_bfloat16* Ag1 = o1 + (size_t)(bm * 128 + r0 + 64) * 256 + kc0;
  const __hip_bfloat16* Bg0 = W1t + (size_t)r0 * 256 + kc0;
  const __hip_bfloat16* Bg1 = W1t + (size_t)(r0 + 64) * 256 + kc0;

  f32x4 acc[4][4];
  #pragma unroll
  for (int i = 0; i < 4; i++)
    #pragma unroll
    for (int j = 0; j < 4; j++)
      acc[i][j] = (f32x4){0.f, 0.f, 0.f, 0.f};

  for (int kt = 0; kt < 256; kt += 32) {
    __syncthreads();
    gload_lds16(Ag0 + kt, &sA[tid * 8]);
    gload_lds16(Ag1 + kt, &sA[2048 + tid * 8]);
    gload_lds16(Bg0 + kt, &sB[tid * 8]);
    gload_lds16(Bg1 + kt, &sB[2048 + tid * 8]);
    __syncthreads();

    bf16x8 af[4], bfr[4];
    #pragma unroll
    for (int i = 0; i < 4; i++) {
      af[i]  = *(const bf16x8*)&sA[(wy * 64 + i * 16 + mrow) * 32 + quad * 8];
      bfr[i] = *(const bf16x8*)&sB[(wx * 64 + i * 16 + mrow) * 32 + quad * 8];
    }
    #pragma unroll
    for (int i = 0; i < 4; i++)
      #pragma unroll
      for (int j = 0; j < 4; j++)
        acc[i][j] = __builtin_amdgcn_mfma_f32_16x16x32_bf16(af[i], bfr[j], acc[i][j], 0, 0, 0);
  }

  __syncthreads();
  #pragma unroll
  for (int i = 0; i < 4; i++) {
    #pragma unroll
    for (int r = 0; r < 4; r++) {
      int row = wy * 64 + i * 16 + quad * 4 + r;
      #pragma unroll
      for (int j = 0; j < 4; j++) {
        int col = wx * 64 + j * 16 + mrow;
        float v = acc[i][j][r] + b1[col];
        v = v > 0.f ? v : 0.01f * v;
        sO2[row * O2P + col] = __float2bfloat16(v);
      }
    }
  }

  f32x4 acc2[4][4];
  #pragma unroll
  for (int i = 0; i < 4; i++)
    #pragma unroll
    for (int j = 0; j < 4; j++)
      acc2[i][j] = (f32x4){0.f, 0.f, 0.f, 0.f};

  for (int kt = 0; kt < 128; kt += 32) {
    __syncthreads();
    gload_lds16(W2t + (size_t)r0 * 128 + kt + kc0, &sB[tid * 8]);
    gload_lds16(W2t + (size_t)(r0 + 64) * 128 + kt + kc0, &sB[2048 + tid * 8]);
    __syncthreads();

    bf16x8 af[4], bfr[4];
    #pragma unroll
    for (int i = 0; i < 4; i++) {
      af[i]  = *(const bf16x8*)&sO2[(wy * 64 + i * 16 + mrow) * O2P + kt + quad * 8];
      bfr[i] = *(const bf16x8*)&sB[(wx * 64 + i * 16 + mrow) * 32 + quad * 8];
    }
    #pragma unroll
    for (int i = 0; i < 4; i++)
      #pragma unroll
      for (int j = 0; j < 4; j++)
        acc2[i][j] = __builtin_amdgcn_mfma_f32_16x16x32_bf16(af[i], bfr[j], acc2[i][j], 0, 0, 0);
  }

  float w3v[4], b2v[4];
  #pragma unroll
  for (int j = 0; j < 4; j++) {
    int col = wx * 64 + j * 16 + mrow;
    w3v[j] = w3[col];
    b2v[j] = b2[col];
  }
  #pragma unroll
  for (int i = 0; i < 4; i++) {
    #pragma unroll
    for (int r = 0; r < 4; r++) {
      float s = 0.f;
      #pragma unroll
      for (int j = 0; j < 4; j++) {
        float v = acc2[i][j][r] + b2v[j];
        v = v > 0.f ? v : 0.01f * v;
        s += v * w3v[j];
      }
      #pragma unroll
      for (int off = 8; off; off >>= 1) s += __shfl_xor(s, off);
      if (mrow == 0) {
        int row = wy * 64 + i * 16 + quad * 4 + r;
        spart[wx][row] = s;
      }
    }
  }
  __syncthreads();
  if (tid < 128)
    out[(size_t)bm * 128 + tid] = spart[0][tid] + spart[1][tid] + b3[0];
}

// ---------------------------------------------------------------------------
// LayerNorm over HID=256; one wave per row; writes bf16. (Used once, after proj.)
// ---------------------------------------------------------------------------
__global__ __launch_bounds__(256)
void layernorm(const float* __restrict__ h, const float* __restrict__ g,
               const float* __restrict__ b, __hip_bfloat16* __restrict__ hn)
{
  const int wv = threadIdx.x >> 6, lane = threadIdx.x & 63;
  const size_t row = (size_t)blockIdx.x * 4 + wv;
  const float* hr = h + row * HID;
  float v[4];
  float sum = 0.f;
  #pragma unroll
  for (int j = 0; j < 4; j++) { v[j] = hr[lane + 64 * j]; sum += v[j]; }
  #pragma unroll
  for (int off = 32; off; off >>= 1) sum += __shfl_xor(sum, off);
  float mu = sum * (1.f / 256.f);
  float vs = 0.f;
  #pragma unroll
  for (int j = 0; j < 4; j++) { float d = v[j] - mu; vs += d * d; }
  #pragma unroll
  for (int off = 32; off; off >>= 1) vs += __shfl_xor(vs, off);
  float rs = rsqrtf(vs * (1.f / 256.f) + 1e-5f);
  __hip_bfloat16* outr = hn + row * HID;
  #pragma unroll
  for (int j = 0; j < 4; j++) {
    int c = lane + 64 * j;
    outr[c] = __float2bfloat16((v[j] - mu) * rs * g[c] + b[c]);
  }
}

// ---------------------------------------------------------------------------
// R16: MERGED alpha+agg (gat_alag) — one block per graph, loop over heads.
// Combines the EXACT proven bodies of R0's gat_alpha and gat_agg so xl is
// read from HBM once per head instead of twice (saves 47/31/16 MB per layer),
// kills the alphaG round-trip, and drops 3 launches. Unlike R3's full fusion
// there is NO GEMM inside — this stays the same memory-bound gather the two
// source kernels were; xcat is still produced by the proven-fast gemm_mfma.
// Staging: xl double-buffered across heads (R0 agg pattern); xr single-
// buffered, re-staged after the logits barrier (alpha is its only reader),
// drained by the loop-head barrier (__syncthreads drains vmcnt).
// LDS ~52 KB -> 3 blocks/CU.
// ---------------------------------------------------------------------------
template<int DO_LN>
__global__ __launch_bounds__(256, 3)
void gat_alag(const __hip_bfloat16* __restrict__ xcat, const float* __restrict__ att,
              const float* __restrict__ bias, float* __restrict__ h,
              const float* __restrict__ lnG, const float* __restrict__ lnB,
              __hip_bfloat16* __restrict__ hn, const int* __restrict__ meta, int H)
{
  __shared__ __hip_bfloat16 sxl[2][N_NODES * HID];   // 2 x 15 KB (head dbuf)
  __shared__ __hip_bfloat16 sxr[N_NODES * HID];      // 15 KB
  __shared__ float slog[E_TOT], salpha[E_TOT], smax[N_NODES], sden[N_NODES];
  __shared__ int ssrc[E_TOT], sdst[E_TOT], scnt[N_NODES], slist[N_NODES * MAXIN];

  const int tid = threadIdx.x;
  const int g = blockIdx.x;
  const size_t nodebase = (size_t)g * N_NODES;
  const int S = 2 * H * HID;
  const int c4 = tid & 63;
  const int ng = tid >> 6;
  const int wv = tid >> 6;

  if (tid < E_TOT) { ssrc[tid] = meta[META_SRC + tid]; sdst[tid] = meta[META_DST + tid]; }
  if (tid < N_NODES) scnt[tid] = meta[META_CNT + tid];
  for (int i = tid; i < N_NODES * MAXIN; i += 256) slist[i] = meta[META_LIST + i];

  float4 hres[8];
  #pragma unroll
  for (int ki = 0; ki < 8; ki++) {
    int k = ng + ki * 4;
    if (k < N_NODES) hres[ki] = *(const float4*)&h[(nodebase + k) * HID + c4 * 4];
  }

  // stage xl[0] -> sxl[0], xr[0] -> sxr
  {
    int i = tid;
    #pragma unroll
    for (int p = 0; p < 4; p++, i += 256) {
      if (i < N_NODES * HID / 8) {
        int node = i >> 5, c = (i & 31) * 8;
        const __hip_bfloat16* row = &xcat[(nodebase + node) * S + c];
        gload_lds16(row + 0 * HID, &sxl[0][(size_t)i * 8]);
        gload_lds16(row + H * HID, &sxr[(size_t)i * 8]);
      }
    }
  }

  float agg[8][4];
  #pragma unroll
  for (int ki = 0; ki < 8; ki++)
    #pragma unroll
    for (int j = 0; j < 4; j++) agg[ki][j] = 0.f;

  for (int hh = 0; hh < H; hh++) {
    const int buf = hh & 1;
    __syncthreads();   // loop-head: staged loads drained; prev agg/norm done

    // prefetch next head's xl into the other buffer (safe: its last reader was
    // the agg of head hh-1, complete before the barrier above)
    if (hh + 1 < H) {
      int i = tid;
      #pragma unroll
      for (int p = 0; p < 4; p++, i += 256) {
        if (i < N_NODES * HID / 8) {
          int node = i >> 5, c = (i & 31) * 8;
          gload_lds16(&xcat[(nodebase + node) * S + (hh + 1) * HID + c],
                      &sxl[buf ^ 1][(size_t)i * 8]);
        }
      }
    }

    // ---- logits (proven gat_alpha body) ----
    if (tid < N_NODES) sden[tid] = 0.f;
    {
      const int l32 = tid & 31, esub = (tid >> 5) & 1;
      const int c0 = l32 * 8;
      float attr[8];
      #pragma unroll
      for (int j = 0; j < 8; j++) attr[j] = att[hh * HID + c0 + j];
      #pragma unroll
      for (int pass = 0; pass < 14; pass++) {
        int e = pass * 8 + wv * 2 + esub;
        bf16x8 a = *(const bf16x8*)&sxl[buf][ssrc[e] * HID + c0];
        bf16x8 b = *(const bf16x8*)&sxr[sdst[e] * HID + c0];
        float sum = 0.f;
        #pragma unroll
        for (int j = 0; j < 8; j++) {
          float v = b2f(a[j]) + b2f(b[j]);
          v = v > 0.f ? v : 0.2f * v;
          sum += v * attr[j];
        }
        #pragma unroll
        for (int off = 16; off; off >>= 1) sum += __shfl_xor(sum, off);
        if (l32 == 0) slog[e] = sum;
      }
    }
    __syncthreads();   // (C) logits done; sxr reads complete

    // prefetch next head's xr into sxr (only logits reads it; safe after C;
    // drained by next loop-head barrier)
    if (hh + 1 < H) {
      int i = tid;
      #pragma unroll
      for (int p = 0; p < 4; p++, i += 256) {
        if (i < N_NODES * HID / 8) {
          int node = i >> 5, c = (i & 31) * 8;
          gload_lds16(&xcat[(nodebase + node) * S + (H + hh + 1) * HID + c],
                      &sxr[(size_t)i * 8]);
        }
      }
    }

    if (tid < N_NODES) {
      int cnt = scnt[tid];
      const int* lst = &slist[tid * MAXIN];
      float m = -1e30f;
      for (int i = 0; i < cnt; i++) m = fmaxf(m, slog[lst[i]]);
      smax[tid] = m;
    }
    __syncthreads();   // (D)
    if (tid < E_TOT) {
      float ex = expf(slog[tid] - smax[sdst[tid]]);
      slog[tid] = ex;
      atomicAdd(&sden[sdst[tid]], ex);
    }
    __syncthreads();   // (E)
    if (tid < E_TOT) salpha[tid] = slog[tid] / sden[sdst[tid]];
    __syncthreads();   // (F) alpha ready

    // ---- agg (proven gat_agg body) ----
    #pragma unroll
    for (int ki = 0; ki < 8; ki++) {
      int k = ng + ki * 4;
      if (k < N_NODES) {
        int cnt = scnt[k];
        const int* lst = &slist[k * MAXIN];
        for (int i = 0; i < cnt; i++) {
          int e = lst[i];                       // wave-uniform broadcast reads
          float al = salpha[e];
          bf16x4 v = *(const bf16x4*)&sxl[buf][ssrc[e] * HID + c4 * 4];
          agg[ki][0] += al * b2f(v[0]);
          agg[ki][1] += al * b2f(v[1]);
          agg[ki][2] += al * b2f(v[2]);
          agg[ki][3] += al * b2f(v[3]);
        }
      }
    }
  }

  // ---- finalize (proven gat_agg epilogue) ----
  const float invH = 1.f / (float)H;
  const float4 bs = *(const float4*)&bias[c4 * 4];
  float4 gv, bv;
  if (DO_LN) {
    gv = *(const float4*)&lnG[c4 * 4];
    bv = *(const float4*)&lnB[c4 * 4];
  }
  #pragma unroll
  for (int ki = 0; ki < 8; ki++) {
    int k = ng + ki * 4;
    if (k < N_NODES) {
      float o0 = agg[ki][0] * invH + bs.x; o0 = o0 > 0.f ? o0 : 0.01f * o0; o0 += hres[ki].x;
      float o1 = agg[ki][1] * invH + bs.y; o1 = o1 > 0.f ? o1 : 0.01f * o1; o1 += hres[ki].y;
      float o2 = agg[ki][2] * invH + bs.z; o2 = o2 > 0.f ? o2 : 0.01f * o2; o2 += hres[ki].z;
      float o3 = agg[ki][3] * invH + bs.w; o3 = o3 > 0.f ? o3 : 0.01f * o3; o3 += hres[ki].w;
      float4 o4 = {o0, o1, o2, o3};
      *(float4*)&h[(nodebase + k) * HID + c4 * 4] = o4;
      if (DO_LN) {
        float sum = o0 + o1 + o2 + o3;
        #pragma unroll
        for (int off = 32; off; off >>= 1) sum += __shfl_xor(sum, off);
        float mu = sum * (1.f / 256.f);
        float d0 = o0 - mu, d1 = o1 - mu, d2 = o2 - mu, d3 = o3 - mu;
        float vs = d0 * d0 + d1 * d1 + d2 * d2 + d3 * d3;
        #pragma unroll
        for (int off = 32; off; off >>= 1) vs += __shfl_xor(vs, off);
        float rs = rsqrtf(vs * (1.f / 256.f) + 1e-5f);
        __hip_bfloat16 t[4];
        t[0] = __float2bfloat16(d0 * rs * gv.x + bv.x);
        t[1] = __float2bfloat16(d1 * rs * gv.y + bv.y);
        t[2] = __float2bfloat16(d2 * rs * gv.z + bv.z);
        t[3] = __float2bfloat16(d3 * rs * gv.w + bv.w);
        *(bf16x4*)&hn[(nodebase + k) * HID + c4 * 4] = *(bf16x4*)t;
      }
    }
  }
}

// ---------------------------------------------------------------------------
extern "C" void kernel_launch(void* const* d_in, const int* in_sizes, int n_in,
                              void* d_out, int out_size, void* d_ws, size_t ws_size,
                              hipStream_t stream) {
  const float* x     = (const float*)d_in[0];
  const int*   ei    = (const int*)d_in[1];
  const int*   pairs = (const int*)d_in[2];
  const float* bp    = (const float*)d_in[4];
  const float *lng[3], *lnb[3], *bl[3], *br[3], *att[3], *bias[3];
  const float *WlF[3], *WrF[3];
  for (int l = 0; l < 3; l++) {
    int base = 5 + l * 8;
    lng[l]  = (const float*)d_in[base + 0];
    lnb[l]  = (const float*)d_in[base + 1];
    WlF[l]  = (const float*)d_in[base + 2];
    bl[l]   = (const float*)d_in[base + 3];
    WrF[l]  = (const float*)d_in[base + 4];
    br[l]   = (const float*)d_in[base + 5];
    att[l]  = (const float*)d_in[base + 6];
    bias[l] = (const float*)d_in[base + 7];
  }
  const float* WmF[4] = {(const float*)d_in[29], (const float*)d_in[31],
                         (const float*)d_in[33], (const float*)d_in[35]};
  const float* bm[4] = {(const float*)d_in[30], (const float*)d_in[32],
                        (const float*)d_in[34], (const float*)d_in[36]};

  // workspace layout (float offsets)
  float* ws  = (float*)d_ws;
  float* h   = ws;                                           // [0, 7864320)
  __hip_bfloat16* hnb = (__hip_bfloat16*)(ws + 7864320);     // 3,932,160 bf
  __hip_bfloat16* xcat = (__hip_bfloat16*)(ws + 11796480);   // up to 47,185,920 bf
  __hip_bfloat16* wbuf = (__hip_bfloat16*)(ws + 35733504);   // 999,424 bf
  int*   meta = (int*)(ws + 36233216);
  __hip_bfloat16* o1b = (__hip_bfloat16*)xcat;               // 10,747,904 bf (xcat dead)
  float* out = (float*)d_out;

  // bf16 transposed weight offsets (Wl and Wr contiguous per layer -> one GEMM)
  const int oWp = 0, oWl0 = 32768, oWr0 = 229376, oWl1 = 425984, oWr1 = 557056;
  const int oWl2 = 688128, oWr2 = 753664, oWm0 = 819200, oWm1 = 950272, oWm2 = 983040;

  WtArgs wa;
  wa.j[0] = {(const float*)d_in[3], 128, 256,   0, oWp };
  wa.j[1] = {WlF[0],              256, 768,  32, oWl0};
  wa.j[2] = {WrF[0],              256, 768, 224, oWr0};
  wa.j[3] = {WlF[1],              256, 512, 416, oWl1};
  wa.j[4] = {WrF[1],              256, 512, 544, oWr1};
  wa.j[5] = {WlF[2],              256, 256, 672, oWl2};
  wa.j[6] = {WrF[2],              256, 256, 736, oWr2};
  wa.j[7] = {WmF[0],              512, 256, 800, oWm0};
  wa.j[8] = {WmF[1],              256, 128, 928, oWm1};
  wa.j[9] = {WmF[2],              128, 128, 960, oWm2};
  transpose_weights<<<977, 256, 0, stream>>>(wa, wbuf, ei, meta);  // block 976 = build_graph

  // h = x @ Wp + bp   (fp32 A staged with fused bf16 cast; fp32 out)
  gemm_mfma_f32a<0, 0><<<dim3(NTOT / 128, 2), 256, 0, stream>>>(x, wbuf + oWp, bp, h,
                                                                NTOT, 128, 256);

  layernorm<<<NTOT / 4, 256, 0, stream>>>(h, lng[0], lnb[0], hnb);

  const int Hs[3] = {3, 2, 1};
  const int oWl[3] = {oWl0, oWl1, oWl2};
  for (int l = 0; l < 3; l++) {
    int N = 2 * Hs[l] * HID;   // combined xl|xr output
    gemm_mfma<0, 1><<<dim3(NTOT / 128, N / 128), 256, 0, stream>>>(
        hnb, wbuf + oWl[l], bl[l], br[l], xcat, NTOT, HID, N, N / 2);
    if (l < 2)
      gat_alag<1><<<B_GRAPH, 256, 0, stream>>>(xcat, att[l], bias[l], h,
                                               lng[l + 1], lnb[l + 1], hnb, meta, Hs[l]);
    else
      gat_alag<0><<<B_GRAPH, 256, 0, stream>>>(xcat, att[l], bias[l], h,
                                               nullptr, nullptr, nullptr, meta, Hs[l]);
  }

  gemm_mfma_pair<<<dim3(M_MLP / 128, 2), 256, 0, stream>>>(h, pairs, wbuf + oWm0, bm[0], o1b, 256);
  mlp_tail<<<M_MLP / 128, 256, 0, stream>>>(o1b, wbuf + oWm1, bm[1], wbuf + oWm2, bm[2],
                                            WmF[3], bm[3], out);
}

// Round 5
// 459.903 us; speedup vs baseline: 1.1691x; 1.0280x over previous
//
#include <hip/hip_runtime.h>
#include <hip/hip_bf16.h>
#include <math.h>

// Problem constants
#define N_NODES 30
#define E_BASE  82
#define E_TOT   112         // 82 edges + 30 self loops
#define B_GRAPH 1024
#define HID     256
#define NTOT    (B_GRAPH * N_NODES)   // 30720
#define MAXIN   32
#define N_EH    41
#define M_MLP   (B_GRAPH * N_EH)      // 41984

#define META_SRC  0
#define META_DST  E_TOT
#define META_CNT  (2 * E_TOT)
#define META_LIST 256
#define META_INTS 1216

typedef __attribute__((ext_vector_type(8))) short bf16x8;
typedef __attribute__((ext_vector_type(4))) short bf16x4;
typedef __attribute__((ext_vector_type(4))) float f32x4;
#define AS3 __attribute__((address_space(3)))
#define AS1 __attribute__((address_space(1)))

__device__ __forceinline__ void gload_lds16(const void* g, void* l) {
  __builtin_amdgcn_global_load_lds((const AS1 void*)g, (AS3 void*)l, 16, 0, 0);
}

// Bit-reinterpret ONLY — callers must pass raw bf16 bit patterns (short lanes
// of bf16x4/8 vectors). Never pass __hip_bfloat16 (would value-convert via
// float->short — the R3 NaN bug).
__device__ __forceinline__ float b2f(short s) {
  union { unsigned u; float f; } x;
  x.u = ((unsigned)(unsigned short)s) << 16;
  return x.f;
}

// float -> bf16 bit pattern (same rounding as __float2bfloat16; raw short out)
__device__ __forceinline__ short f2bf_bits(float f) {
  union { __hip_bfloat16 h; short s; } u;
  u.h = __float2bfloat16(f);
  return u.s;
}

// ---------------------------------------------------------------------------
// Transpose-cast all weights fp32 [K,N] -> bf16 [N,K]; block 976 instead
// builds the base-graph CSR (merged to save a launch).
// ---------------------------------------------------------------------------
struct WtJob { const float* in; int K, N, tstart, ooff; };
struct WtArgs { WtJob j[10]; };

__global__ __launch_bounds__(256)
void transpose_weights(WtArgs args, __hip_bfloat16* __restrict__ out,
                       const int* __restrict__ ei, int* __restrict__ meta) {
  int b = blockIdx.x;
  if (b == 976) {   // build_graph job
    __shared__ int cnt[N_NODES];
    int tid = threadIdx.x;
    if (tid < N_NODES) cnt[tid] = 0;
    __syncthreads();
    if (tid < E_TOT) {
      int s, d;
      if (tid < E_BASE) { s = ei[tid]; d = ei[B_GRAPH * E_BASE + tid]; }
      else              { s = tid - E_BASE; d = s; }
      meta[META_SRC + tid] = s;
      meta[META_DST + tid] = d;
      int pos = atomicAdd(&cnt[d], 1);
      if (pos < MAXIN) meta[META_LIST + d * MAXIN + pos] = tid;
    }
    __syncthreads();
    if (tid < N_NODES) meta[META_CNT + tid] = cnt[tid];
    return;
  }
  int ji = 0;
  #pragma unroll
  for (int i = 1; i < 10; i++) if (b >= args.j[i].tstart) ji = i;
  WtJob jb = args.j[ji];
  int t = b - jb.tstart;
  int ntn = jb.N >> 5;
  int tk = t / ntn, tn = t - tk * ntn;
  int k0 = tk * 32, n0 = tn * 32;
  __shared__ float s[32][33];
  int tx = threadIdx.x & 31, ty = threadIdx.x >> 5;
  #pragma unroll
  for (int p = 0; p < 4; p++)
    s[ty + p * 8][tx] = jb.in[(size_t)(k0 + ty + p * 8) * jb.N + n0 + tx];
  __syncthreads();
  __hip_bfloat16* o = out + jb.ooff;
  #pragma unroll
  for (int p = 0; p < 4; p++) {
    int n = ty + p * 8;
    o[(size_t)(n0 + n) * jb.K + k0 + tx] = __float2bfloat16(s[tx][n]);
  }
}

// ---------------------------------------------------------------------------
// R17 gemm_gat: layer GEMM with IN-KERNEL edge logits; xr never hits HBM.
// Mechanism (from R0-R4 counters): the gather phase (~240 of 437 µs) is
// latency-bound and insensitive to access-pattern tuning; the only wins come
// from traffic never emitted. The alpha kernels (~110 µs) exist solely to
// re-read xcat and reduce it to 112 scalars/(g,h) — so compute those scalars
// HERE, while xl/xr are still on-chip, and drop the xr half of xcat.
//
// Block (bm, bn): bn = h*4+cg covers head h, channel-group cg (64 ch).
//   cols 0-63  = xl channels [cg*64, +64)  (B rows from Wl)
//   cols 64-127= xr channels [cg*64, +64)  (B rows from Wr)
// M-tile = 120 rows = 4 WHOLE graphs (+8 pad rows, outputs discarded) so every
// edge's src/dst rows are in-block. Epilogue: bias + bf16 round -> LDS (union
// over the K-loop staging buffers; LDS stays 32 KB); xl half also stored to
// xlcat (write traffic halves); then 28-pass edge pass computes the 64-channel
// partial logit and atomicAdds into zeroed logitsG (4 contenders per logit).
// bf16 rounding points identical to the R0 path (logits read back bf16 values).
// ---------------------------------------------------------------------------
__global__ __launch_bounds__(256)
void gemm_gat(const __hip_bfloat16* __restrict__ A,      // hnb [NTOT][256]
              const __hip_bfloat16* __restrict__ Wl,     // [H*256][256] bf16 (transposed)
              const __hip_bfloat16* __restrict__ Wr,
              const float* __restrict__ blv, const float* __restrict__ brv,
              const float* __restrict__ att,             // [H][256]
              __hip_bfloat16* __restrict__ xlcat,        // [NTOT][H*256]
              float* __restrict__ logitsG,               // [B][H][E_TOT], pre-zeroed
              const int* __restrict__ meta, int H)
{
  union GatSmem {
    struct { short a[2][4096]; short b[2][4096]; } st;   // 32 KB staging
    short xlr[128 * 128];                                 // 32 KB epilogue
  };
  __shared__ GatSmem sm;
  __shared__ int ssrc[E_TOT], sdst[E_TOT];

  const int tid = threadIdx.x;
  const int lane = tid & 63, wave = tid >> 6;
  const int wx = wave & 1, wy = wave >> 1;
  const int bm = blockIdx.x, bn = blockIdx.y;
  const int mrow = lane & 15, quad = lane >> 4;
  const int hh = bn >> 2, cg = bn & 3;
  const int K = HID;

  if (tid < E_TOT) { ssrc[tid] = meta[META_SRC + tid]; sdst[tid] = meta[META_DST + tid]; }

  const int r0 = tid >> 2, kc0 = (tid & 3) * 8;
  const int Ra = bm * 120 + r0;                              // rows 0..63: real
  const int Rb = bm * 120 + (r0 + 64 > 119 ? 119 : r0 + 64); // clamp pad rows
  const __hip_bfloat16* Ag0 = A + (size_t)Ra * K + kc0;
  const __hip_bfloat16* Ag1 = A + (size_t)Rb * K + kc0;
  const int brow = hh * 256 + cg * 64 + r0;                  // r0 in 0..63
  const __hip_bfloat16* Bg0 = Wl + (size_t)brow * K + kc0;   // cols 0-63  = xl
  const __hip_bfloat16* Bg1 = Wr + (size_t)brow * K + kc0;   // cols 64-127= xr

  f32x4 acc[4][4];
  #pragma unroll
  for (int i = 0; i < 4; i++)
    #pragma unroll
    for (int j = 0; j < 4; j++)
      acc[i][j] = (f32x4){0.f, 0.f, 0.f, 0.f};

  for (int kt = 0; kt < K; kt += 64) {
    __syncthreads();
    #pragma unroll
    for (int s = 0; s < 2; s++) {
      gload_lds16(Ag0 + kt + s * 32, &sm.st.a[s][tid * 8]);
      gload_lds16(Ag1 + kt + s * 32, &sm.st.a[s][2048 + tid * 8]);
      gload_lds16(Bg0 + kt + s * 32, &sm.st.b[s][tid * 8]);
      gload_lds16(Bg1 + kt + s * 32, &sm.st.b[s][2048 + tid * 8]);
    }
    __syncthreads();

    #pragma unroll
    for (int s = 0; s < 2; s++) {
      bf16x8 af[4], bfr[4];
      #pragma unroll
      for (int i = 0; i < 4; i++) {
        af[i]  = *(const bf16x8*)&sm.st.a[s][(wy * 64 + i * 16 + mrow) * 32 + quad * 8];
        bfr[i] = *(const bf16x8*)&sm.st.b[s][(wx * 64 + i * 16 + mrow) * 32 + quad * 8];
      }
      #pragma unroll
      for (int i = 0; i < 4; i++)
        #pragma unroll
        for (int j = 0; j < 4; j++)
          acc[i][j] = __builtin_amdgcn_mfma_f32_16x16x32_bf16(af[i], bfr[j], acc[i][j], 0, 0, 0);
    }
  }

  __syncthreads();   // K-loop LDS reads done; safe to repurpose union as xlr

  // ---- epilogue: bias + bf16 -> LDS; xl half -> global ----
  const float* bb = wx ? brv : blv;
  float bv[4];
  #pragma unroll
  for (int j = 0; j < 4; j++) bv[j] = bb[hh * 256 + cg * 64 + j * 16 + mrow];
  #pragma unroll
  for (int i = 0; i < 4; i++) {
    #pragma unroll
    for (int r = 0; r < 4; r++) {
      int lrow = wy * 64 + i * 16 + quad * 4 + r;
      size_t grow = (size_t)bm * 120 + lrow;
      #pragma unroll
      for (int j = 0; j < 4; j++) {
        int ch = j * 16 + mrow;                 // 0..63 within half
        short hv = f2bf_bits(acc[i][j][r] + bv[j]);
        sm.xlr[lrow * 128 + wx * 64 + ch] = hv;
        if (!wx && lrow < 120)
          ((short*)xlcat)[grow * (size_t)(H * HID) + hh * HID + cg * 64 + ch] = hv;
      }
    }
  }
  __syncthreads();

  // ---- logit partials: 448 edges (4 graphs x 112), 64 channels each ----
  const int slot = tid >> 4, chsub = tid & 15;   // 16 edges/pass, 16 lanes/edge
  float av[4];
  #pragma unroll
  for (int i = 0; i < 4; i++) av[i] = att[hh * HID + cg * 64 + chsub * 4 + i];
  for (int p = 0; p < 28; p++) {
    int eidx = p * 16 + slot;
    int gl = eidx / E_TOT, e = eidx - gl * E_TOT;
    int rs = gl * 30 + ssrc[e], rd = gl * 30 + sdst[e];
    bf16x4 xlv = *(const bf16x4*)&sm.xlr[rs * 128 + chsub * 4];
    bf16x4 xrv = *(const bf16x4*)&sm.xlr[rd * 128 + 64 + chsub * 4];
    float sum = 0.f;
    #pragma unroll
    for (int i = 0; i < 4; i++) {
      float s = b2f(xlv[i]) + b2f(xrv[i]);
      s = s > 0.f ? s : 0.2f * s;
      sum += s * av[i];
    }
    sum += __shfl_xor(sum, 1); sum += __shfl_xor(sum, 2);
    sum += __shfl_xor(sum, 4); sum += __shfl_xor(sum, 8);
    if (chsub == 0)
      atomicAdd(&logitsG[((size_t)(bm * 4 + gl) * H + hh) * E_TOT + e], sum);
  }
}

// ---------------------------------------------------------------------------
// R17 gat_softmax: tiny per-(graph,head) softmax over 112 pre-computed logits.
// Exact semantics of the proven R0 gat_alpha tail (segment max, exp, atomicAdd
// denom, normalize); replaces the ~110 µs of alpha kernels that re-read xcat.
// ---------------------------------------------------------------------------
__global__ __launch_bounds__(128)
void gat_softmax(const float* __restrict__ logitsG, float* __restrict__ alphaG,
                 const int* __restrict__ meta, int H)
{
  __shared__ float slog[E_TOT], smax[N_NODES], sden[N_NODES];
  __shared__ int sdst[E_TOT], scnt[N_NODES], slist[N_NODES * MAXIN];
  const int tid = threadIdx.x;
  const int g = blockIdx.x, hh = blockIdx.y;
  const size_t base = ((size_t)g * H + hh) * E_TOT;
  if (tid < E_TOT) { slog[tid] = logitsG[base + tid]; sdst[tid] = meta[META_DST + tid]; }
  if (tid < N_NODES) { scnt[tid] = meta[META_CNT + tid]; sden[tid] = 0.f; }
  for (int i = tid; i < N_NODES * MAXIN; i += 128) slist[i] = meta[META_LIST + i];
  __syncthreads();
  if (tid < N_NODES) {
    int cnt = scnt[tid];
    const int* lst = &slist[tid * MAXIN];
    float m = -1e30f;
    for (int i = 0; i < cnt; i++) m = fmaxf(m, slog[lst[i]]);
    smax[tid] = m;
  }
  __syncthreads();
  if (tid < E_TOT) {
    float ex = expf(slog[tid] - smax[sdst[tid]]);
    slog[tid] = ex;
    atomicAdd(&sden[sdst[tid]], ex);
  }
  __syncthreads();
  if (tid < E_TOT) alphaG[base + tid] = slog[tid] / sden[sdst[tid]];
}

// ---------------------------------------------------------------------------
// MFMA GEMM with fp32 A staged via in-register bf16 cast (fused cast): proj.
// (EXACT R0 version.)
// ---------------------------------------------------------------------------
template<int ACT, int OUTBF>
__global__ __launch_bounds__(256)
void gemm_mfma_f32a(const float* __restrict__ A, const __hip_bfloat16* __restrict__ Bt,
                    const float* __restrict__ bias, void* __restrict__ Cv,
                    int M, int K, int N)
{
  __shared__ __hip_bfloat16 sA[128 * 32];
  __shared__ __hip_bfloat16 sB[128 * 32];
  const int tid = threadIdx.x;
  const int lane = tid & 63;
  const int wave = tid >> 6;
  const int wx = wave & 1, wy = wave >> 1;
  const int bm = blockIdx.x, bn = blockIdx.y;
  const int mrow = lane & 15, quad = lane >> 4;

  const int r0 = tid >> 2, kc0 = (tid & 3) * 8;
  const float* Ag0 = A + (size_t)(bm * 128 + r0) * K + kc0;
  const float* Ag1 = A + (size_t)(bm * 128 + r0 + 64) * K + kc0;
  const __hip_bfloat16* Bg0 = Bt + (size_t)(bn * 128 + r0) * K + kc0;
  const __hip_bfloat16* Bg1 = Bt + (size_t)(bn * 128 + r0 + 64) * K + kc0;

  f32x4 acc[4][4];
  #pragma unroll
  for (int i = 0; i < 4; i++)
    #pragma unroll
    for (int j = 0; j < 4; j++)
      acc[i][j] = (f32x4){0.f, 0.f, 0.f, 0.f};

  for (int kt = 0; kt < K; kt += 32) {
    float4 a00 = *(const float4*)(Ag0 + kt);
    float4 a01 = *(const float4*)(Ag0 + kt + 4);
    float4 a10 = *(const float4*)(Ag1 + kt);
    float4 a11 = *(const float4*)(Ag1 + kt + 4);
    __syncthreads();
    {
      __hip_bfloat16 t[8];
      t[0] = __float2bfloat16(a00.x); t[1] = __float2bfloat16(a00.y);
      t[2] = __float2bfloat16(a00.z); t[3] = __float2bfloat16(a00.w);
      t[4] = __float2bfloat16(a01.x); t[5] = __float2bfloat16(a01.y);
      t[6] = __float2bfloat16(a01.z); t[7] = __float2bfloat16(a01.w);
      *(bf16x8*)&sA[tid * 8] = *(bf16x8*)t;
      t[0] = __float2bfloat16(a10.x); t[1] = __float2bfloat16(a10.y);
      t[2] = __float2bfloat16(a10.z); t[3] = __float2bfloat16(a10.w);
      t[4] = __float2bfloat16(a11.x); t[5] = __float2bfloat16(a11.y);
      t[6] = __float2bfloat16(a11.z); t[7] = __float2bfloat16(a11.w);
      *(bf16x8*)&sA[2048 + tid * 8] = *(bf16x8*)t;
    }
    gload_lds16(Bg0 + kt, &sB[tid * 8]);
    gload_lds16(Bg1 + kt, &sB[2048 + tid * 8]);
    __syncthreads();

    bf16x8 af[4], bfr[4];
    #pragma unroll
    for (int i = 0; i < 4; i++) {
      af[i]  = *(const bf16x8*)&sA[(wy * 64 + i * 16 + mrow) * 32 + quad * 8];
      bfr[i] = *(const bf16x8*)&sB[(wx * 64 + i * 16 + mrow) * 32 + quad * 8];
    }
    #pragma unroll
    for (int i = 0; i < 4; i++)
      #pragma unroll
      for (int j = 0; j < 4; j++)
        acc[i][j] = __builtin_amdgcn_mfma_f32_16x16x32_bf16(af[i], bfr[j], acc[i][j], 0, 0, 0);
  }

  #pragma unroll
  for (int i = 0; i < 4; i++) {
    #pragma unroll
    for (int r = 0; r < 4; r++) {
      size_t row = (size_t)bm * 128 + wy * 64 + i * 16 + quad * 4 + r;
      #pragma unroll
      for (int j = 0; j < 4; j++) {
        int col = bn * 128 + wx * 64 + j * 16 + mrow;
        float v = acc[i][j][r] + bias[col];
        if (ACT) v = v > 0.f ? v : 0.01f * v;
        if (OUTBF) ((__hip_bfloat16*)Cv)[row * N + col] = __float2bfloat16(v);
        else       ((float*)Cv)[row * N + col] = v;
      }
    }
  }
}

// ---------------------------------------------------------------------------
// MFMA GEMM with fused edge-pair gather from fp32 h (EXACT R0 version).
// ---------------------------------------------------------------------------
__global__ __launch_bounds__(256)
void gemm_mfma_pair(const float* __restrict__ h, const int* __restrict__ pairs,
                    const __hip_bfloat16* __restrict__ Bt, const float* __restrict__ bias,
                    __hip_bfloat16* __restrict__ C, int N)
{
  const int K = 512;
  __shared__ __hip_bfloat16 sA[128 * 32];
  __shared__ __hip_bfloat16 sB[128 * 32];
  const int tid = threadIdx.x;
  const int lane = tid & 63;
  const int wave = tid >> 6;
  const int wx = wave & 1, wy = wave >> 1;
  const int bm = blockIdx.x, bn = blockIdx.y;
  const int mrow = lane & 15, quad = lane >> 4;

  const float* pu[2]; const float* pv[2]; int sub[2];
  #pragma unroll
  for (int cI = 0; cI < 2; cI++) {
    int c = tid + cI * 256;
    int r0 = c >> 2; sub[cI] = (c & 3) * 8;
    int R = bm * 128 + r0;
    int b = R / N_EH, p = R - b * N_EH;
    int u = pairs[p * 2], v = pairs[p * 2 + 1];
    pu[cI] = h + ((size_t)b * N_NODES + u) * HID;
    pv[cI] = h + ((size_t)b * N_NODES + v) * HID;
  }

  const int r0 = tid >> 2, kc0 = (tid & 3) * 8;
  const __hip_bfloat16* Bg0 = Bt + (size_t)(bn * 128 + r0) * K + kc0;
  const __hip_bfloat16* Bg1 = Bt + (size_t)(bn * 128 + r0 + 64) * K + kc0;

  f32x4 acc[4][4];
  #pragma unroll
  for (int i = 0; i < 4; i++)
    #pragma unroll
    for (int j = 0; j < 4; j++)
      acc[i][j] = (f32x4){0.f, 0.f, 0.f, 0.f};

  for (int kt = 0; kt < 512; kt += 32) {
    float4 av[2][2];
    #pragma unroll
    for (int cI = 0; cI < 2; cI++) {
      const float* src = (kt < 256 ? pu[cI] + kt : pv[cI] + kt - 256) + sub[cI];
      av[cI][0] = *(const float4*)src;
      av[cI][1] = *(const float4*)(src + 4);
    }
    __syncthreads();
    #pragma unroll
    for (int cI = 0; cI < 2; cI++) {
      __hip_bfloat16 t[8];
      t[0] = __float2bfloat16(av[cI][0].x); t[1] = __float2bfloat16(av[cI][0].y);
      t[2] = __float2bfloat16(av[cI][0].z); t[3] = __float2bfloat16(av[cI][0].w);
      t[4] = __float2bfloat16(av[cI][1].x); t[5] = __float2bfloat16(av[cI][1].y);
      t[6] = __float2bfloat16(av[cI][1].z); t[7] = __float2bfloat16(av[cI][1].w);
      *(bf16x8*)&sA[(tid + cI * 256) * 8] = *(bf16x8*)t;
    }
    gload_lds16(Bg0 + kt, &sB[tid * 8]);
    gload_lds16(Bg1 + kt, &sB[2048 + tid * 8]);
    __syncthreads();

    bf16x8 af[4], bfr[4];
    #pragma unroll
    for (int i = 0; i < 4; i++) {
      af[i]  = *(const bf16x8*)&sA[(wy * 64 + i * 16 + mrow) * 32 + quad * 8];
      bfr[i] = *(const bf16x8*)&sB[(wx * 64 + i * 16 + mrow) * 32 + quad * 8];
    }
    #pragma unroll
    for (int i = 0; i < 4; i++)
      #pragma unroll
      for (int j = 0; j < 4; j++)
        acc[i][j] = __builtin_amdgcn_mfma_f32_16x16x32_bf16(af[i], bfr[j], acc[i][j], 0, 0, 0);
  }

  #pragma unroll
  for (int i = 0; i < 4; i++) {
    #pragma unroll
    for (int r = 0; r < 4; r++) {
      size_t row = (size_t)bm * 128 + wy * 64 + i * 16 + quad * 4 + r;
      #pragma unroll
      for (int j = 0; j < 4; j++) {
        int col = bn * 128 + wx * 64 + j * 16 + mrow;
        float v = acc[i][j][r] + bias[col];
        v = v > 0.f ? v : 0.01f * v;
        C[row * N + col] = __float2bfloat16(v);
      }
    }
  }
}

// ---------------------------------------------------------------------------
// Fused MLP tail (R11 — proven win; EXACT R0 version).
// ---------------------------------------------------------------------------
#define O2P 136
__global__ __launch_bounds__(256)
void mlp_tail(const __hip_bfloat16* __restrict__ o1, const __hip_bfloat16* __restrict__ W1t,
              const float* __restrict__ b1, const __hip_bfloat16* __restrict__ W2t,
              const float* __restrict__ b2, const float* __restrict__ w3,
              const float* __restrict__ b3, float* __restrict__ out)
{
  __shared__ __hip_bfloat16 sA[128 * 32];
  __shared__ __hip_bfloat16 sB[128 * 32];
  __shared__ __hip_bfloat16 sO2[128 * O2P];
  __shared__ float spart[2][128];
  const int tid = threadIdx.x;
  const int lane = tid & 63;
  const int wave = tid >> 6;
  const int wx = wave & 1, wy = wave >> 1;
  const int bm = blockIdx.x;
  const int mrow = lane & 15, quad = lane >> 4;
  const int r0 = tid >> 2, kc0 = (tid & 3) * 8;

  const __hip_bfloat16* Ag0 = o1 + (size_t)(bm * 128 + r0) * 256 + kc0;
  const __hip_bfloat16* Ag1 = o1 + (size_t)(bm * 128 + r0 + 64) * 256 + kc0;
  const __hip_bfloat16* Bg0 = W1t + (size_t)r0 * 256 + kc0;
  const __hip_bfloat16* Bg1 = W1t + (size_t)(r0 + 64) * 256 + kc0;

  f32x4 acc[4][4];
  #pragma unroll
  for (int i = 0; i < 4; i++)
    #pragma unroll
    for (int j = 0; j < 4; j++)
      acc[i][j] = (f32x4){0.f, 0.f, 0.f, 0.f};

  for (int kt = 0; kt < 256; kt += 32) {
    __syncthreads();
    gload_lds16(Ag0 + kt, &sA[tid * 8]);
    gload_lds16(Ag1 + kt, &sA[2048 + tid * 8]);
    gload_lds16(Bg0 + kt, &sB[tid * 8]);
    gload_lds16(Bg1 + kt, &sB[2048 + tid * 8]);
    __syncthreads();

    bf16x8 af[4], bfr[4];
    #pragma unroll
    for (int i = 0; i < 4; i++) {
      af[i]  = *(const bf16x8*)&sA[(wy * 64 + i * 16 + mrow) * 32 + quad * 8];
      bfr[i] = *(const bf16x8*)&sB[(wx * 64 + i * 16 + mrow) * 32 + quad * 8];
    }
    #pragma unroll
    for (int i = 0; i < 4; i++)
      #pragma unroll
      for (int j = 0; j < 4; j++)
        acc[i][j] = __builtin_amdgcn_mfma_f32_16x16x32_bf16(af[i], bfr[j], acc[i][j], 0, 0, 0);
  }

  __syncthreads();
  #pragma unroll
  for (int i = 0; i < 4; i++) {
    #pragma unroll
    for (int r = 0; r < 4; r++) {
      int row = wy * 64 + i * 16 + quad * 4 + r;
      #pragma unroll
      for (int j = 0; j < 4; j++) {
        int col = wx * 64 + j * 16 + mrow;
        float v = acc[i][j][r] + b1[col];
        v = v > 0.f ? v : 0.01f * v;
        sO2[row * O2P + col] = __float2bfloat16(v);
      }
    }
  }

  f32x4 acc2[4][4];
  #pragma unroll
  for (int i = 0; i < 4; i++)
    #pragma unroll
    for (int j = 0; j < 4; j++)
      acc2[i][j] = (f32x4){0.f, 0.f, 0.f, 0.f};

  for (int kt = 0; kt < 128; kt += 32) {
    __syncthreads();
    gload_lds16(W2t + (size_t)r0 * 128 + kt + kc0, &sB[tid * 8]);
    gload_lds16(W2t + (size_t)(r0 + 64) * 128 + kt + kc0, &sB[2048 + tid * 8]);
    __syncthreads();

    bf16x8 af[4], bfr[4];
    #pragma unroll
    for (int i = 0; i < 4; i++) {
      af[i]  = *(const bf16x8*)&sO2[(wy * 64 + i * 16 + mrow) * O2P + kt + quad * 8];
      bfr[i] = *(const bf16x8*)&sB[(wx * 64 + i * 16 + mrow) * 32 + quad * 8];
    }
    #pragma unroll
    for (int i = 0; i < 4; i++)
      #pragma unroll
      for (int j = 0; j < 4; j++)
        acc2[i][j] = __builtin_amdgcn_mfma_f32_16x16x32_bf16(af[i], bfr[j], acc2[i][j], 0, 0, 0);
  }

  float w3v[4], b2v[4];
  #pragma unroll
  for (int j = 0; j < 4; j++) {
    int col = wx * 64 + j * 16 + mrow;
    w3v[j] = w3[col];
    b2v[j] = b2[col];
  }
  #pragma unroll
  for (int i = 0; i < 4; i++) {
    #pragma unroll
    for (int r = 0; r < 4; r++) {
      float s = 0.f;
      #pragma unroll
      for (int j = 0; j < 4; j++) {
        float v = acc2[i][j][r] + b2v[j];
        v = v > 0.f ? v : 0.01f * v;
        s += v * w3v[j];
      }
      #pragma unroll
      for (int off = 8; off; off >>= 1) s += __shfl_xor(s, off);
      if (mrow == 0) {
        int row = wy * 64 + i * 16 + quad * 4 + r;
        spart[wx][row] = s;
      }
    }
  }
  __syncthreads();
  if (tid < 128)
    out[(size_t)bm * 128 + tid] = spart[0][tid] + spart[1][tid] + b3[0];
}

// ---------------------------------------------------------------------------
// LayerNorm over HID=256; one wave per row; writes bf16. (Used once, after proj.)
// ---------------------------------------------------------------------------
__global__ __launch_bounds__(256)
void layernorm(const float* __restrict__ h, const float* __restrict__ g,
               const float* __restrict__ b, __hip_bfloat16* __restrict__ hn)
{
  const int wv = threadIdx.x >> 6, lane = threadIdx.x & 63;
  const size_t row = (size_t)blockIdx.x * 4 + wv;
  const float* hr = h + row * HID;
  float v[4];
  float sum = 0.f;
  #pragma unroll
  for (int j = 0; j < 4; j++) { v[j] = hr[lane + 64 * j]; sum += v[j]; }
  #pragma unroll
  for (int off = 32; off; off >>= 1) sum += __shfl_xor(sum, off);
  float mu = sum * (1.f / 256.f);
  float vs = 0.f;
  #pragma unroll
  for (int j = 0; j < 4; j++) { float d = v[j] - mu; vs += d * d; }
  #pragma unroll
  for (int off = 32; off; off >>= 1) vs += __shfl_xor(vs, off);
  float rs = rsqrtf(vs * (1.f / 256.f) + 1e-5f);
  __hip_bfloat16* outr = hn + row * HID;
  #pragma unroll
  for (int j = 0; j < 4; j++) {
    int c = lane + 64 * j;
    outr[c] = __float2bfloat16((v[j] - mu) * rs * g[c] + b[c]);
  }
}

// ---------------------------------------------------------------------------
// GATv2 aggregation + h update (+ optional fused next-layer LayerNorm).
// EXACT R0 gat_agg except xcat is now xl-only: row stride S = H*HID (was
// 2*H*HID), head hh slice at offset hh*HID (unchanged formula).
// One block per graph; thread = (channel-quad c4, node-group ng).
// ---------------------------------------------------------------------------
template<int DO_LN>
__global__ __launch_bounds__(256, 4)
void gat_agg(const __hip_bfloat16* __restrict__ xcat, const float* __restrict__ alphaG,
             const float* __restrict__ bias, float* __restrict__ h,
             const float* __restrict__ lnG, const float* __restrict__ lnB,
             __hip_bfloat16* __restrict__ hn, const int* __restrict__ meta, int H)
{
  __shared__ __hip_bfloat16 sxl[2][N_NODES * HID];   // 2 x 15 KB, head double-buffer
  __shared__ float salpha[2][E_TOT];
  __shared__ int ssrc[E_TOT], scnt[N_NODES], slist[N_NODES * MAXIN];

  const int tid = threadIdx.x;
  const int g = blockIdx.x;
  const size_t nodebase = (size_t)g * N_NODES;
  const int S = H * HID;                    // xl-only stride (R17)
  const int c4 = tid & 63;
  const int ng = tid >> 6;

  if (tid < E_TOT) ssrc[tid] = meta[META_SRC + tid];
  if (tid < N_NODES) scnt[tid] = meta[META_CNT + tid];
  for (int i = tid; i < N_NODES * MAXIN; i += 256) slist[i] = meta[META_LIST + i];

  float4 hres[8];
  #pragma unroll
  for (int ki = 0; ki < 8; ki++) {
    int k = ng + ki * 4;
    if (k < N_NODES) hres[ki] = *(const float4*)&h[(nodebase + k) * HID + c4 * 4];
  }

  {
    int i = tid;
    #pragma unroll
    for (int p = 0; p < 4; p++, i += 256) {
      if (i < N_NODES * HID / 8) {
        int node = i >> 5, c = (i & 31) * 8;
        gload_lds16(&xcat[(nodebase + node) * S + 0 * HID + c], &sxl[0][(size_t)i * 8]);
      }
    }
    if (tid < E_TOT) salpha[0][tid] = alphaG[((size_t)g * H + 0) * E_TOT + tid];
  }

  float acc[8][4];
  #pragma unroll
  for (int ki = 0; ki < 8; ki++)
    #pragma unroll
    for (int j = 0; j < 4; j++) acc[ki][j] = 0.f;

  for (int hh = 0; hh < H; hh++) {
    const int buf = hh & 1;
    __syncthreads();
    if (hh + 1 < H) {
      const int nb = buf ^ 1;
      int i = tid;
      #pragma unroll
      for (int p = 0; p < 4; p++, i += 256) {
        if (i < N_NODES * HID / 8) {
          int node = i >> 5, c = (i & 31) * 8;
          gload_lds16(&xcat[(nodebase + node) * S + (hh + 1) * HID + c], &sxl[nb][(size_t)i * 8]);
        }
      }
      if (tid < E_TOT) salpha[nb][tid] = alphaG[((size_t)g * H + hh + 1) * E_TOT + tid];
    }
    #pragma unroll
    for (int ki = 0; ki < 8; ki++) {
      int k = ng + ki * 4;
      if (k < N_NODES) {
        int cnt = scnt[k];
        const int* lst = &slist[k * MAXIN];
        for (int i = 0; i < cnt; i++) {
          int e = lst[i];                       // wave-uniform broadcast reads
          float al = salpha[buf][e];
          bf16x4 v = *(const bf16x4*)&sxl[buf][ssrc[e] * HID + c4 * 4];
          acc[ki][0] += al * b2f(v[0]);
          acc[ki][1] += al * b2f(v[1]);
          acc[ki][2] += al * b2f(v[2]);
          acc[ki][3] += al * b2f(v[3]);
        }
      }
    }
  }

  const float invH = 1.f / (float)H;
  const float4 bs = *(const float4*)&bias[c4 * 4];
  float4 gv, bv;
  if (DO_LN) {
    gv = *(const float4*)&lnG[c4 * 4];
    bv = *(const float4*)&lnB[c4 * 4];
  }
  #pragma unroll
  for (int ki = 0; ki < 8; ki++) {
    int k = ng + ki * 4;
    if (k < N_NODES) {
      float o0 = acc[ki][0] * invH + bs.x; o0 = o0 > 0.f ? o0 : 0.01f * o0; o0 += hres[ki].x;
      float o1 = acc[ki][1] * invH + bs.y; o1 = o1 > 0.f ? o1 : 0.01f * o1; o1 += hres[ki].y;
      float o2 = acc[ki][2] * invH + bs.z; o2 = o2 > 0.f ? o2 : 0.01f * o2; o2 += hres[ki].z;
      float o3 = acc[ki][3] * invH + bs.w; o3 = o3 > 0.f ? o3 : 0.01f * o3; o3 += hres[ki].w;
      float4 o4 = {o0, o1, o2, o3};
      *(float4*)&h[(nodebase + k) * HID + c4 * 4] = o4;
      if (DO_LN) {
        float sum = o0 + o1 + o2 + o3;
        #pragma unroll
        for (int off = 32; off; off >>= 1) sum += __shfl_xor(sum, off);
        float mu = sum * (1.f / 256.f);
        float d0 = o0 - mu, d1 = o1 - mu, d2 = o2 - mu, d3 = o3 - mu;
        float vs = d0 * d0 + d1 * d1 + d2 * d2 + d3 * d3;
        #pragma unroll
        for (int off = 32; off; off >>= 1) vs += __shfl_xor(vs, off);
        float rs = rsqrtf(vs * (1.f / 256.f) + 1e-5f);
        __hip_bfloat16 t[4];
        t[0] = __float2bfloat16(d0 * rs * gv.x + bv.x);
        t[1] = __float2bfloat16(d1 * rs * gv.y + bv.y);
        t[2] = __float2bfloat16(d2 * rs * gv.z + bv.z);
        t[3] = __float2bfloat16(d3 * rs * gv.w + bv.w);
        *(bf16x4*)&hn[(nodebase + k) * HID + c4 * 4] = *(bf16x4*)t;
      }
    }
  }
}

// ---------------------------------------------------------------------------
extern "C" void kernel_launch(void* const* d_in, const int* in_sizes, int n_in,
                              void* d_out, int out_size, void* d_ws, size_t ws_size,
                              hipStream_t stream) {
  const float* x     = (const float*)d_in[0];
  const int*   ei    = (const int*)d_in[1];
  const int*   pairs = (const int*)d_in[2];
  const float* bp    = (const float*)d_in[4];
  const float *lng[3], *lnb[3], *bl[3], *br[3], *att[3], *bias[3];
  const float *WlF[3], *WrF[3];
  for (int l = 0; l < 3; l++) {
    int base = 5 + l * 8;
    lng[l]  = (const float*)d_in[base + 0];
    lnb[l]  = (const float*)d_in[base + 1];
    WlF[l]  = (const float*)d_in[base + 2];
    bl[l]   = (const float*)d_in[base + 3];
    WrF[l]  = (const float*)d_in[base + 4];
    br[l]   = (const float*)d_in[base + 5];
    att[l]  = (const float*)d_in[base + 6];
    bias[l] = (const float*)d_in[base + 7];
  }
  const float* WmF[4] = {(const float*)d_in[29], (const float*)d_in[31],
                         (const float*)d_in[33], (const float*)d_in[35]};
  const float* bm[4] = {(const float*)d_in[30], (const float*)d_in[32],
                        (const float*)d_in[34], (const float*)d_in[36]};

  // workspace layout (float offsets)
  float* ws  = (float*)d_ws;
  float* h   = ws;                                           // [0, 7864320)
  __hip_bfloat16* hnb = (__hip_bfloat16*)(ws + 7864320);     // 3,932,160 bf
  __hip_bfloat16* xlcat = (__hip_bfloat16*)(ws + 11796480);  // xl-only: <= 23,592,960 bf
  float* logits0 = ws + 30000000;                            // 344,064 f (l=0)
  float* logits1 = logits0 + 344064;                         // 229,376 f (l=1)
  float* logits2 = logits1 + 229376;                         // 114,688 f (l=2)
  float* alphaG = ws + 35389440;                             // 344,064 f
  __hip_bfloat16* wbuf = (__hip_bfloat16*)(ws + 35733504);   // 999,424 bf
  int*   meta = (int*)(ws + 36233216);
  __hip_bfloat16* o1b = (__hip_bfloat16*)xlcat;              // pair out (xlcat dead then)
  float* out = (float*)d_out;

  // zero the logit accumulators (gemm_gat atomically adds into them)
  hipMemsetAsync(logits0, 0, (344064 + 229376 + 114688) * sizeof(float), stream);

  // bf16 transposed weight offsets (layouts unchanged from R0)
  const int oWp = 0, oWl0 = 32768, oWr0 = 229376, oWl1 = 425984, oWr1 = 557056;
  const int oWl2 = 688128, oWr2 = 753664, oWm0 = 819200, oWm1 = 950272, oWm2 = 983040;

  WtArgs wa;
  wa.j[0] = {(const float*)d_in[3], 128, 256,   0, oWp };
  wa.j[1] = {WlF[0],              256, 768,  32, oWl0};
  wa.j[2] = {WrF[0],              256, 768, 224, oWr0};
  wa.j[3] = {WlF[1],              256, 512, 416, oWl1};
  wa.j[4] = {WrF[1],              256, 512, 544, oWr1};
  wa.j[5] = {WlF[2],              256, 256, 672, oWl2};
  wa.j[6] = {WrF[2],              256, 256, 736, oWr2};
  wa.j[7] = {WmF[0],              512, 256, 800, oWm0};
  wa.j[8] = {WmF[1],              256, 128, 928, oWm1};
  wa.j[9] = {WmF[2],              128, 128, 960, oWm2};
  transpose_weights<<<977, 256, 0, stream>>>(wa, wbuf, ei, meta);  // block 976 = build_graph

  // h = x @ Wp + bp   (fp32 A staged with fused bf16 cast; fp32 out)
  gemm_mfma_f32a<0, 0><<<dim3(NTOT / 128, 2), 256, 0, stream>>>(x, wbuf + oWp, bp, h,
                                                                NTOT, 128, 256);

  layernorm<<<NTOT / 4, 256, 0, stream>>>(h, lng[0], lnb[0], hnb);

  const int Hs[3] = {3, 2, 1};
  const int oWl[3] = {oWl0, oWl1, oWl2};
  const int oWr[3] = {oWr0, oWr1, oWr2};
  float* logitsL[3] = {logits0, logits1, logits2};
  for (int l = 0; l < 3; l++) {
    int H = Hs[l];
    gemm_gat<<<dim3(NTOT / 120, H * 4), 256, 0, stream>>>(
        hnb, wbuf + oWl[l], wbuf + oWr[l], bl[l], br[l], att[l],
        xlcat, logitsL[l], meta, H);
    gat_softmax<<<dim3(B_GRAPH, H), 128, 0, stream>>>(logitsL[l], alphaG, meta, H);
    if (l < 2)
      gat_agg<1><<<B_GRAPH, 256, 0, stream>>>(xlcat, alphaG, bias[l], h,
                                              lng[l + 1], lnb[l + 1], hnb, meta, H);
    else
      gat_agg<0><<<B_GRAPH, 256, 0, stream>>>(xlcat, alphaG, bias[l], h,
                                              nullptr, nullptr, nullptr, meta, H);
  }

  gemm_mfma_pair<<<dim3(M_MLP / 128, 2), 256, 0, stream>>>(h, pairs, wbuf + oWm0, bm[0], o1b, 256);
  mlp_tail<<<M_MLP / 128, 256, 0, stream>>>(o1b, wbuf + oWm1, bm[1], wbuf + oWm2, bm[2],
                                            WmF[3], bm[3], out);
}

// Round 6
// 449.400 us; speedup vs baseline: 1.1964x; 1.0234x over previous
//
#include <hip/hip_runtime.h>
#include <hip/hip_bf16.h>
#include <math.h>

// Problem constants
#define N_NODES 30
#define E_BASE  82
#define E_TOT   112         // 82 edges + 30 self loops
#define B_GRAPH 1024
#define HID     256
#define NTOT    (B_GRAPH * N_NODES)   // 30720
#define MAXIN   32
#define N_EH    41
#define M_MLP   (B_GRAPH * N_EH)      // 41984

#define META_SRC  0
#define META_DST  E_TOT
#define META_CNT  (2 * E_TOT)
#define META_LIST 256
#define META_INTS 1216

typedef __attribute__((ext_vector_type(8))) short bf16x8;
typedef __attribute__((ext_vector_type(4))) short bf16x4;
typedef __attribute__((ext_vector_type(4))) float f32x4;
#define AS3 __attribute__((address_space(3)))
#define AS1 __attribute__((address_space(1)))

__device__ __forceinline__ void gload_lds16(const void* g, void* l) {
  __builtin_amdgcn_global_load_lds((const AS1 void*)g, (AS3 void*)l, 16, 0, 0);
}

// Bit-reinterpret ONLY — callers must pass raw bf16 bit patterns (short lanes
// of bf16x4/8 vectors). Never pass __hip_bfloat16 (would value-convert via
// float->short — the R3 NaN bug).
__device__ __forceinline__ float b2f(short s) {
  union { unsigned u; float f; } x;
  x.u = ((unsigned)(unsigned short)s) << 16;
  return x.f;
}

// float -> bf16 bit pattern (same rounding as __float2bfloat16; raw short out)
__device__ __forceinline__ short f2bf_bits(float f) {
  union { __hip_bfloat16 h; short s; } u;
  u.h = __float2bfloat16(f);
  return u.s;
}

// ---------------------------------------------------------------------------
// Transpose-cast all weights fp32 [K,N] -> bf16 [N,K]; block 976 instead
// builds the base-graph CSR (merged to save a launch).
// ---------------------------------------------------------------------------
struct WtJob { const float* in; int K, N, tstart, ooff; };
struct WtArgs { WtJob j[10]; };

__global__ __launch_bounds__(256)
void transpose_weights(WtArgs args, __hip_bfloat16* __restrict__ out,
                       const int* __restrict__ ei, int* __restrict__ meta) {
  int b = blockIdx.x;
  if (b == 976) {   // build_graph job
    __shared__ int cnt[N_NODES];
    int tid = threadIdx.x;
    if (tid < N_NODES) cnt[tid] = 0;
    __syncthreads();
    if (tid < E_TOT) {
      int s, d;
      if (tid < E_BASE) { s = ei[tid]; d = ei[B_GRAPH * E_BASE + tid]; }
      else              { s = tid - E_BASE; d = s; }
      meta[META_SRC + tid] = s;
      meta[META_DST + tid] = d;
      int pos = atomicAdd(&cnt[d], 1);
      if (pos < MAXIN) meta[META_LIST + d * MAXIN + pos] = tid;
    }
    __syncthreads();
    if (tid < N_NODES) meta[META_CNT + tid] = cnt[tid];
    return;
  }
  int ji = 0;
  #pragma unroll
  for (int i = 1; i < 10; i++) if (b >= args.j[i].tstart) ji = i;
  WtJob jb = args.j[ji];
  int t = b - jb.tstart;
  int ntn = jb.N >> 5;
  int tk = t / ntn, tn = t - tk * ntn;
  int k0 = tk * 32, n0 = tn * 32;
  __shared__ float s[32][33];
  int tx = threadIdx.x & 31, ty = threadIdx.x >> 5;
  #pragma unroll
  for (int p = 0; p < 4; p++)
    s[ty + p * 8][tx] = jb.in[(size_t)(k0 + ty + p * 8) * jb.N + n0 + tx];
  __syncthreads();
  __hip_bfloat16* o = out + jb.ooff;
  #pragma unroll
  for (int p = 0; p < 4; p++) {
    int n = ty + p * 8;
    o[(size_t)(n0 + n) * jb.K + k0 + tx] = __float2bfloat16(s[tx][n]);
  }
}

// ---------------------------------------------------------------------------
// R17/R18 gemm_gat: layer GEMM with IN-KERNEL edge logits; xr never hits HBM.
// R18 fixes the two R5-measured pathologies (VALUBusy 50%, 6.08M LDS bank
// conflicts): (1) epilogue writes bf16 to LDS only; the xl half is then stored
// to global COOPERATIVELY with bf16x8 16B chunks (was: 64 scalar 2B stores per
// thread); (2) xlr row stride padded 128->132 shorts (264B = 66 words) so the
// logit pass's 4 concurrent edge-rows land on different bank sets.
//
// Block (bm, bn): bn = h*4+cg covers head h, channel-group cg (64 ch).
//   cols 0-63  = xl channels [cg*64, +64)  (B rows from Wl)
//   cols 64-127= xr channels [cg*64, +64)  (B rows from Wr)
// M-tile = 120 rows = 4 WHOLE graphs (+8 pad rows, outputs discarded) so every
// edge's src/dst rows are in-block. Then a 28-pass edge pass computes the
// 64-channel partial logit and atomicAdds into zeroed logitsG (4 contenders).
// bf16 rounding points identical to the R0 path (logits read back bf16 values).
// ---------------------------------------------------------------------------
#define XP 132   // padded xlr row stride (shorts)
__global__ __launch_bounds__(256)
void gemm_gat(const __hip_bfloat16* __restrict__ A,      // hnb [NTOT][256]
              const __hip_bfloat16* __restrict__ Wl,     // [H*256][256] bf16 (transposed)
              const __hip_bfloat16* __restrict__ Wr,
              const float* __restrict__ blv, const float* __restrict__ brv,
              const float* __restrict__ att,             // [H][256]
              __hip_bfloat16* __restrict__ xlcat,        // [NTOT][H*256]
              float* __restrict__ logitsG,               // [B][H][E_TOT], pre-zeroed
              const int* __restrict__ meta, int H)
{
  union GatSmem {
    struct { short a[2][4096]; short b[2][4096]; } st;   // 32 KB staging
    short xlr[128 * XP];                                  // 33.8 KB epilogue
  };
  __shared__ GatSmem sm;
  __shared__ int ssrc[E_TOT], sdst[E_TOT];

  const int tid = threadIdx.x;
  const int lane = tid & 63, wave = tid >> 6;
  const int wx = wave & 1, wy = wave >> 1;
  const int bm = blockIdx.x, bn = blockIdx.y;
  const int mrow = lane & 15, quad = lane >> 4;
  const int hh = bn >> 2, cg = bn & 3;
  const int K = HID;

  if (tid < E_TOT) { ssrc[tid] = meta[META_SRC + tid]; sdst[tid] = meta[META_DST + tid]; }

  const int r0 = tid >> 2, kc0 = (tid & 3) * 8;
  const int Ra = bm * 120 + r0;                              // rows 0..63: real
  const int Rb = bm * 120 + (r0 + 64 > 119 ? 119 : r0 + 64); // clamp pad rows
  const __hip_bfloat16* Ag0 = A + (size_t)Ra * K + kc0;
  const __hip_bfloat16* Ag1 = A + (size_t)Rb * K + kc0;
  const int brow = hh * 256 + cg * 64 + r0;                  // r0 in 0..63
  const __hip_bfloat16* Bg0 = Wl + (size_t)brow * K + kc0;   // cols 0-63  = xl
  const __hip_bfloat16* Bg1 = Wr + (size_t)brow * K + kc0;   // cols 64-127= xr

  f32x4 acc[4][4];
  #pragma unroll
  for (int i = 0; i < 4; i++)
    #pragma unroll
    for (int j = 0; j < 4; j++)
      acc[i][j] = (f32x4){0.f, 0.f, 0.f, 0.f};

  for (int kt = 0; kt < K; kt += 64) {
    __syncthreads();
    #pragma unroll
    for (int s = 0; s < 2; s++) {
      gload_lds16(Ag0 + kt + s * 32, &sm.st.a[s][tid * 8]);
      gload_lds16(Ag1 + kt + s * 32, &sm.st.a[s][2048 + tid * 8]);
      gload_lds16(Bg0 + kt + s * 32, &sm.st.b[s][tid * 8]);
      gload_lds16(Bg1 + kt + s * 32, &sm.st.b[s][2048 + tid * 8]);
    }
    __syncthreads();

    #pragma unroll
    for (int s = 0; s < 2; s++) {
      bf16x8 af[4], bfr[4];
      #pragma unroll
      for (int i = 0; i < 4; i++) {
        af[i]  = *(const bf16x8*)&sm.st.a[s][(wy * 64 + i * 16 + mrow) * 32 + quad * 8];
        bfr[i] = *(const bf16x8*)&sm.st.b[s][(wx * 64 + i * 16 + mrow) * 32 + quad * 8];
      }
      #pragma unroll
      for (int i = 0; i < 4; i++)
        #pragma unroll
        for (int j = 0; j < 4; j++)
          acc[i][j] = __builtin_amdgcn_mfma_f32_16x16x32_bf16(af[i], bfr[j], acc[i][j], 0, 0, 0);
    }
  }

  __syncthreads();   // K-loop LDS reads done; safe to repurpose union as xlr

  // ---- epilogue: bias + bf16 -> LDS only ----
  const float* bb = wx ? brv : blv;
  float bv[4];
  #pragma unroll
  for (int j = 0; j < 4; j++) bv[j] = bb[hh * 256 + cg * 64 + j * 16 + mrow];
  #pragma unroll
  for (int i = 0; i < 4; i++) {
    #pragma unroll
    for (int r = 0; r < 4; r++) {
      int lrow = wy * 64 + i * 16 + quad * 4 + r;
      #pragma unroll
      for (int j = 0; j < 4; j++) {
        int ch = j * 16 + mrow;                 // 0..63 within half
        sm.xlr[lrow * XP + wx * 64 + ch] = f2bf_bits(acc[i][j][r] + bv[j]);
      }
    }
  }
  __syncthreads();

  // ---- cooperative vectorized store of the xl half (120 rows x 64 ch) ----
  // 960 16B chunks; chunk c -> row c>>3, part c&7. 128B contiguous per row.
  {
    const size_t SROW = (size_t)H * HID;
    #pragma unroll
    for (int p = 0; p < 4; p++) {
      int c = tid + p * 256;
      if (c < 960) {
        int row = c >> 3, part = c & 7;
        bf16x8 v = *(const bf16x8*)&sm.xlr[row * XP + part * 8];
        *(bf16x8*)&((short*)xlcat)[((size_t)bm * 120 + row) * SROW
                                   + hh * HID + cg * 64 + part * 8] = v;
      }
    }
  }

  // ---- logit partials: 448 edges (4 graphs x 112), 64 channels each ----
  const int slot = tid >> 4, chsub = tid & 15;   // 16 edges/pass, 16 lanes/edge
  float av[4];
  #pragma unroll
  for (int i = 0; i < 4; i++) av[i] = att[hh * HID + cg * 64 + chsub * 4 + i];
  for (int p = 0; p < 28; p++) {
    int eidx = p * 16 + slot;
    int gl = eidx / E_TOT, e = eidx - gl * E_TOT;
    int rs = gl * 30 + ssrc[e], rd = gl * 30 + sdst[e];
    bf16x4 xlv = *(const bf16x4*)&sm.xlr[rs * XP + chsub * 4];
    bf16x4 xrv = *(const bf16x4*)&sm.xlr[rd * XP + 64 + chsub * 4];
    float sum = 0.f;
    #pragma unroll
    for (int i = 0; i < 4; i++) {
      float s = b2f(xlv[i]) + b2f(xrv[i]);
      s = s > 0.f ? s : 0.2f * s;
      sum += s * av[i];
    }
    sum += __shfl_xor(sum, 1); sum += __shfl_xor(sum, 2);
    sum += __shfl_xor(sum, 4); sum += __shfl_xor(sum, 8);
    if (chsub == 0)
      atomicAdd(&logitsG[((size_t)(bm * 4 + gl) * H + hh) * E_TOT + e], sum);
  }
}

// ---------------------------------------------------------------------------
// R17 gat_softmax: tiny per-(graph,head) softmax over 112 pre-computed logits.
// Exact semantics of the proven R0 gat_alpha tail (segment max, exp, atomicAdd
// denom, normalize); replaces the ~110 µs of alpha kernels that re-read xcat.
// ---------------------------------------------------------------------------
__global__ __launch_bounds__(128)
void gat_softmax(const float* __restrict__ logitsG, float* __restrict__ alphaG,
                 const int* __restrict__ meta, int H)
{
  __shared__ float slog[E_TOT], smax[N_NODES], sden[N_NODES];
  __shared__ int sdst[E_TOT], scnt[N_NODES], slist[N_NODES * MAXIN];
  const int tid = threadIdx.x;
  const int g = blockIdx.x, hh = blockIdx.y;
  const size_t base = ((size_t)g * H + hh) * E_TOT;
  if (tid < E_TOT) { slog[tid] = logitsG[base + tid]; sdst[tid] = meta[META_DST + tid]; }
  if (tid < N_NODES) { scnt[tid] = meta[META_CNT + tid]; sden[tid] = 0.f; }
  for (int i = tid; i < N_NODES * MAXIN; i += 128) slist[i] = meta[META_LIST + i];
  __syncthreads();
  if (tid < N_NODES) {
    int cnt = scnt[tid];
    const int* lst = &slist[tid * MAXIN];
    float m = -1e30f;
    for (int i = 0; i < cnt; i++) m = fmaxf(m, slog[lst[i]]);
    smax[tid] = m;
  }
  __syncthreads();
  if (tid < E_TOT) {
    float ex = expf(slog[tid] - smax[sdst[tid]]);
    slog[tid] = ex;
    atomicAdd(&sden[sdst[tid]], ex);
  }
  __syncthreads();
  if (tid < E_TOT) alphaG[base + tid] = slog[tid] / sden[sdst[tid]];
}

// ---------------------------------------------------------------------------
// MFMA GEMM with fp32 A staged via in-register bf16 cast (fused cast): proj.
// (EXACT R0 version.)
// ---------------------------------------------------------------------------
template<int ACT, int OUTBF>
__global__ __launch_bounds__(256)
void gemm_mfma_f32a(const float* __restrict__ A, const __hip_bfloat16* __restrict__ Bt,
                    const float* __restrict__ bias, void* __restrict__ Cv,
                    int M, int K, int N)
{
  __shared__ __hip_bfloat16 sA[128 * 32];
  __shared__ __hip_bfloat16 sB[128 * 32];
  const int tid = threadIdx.x;
  const int lane = tid & 63;
  const int wave = tid >> 6;
  const int wx = wave & 1, wy = wave >> 1;
  const int bm = blockIdx.x, bn = blockIdx.y;
  const int mrow = lane & 15, quad = lane >> 4;

  const int r0 = tid >> 2, kc0 = (tid & 3) * 8;
  const float* Ag0 = A + (size_t)(bm * 128 + r0) * K + kc0;
  const float* Ag1 = A + (size_t)(bm * 128 + r0 + 64) * K + kc0;
  const __hip_bfloat16* Bg0 = Bt + (size_t)(bn * 128 + r0) * K + kc0;
  const __hip_bfloat16* Bg1 = Bt + (size_t)(bn * 128 + r0 + 64) * K + kc0;

  f32x4 acc[4][4];
  #pragma unroll
  for (int i = 0; i < 4; i++)
    #pragma unroll
    for (int j = 0; j < 4; j++)
      acc[i][j] = (f32x4){0.f, 0.f, 0.f, 0.f};

  for (int kt = 0; kt < K; kt += 32) {
    float4 a00 = *(const float4*)(Ag0 + kt);
    float4 a01 = *(const float4*)(Ag0 + kt + 4);
    float4 a10 = *(const float4*)(Ag1 + kt);
    float4 a11 = *(const float4*)(Ag1 + kt + 4);
    __syncthreads();
    {
      __hip_bfloat16 t[8];
      t[0] = __float2bfloat16(a00.x); t[1] = __float2bfloat16(a00.y);
      t[2] = __float2bfloat16(a00.z); t[3] = __float2bfloat16(a00.w);
      t[4] = __float2bfloat16(a01.x); t[5] = __float2bfloat16(a01.y);
      t[6] = __float2bfloat16(a01.z); t[7] = __float2bfloat16(a01.w);
      *(bf16x8*)&sA[tid * 8] = *(bf16x8*)t;
      t[0] = __float2bfloat16(a10.x); t[1] = __float2bfloat16(a10.y);
      t[2] = __float2bfloat16(a10.z); t[3] = __float2bfloat16(a10.w);
      t[4] = __float2bfloat16(a11.x); t[5] = __float2bfloat16(a11.y);
      t[6] = __float2bfloat16(a11.z); t[7] = __float2bfloat16(a11.w);
      *(bf16x8*)&sA[2048 + tid * 8] = *(bf16x8*)t;
    }
    gload_lds16(Bg0 + kt, &sB[tid * 8]);
    gload_lds16(Bg1 + kt, &sB[2048 + tid * 8]);
    __syncthreads();

    bf16x8 af[4], bfr[4];
    #pragma unroll
    for (int i = 0; i < 4; i++) {
      af[i]  = *(const bf16x8*)&sA[(wy * 64 + i * 16 + mrow) * 32 + quad * 8];
      bfr[i] = *(const bf16x8*)&sB[(wx * 64 + i * 16 + mrow) * 32 + quad * 8];
    }
    #pragma unroll
    for (int i = 0; i < 4; i++)
      #pragma unroll
      for (int j = 0; j < 4; j++)
        acc[i][j] = __builtin_amdgcn_mfma_f32_16x16x32_bf16(af[i], bfr[j], acc[i][j], 0, 0, 0);
  }

  #pragma unroll
  for (int i = 0; i < 4; i++) {
    #pragma unroll
    for (int r = 0; r < 4; r++) {
      size_t row = (size_t)bm * 128 + wy * 64 + i * 16 + quad * 4 + r;
      #pragma unroll
      for (int j = 0; j < 4; j++) {
        int col = bn * 128 + wx * 64 + j * 16 + mrow;
        float v = acc[i][j][r] + bias[col];
        if (ACT) v = v > 0.f ? v : 0.01f * v;
        if (OUTBF) ((__hip_bfloat16*)Cv)[row * N + col] = __float2bfloat16(v);
        else       ((float*)Cv)[row * N + col] = v;
      }
    }
  }
}

// ---------------------------------------------------------------------------
// MFMA GEMM with fused edge-pair gather from fp32 h (EXACT R0 version).
// ---------------------------------------------------------------------------
__global__ __launch_bounds__(256)
void gemm_mfma_pair(const float* __restrict__ h, const int* __restrict__ pairs,
                    const __hip_bfloat16* __restrict__ Bt, const float* __restrict__ bias,
                    __hip_bfloat16* __restrict__ C, int N)
{
  const int K = 512;
  __shared__ __hip_bfloat16 sA[128 * 32];
  __shared__ __hip_bfloat16 sB[128 * 32];
  const int tid = threadIdx.x;
  const int lane = tid & 63;
  const int wave = tid >> 6;
  const int wx = wave & 1, wy = wave >> 1;
  const int bm = blockIdx.x, bn = blockIdx.y;
  const int mrow = lane & 15, quad = lane >> 4;

  const float* pu[2]; const float* pv[2]; int sub[2];
  #pragma unroll
  for (int cI = 0; cI < 2; cI++) {
    int c = tid + cI * 256;
    int r0 = c >> 2; sub[cI] = (c & 3) * 8;
    int R = bm * 128 + r0;
    int b = R / N_EH, p = R - b * N_EH;
    int u = pairs[p * 2], v = pairs[p * 2 + 1];
    pu[cI] = h + ((size_t)b * N_NODES + u) * HID;
    pv[cI] = h + ((size_t)b * N_NODES + v) * HID;
  }

  const int r0 = tid >> 2, kc0 = (tid & 3) * 8;
  const __hip_bfloat16* Bg0 = Bt + (size_t)(bn * 128 + r0) * K + kc0;
  const __hip_bfloat16* Bg1 = Bt + (size_t)(bn * 128 + r0 + 64) * K + kc0;

  f32x4 acc[4][4];
  #pragma unroll
  for (int i = 0; i < 4; i++)
    #pragma unroll
    for (int j = 0; j < 4; j++)
      acc[i][j] = (f32x4){0.f, 0.f, 0.f, 0.f};

  for (int kt = 0; kt < 512; kt += 32) {
    float4 av[2][2];
    #pragma unroll
    for (int cI = 0; cI < 2; cI++) {
      const float* src = (kt < 256 ? pu[cI] + kt : pv[cI] + kt - 256) + sub[cI];
      av[cI][0] = *(const float4*)src;
      av[cI][1] = *(const float4*)(src + 4);
    }
    __syncthreads();
    #pragma unroll
    for (int cI = 0; cI < 2; cI++) {
      __hip_bfloat16 t[8];
      t[0] = __float2bfloat16(av[cI][0].x); t[1] = __float2bfloat16(av[cI][0].y);
      t[2] = __float2bfloat16(av[cI][0].z); t[3] = __float2bfloat16(av[cI][0].w);
      t[4] = __float2bfloat16(av[cI][1].x); t[5] = __float2bfloat16(av[cI][1].y);
      t[6] = __float2bfloat16(av[cI][1].z); t[7] = __float2bfloat16(av[cI][1].w);
      *(bf16x8*)&sA[(tid + cI * 256) * 8] = *(bf16x8*)t;
    }
    gload_lds16(Bg0 + kt, &sB[tid * 8]);
    gload_lds16(Bg1 + kt, &sB[2048 + tid * 8]);
    __syncthreads();

    bf16x8 af[4], bfr[4];
    #pragma unroll
    for (int i = 0; i < 4; i++) {
      af[i]  = *(const bf16x8*)&sA[(wy * 64 + i * 16 + mrow) * 32 + quad * 8];
      bfr[i] = *(const bf16x8*)&sB[(wx * 64 + i * 16 + mrow) * 32 + quad * 8];
    }
    #pragma unroll
    for (int i = 0; i < 4; i++)
      #pragma unroll
      for (int j = 0; j < 4; j++)
        acc[i][j] = __builtin_amdgcn_mfma_f32_16x16x32_bf16(af[i], bfr[j], acc[i][j], 0, 0, 0);
  }

  #pragma unroll
  for (int i = 0; i < 4; i++) {
    #pragma unroll
    for (int r = 0; r < 4; r++) {
      size_t row = (size_t)bm * 128 + wy * 64 + i * 16 + quad * 4 + r;
      #pragma unroll
      for (int j = 0; j < 4; j++) {
        int col = bn * 128 + wx * 64 + j * 16 + mrow;
        float v = acc[i][j][r] + bias[col];
        v = v > 0.f ? v : 0.01f * v;
        C[row * N + col] = __float2bfloat16(v);
      }
    }
  }
}

// ---------------------------------------------------------------------------
// Fused MLP tail (R11 — proven win; EXACT R0 version).
// ---------------------------------------------------------------------------
#define O2P 136
__global__ __launch_bounds__(256)
void mlp_tail(const __hip_bfloat16* __restrict__ o1, const __hip_bfloat16* __restrict__ W1t,
              const float* __restrict__ b1, const __hip_bfloat16* __restrict__ W2t,
              const float* __restrict__ b2, const float* __restrict__ w3,
              const float* __restrict__ b3, float* __restrict__ out)
{
  __shared__ __hip_bfloat16 sA[128 * 32];
  __shared__ __hip_bfloat16 sB[128 * 32];
  __shared__ __hip_bfloat16 sO2[128 * O2P];
  __shared__ float spart[2][128];
  const int tid = threadIdx.x;
  const int lane = tid & 63;
  const int wave = tid >> 6;
  const int wx = wave & 1, wy = wave >> 1;
  const int bm = blockIdx.x;
  const int mrow = lane & 15, quad = lane >> 4;
  const int r0 = tid >> 2, kc0 = (tid & 3) * 8;

  const __hip_bfloat16* Ag0 = o1 + (size_t)(bm * 128 + r0) * 256 + kc0;
  const __hip_bfloat16* Ag1 = o1 + (size_t)(bm * 128 + r0 + 64) * 256 + kc0;
  const __hip_bfloat16* Bg0 = W1t + (size_t)r0 * 256 + kc0;
  const __hip_bfloat16* Bg1 = W1t + (size_t)(r0 + 64) * 256 + kc0;

  f32x4 acc[4][4];
  #pragma unroll
  for (int i = 0; i < 4; i++)
    #pragma unroll
    for (int j = 0; j < 4; j++)
      acc[i][j] = (f32x4){0.f, 0.f, 0.f, 0.f};

  for (int kt = 0; kt < 256; kt += 32) {
    __syncthreads();
    gload_lds16(Ag0 + kt, &sA[tid * 8]);
    gload_lds16(Ag1 + kt, &sA[2048 + tid * 8]);
    gload_lds16(Bg0 + kt, &sB[tid * 8]);
    gload_lds16(Bg1 + kt, &sB[2048 + tid * 8]);
    __syncthreads();

    bf16x8 af[4], bfr[4];
    #pragma unroll
    for (int i = 0; i < 4; i++) {
      af[i]  = *(const bf16x8*)&sA[(wy * 64 + i * 16 + mrow) * 32 + quad * 8];
      bfr[i] = *(const bf16x8*)&sB[(wx * 64 + i * 16 + mrow) * 32 + quad * 8];
    }
    #pragma unroll
    for (int i = 0; i < 4; i++)
      #pragma unroll
      for (int j = 0; j < 4; j++)
        acc[i][j] = __builtin_amdgcn_mfma_f32_16x16x32_bf16(af[i], bfr[j], acc[i][j], 0, 0, 0);
  }

  __syncthreads();
  #pragma unroll
  for (int i = 0; i < 4; i++) {
    #pragma unroll
    for (int r = 0; r < 4; r++) {
      int row = wy * 64 + i * 16 + quad * 4 + r;
      #pragma unroll
      for (int j = 0; j < 4; j++) {
        int col = wx * 64 + j * 16 + mrow;
        float v = acc[i][j][r] + b1[col];
        v = v > 0.f ? v : 0.01f * v;
        sO2[row * O2P + col] = __float2bfloat16(v);
      }
    }
  }

  f32x4 acc2[4][4];
  #pragma unroll
  for (int i = 0; i < 4; i++)
    #pragma unroll
    for (int j = 0; j < 4; j++)
      acc2[i][j] = (f32x4){0.f, 0.f, 0.f, 0.f};

  for (int kt = 0; kt < 128; kt += 32) {
    __syncthreads();
    gload_lds16(W2t + (size_t)r0 * 128 + kt + kc0, &sB[tid * 8]);
    gload_lds16(W2t + (size_t)(r0 + 64) * 128 + kt + kc0, &sB[2048 + tid * 8]);
    __syncthreads();

    bf16x8 af[4], bfr[4];
    #pragma unroll
    for (int i = 0; i < 4; i++) {
      af[i]  = *(const bf16x8*)&sO2[(wy * 64 + i * 16 + mrow) * O2P + kt + quad * 8];
      bfr[i] = *(const bf16x8*)&sB[(wx * 64 + i * 16 + mrow) * 32 + quad * 8];
    }
    #pragma unroll
    for (int i = 0; i < 4; i++)
      #pragma unroll
      for (int j = 0; j < 4; j++)
        acc2[i][j] = __builtin_amdgcn_mfma_f32_16x16x32_bf16(af[i], bfr[j], acc2[i][j], 0, 0, 0);
  }

  float w3v[4], b2v[4];
  #pragma unroll
  for (int j = 0; j < 4; j++) {
    int col = wx * 64 + j * 16 + mrow;
    w3v[j] = w3[col];
    b2v[j] = b2[col];
  }
  #pragma unroll
  for (int i = 0; i < 4; i++) {
    #pragma unroll
    for (int r = 0; r < 4; r++) {
      float s = 0.f;
      #pragma unroll
      for (int j = 0; j < 4; j++) {
        float v = acc2[i][j][r] + b2v[j];
        v = v > 0.f ? v : 0.01f * v;
        s += v * w3v[j];
      }
      #pragma unroll
      for (int off = 8; off; off >>= 1) s += __shfl_xor(s, off);
      if (mrow == 0) {
        int row = wy * 64 + i * 16 + quad * 4 + r;
        spart[wx][row] = s;
      }
    }
  }
  __syncthreads();
  if (tid < 128)
    out[(size_t)bm * 128 + tid] = spart[0][tid] + spart[1][tid] + b3[0];
}

// ---------------------------------------------------------------------------
// LayerNorm over HID=256; one wave per row; writes bf16. (Used once, after proj.)
// ---------------------------------------------------------------------------
__global__ __launch_bounds__(256)
void layernorm(const float* __restrict__ h, const float* __restrict__ g,
               const float* __restrict__ b, __hip_bfloat16* __restrict__ hn)
{
  const int wv = threadIdx.x >> 6, lane = threadIdx.x & 63;
  const size_t row = (size_t)blockIdx.x * 4 + wv;
  const float* hr = h + row * HID;
  float v[4];
  float sum = 0.f;
  #pragma unroll
  for (int j = 0; j < 4; j++) { v[j] = hr[lane + 64 * j]; sum += v[j]; }
  #pragma unroll
  for (int off = 32; off; off >>= 1) sum += __shfl_xor(sum, off);
  float mu = sum * (1.f / 256.f);
  float vs = 0.f;
  #pragma unroll
  for (int j = 0; j < 4; j++) { float d = v[j] - mu; vs += d * d; }
  #pragma unroll
  for (int off = 32; off; off >>= 1) vs += __shfl_xor(vs, off);
  float rs = rsqrtf(vs * (1.f / 256.f) + 1e-5f);
  __hip_bfloat16* outr = hn + row * HID;
  #pragma unroll
  for (int j = 0; j < 4; j++) {
    int c = lane + 64 * j;
    outr[c] = __float2bfloat16((v[j] - mu) * rs * g[c] + b[c]);
  }
}

// ---------------------------------------------------------------------------
// GATv2 aggregation + h update (+ optional fused next-layer LayerNorm).
// EXACT R0 gat_agg except xcat is now xl-only: row stride S = H*HID.
// One block per graph; thread = (channel-quad c4, node-group ng).
// ---------------------------------------------------------------------------
template<int DO_LN>
__global__ __launch_bounds__(256, 4)
void gat_agg(const __hip_bfloat16* __restrict__ xcat, const float* __restrict__ alphaG,
             const float* __restrict__ bias, float* __restrict__ h,
             const float* __restrict__ lnG, const float* __restrict__ lnB,
             __hip_bfloat16* __restrict__ hn, const int* __restrict__ meta, int H)
{
  __shared__ __hip_bfloat16 sxl[2][N_NODES * HID];   // 2 x 15 KB, head double-buffer
  __shared__ float salpha[2][E_TOT];
  __shared__ int ssrc[E_TOT], scnt[N_NODES], slist[N_NODES * MAXIN];

  const int tid = threadIdx.x;
  const int g = blockIdx.x;
  const size_t nodebase = (size_t)g * N_NODES;
  const int S = H * HID;                    // xl-only stride (R17)
  const int c4 = tid & 63;
  const int ng = tid >> 6;

  if (tid < E_TOT) ssrc[tid] = meta[META_SRC + tid];
  if (tid < N_NODES) scnt[tid] = meta[META_CNT + tid];
  for (int i = tid; i < N_NODES * MAXIN; i += 256) slist[i] = meta[META_LIST + i];

  float4 hres[8];
  #pragma unroll
  for (int ki = 0; ki < 8; ki++) {
    int k = ng + ki * 4;
    if (k < N_NODES) hres[ki] = *(const float4*)&h[(nodebase + k) * HID + c4 * 4];
  }

  {
    int i = tid;
    #pragma unroll
    for (int p = 0; p < 4; p++, i += 256) {
      if (i < N_NODES * HID / 8) {
        int node = i >> 5, c = (i & 31) * 8;
        gload_lds16(&xcat[(nodebase + node) * S + 0 * HID + c], &sxl[0][(size_t)i * 8]);
      }
    }
    if (tid < E_TOT) salpha[0][tid] = alphaG[((size_t)g * H + 0) * E_TOT + tid];
  }

  float acc[8][4];
  #pragma unroll
  for (int ki = 0; ki < 8; ki++)
    #pragma unroll
    for (int j = 0; j < 4; j++) acc[ki][j] = 0.f;

  for (int hh = 0; hh < H; hh++) {
    const int buf = hh & 1;
    __syncthreads();
    if (hh + 1 < H) {
      const int nb = buf ^ 1;
      int i = tid;
      #pragma unroll
      for (int p = 0; p < 4; p++, i += 256) {
        if (i < N_NODES * HID / 8) {
          int node = i >> 5, c = (i & 31) * 8;
          gload_lds16(&xcat[(nodebase + node) * S + (hh + 1) * HID + c], &sxl[nb][(size_t)i * 8]);
        }
      }
      if (tid < E_TOT) salpha[nb][tid] = alphaG[((size_t)g * H + hh + 1) * E_TOT + tid];
    }
    #pragma unroll
    for (int ki = 0; ki < 8; ki++) {
      int k = ng + ki * 4;
      if (k < N_NODES) {
        int cnt = scnt[k];
        const int* lst = &slist[k * MAXIN];
        for (int i = 0; i < cnt; i++) {
          int e = lst[i];                       // wave-uniform broadcast reads
          float al = salpha[buf][e];
          bf16x4 v = *(const bf16x4*)&sxl[buf][ssrc[e] * HID + c4 * 4];
          acc[ki][0] += al * b2f(v[0]);
          acc[ki][1] += al * b2f(v[1]);
          acc[ki][2] += al * b2f(v[2]);
          acc[ki][3] += al * b2f(v[3]);
        }
      }
    }
  }

  const float invH = 1.f / (float)H;
  const float4 bs = *(const float4*)&bias[c4 * 4];
  float4 gv, bv;
  if (DO_LN) {
    gv = *(const float4*)&lnG[c4 * 4];
    bv = *(const float4*)&lnB[c4 * 4];
  }
  #pragma unroll
  for (int ki = 0; ki < 8; ki++) {
    int k = ng + ki * 4;
    if (k < N_NODES) {
      float o0 = acc[ki][0] * invH + bs.x; o0 = o0 > 0.f ? o0 : 0.01f * o0; o0 += hres[ki].x;
      float o1 = acc[ki][1] * invH + bs.y; o1 = o1 > 0.f ? o1 : 0.01f * o1; o1 += hres[ki].y;
      float o2 = acc[ki][2] * invH + bs.z; o2 = o2 > 0.f ? o2 : 0.01f * o2; o2 += hres[ki].z;
      float o3 = acc[ki][3] * invH + bs.w; o3 = o3 > 0.f ? o3 : 0.01f * o3; o3 += hres[ki].w;
      float4 o4 = {o0, o1, o2, o3};
      *(float4*)&h[(nodebase + k) * HID + c4 * 4] = o4;
      if (DO_LN) {
        float sum = o0 + o1 + o2 + o3;
        #pragma unroll
        for (int off = 32; off; off >>= 1) sum += __shfl_xor(sum, off);
        float mu = sum * (1.f / 256.f);
        float d0 = o0 - mu, d1 = o1 - mu, d2 = o2 - mu, d3 = o3 - mu;
        float vs = d0 * d0 + d1 * d1 + d2 * d2 + d3 * d3;
        #pragma unroll
        for (int off = 32; off; off >>= 1) vs += __shfl_xor(vs, off);
        float rs = rsqrtf(vs * (1.f / 256.f) + 1e-5f);
        __hip_bfloat16 t[4];
        t[0] = __float2bfloat16(d0 * rs * gv.x + bv.x);
        t[1] = __float2bfloat16(d1 * rs * gv.y + bv.y);
        t[2] = __float2bfloat16(d2 * rs * gv.z + bv.z);
        t[3] = __float2bfloat16(d3 * rs * gv.w + bv.w);
        *(bf16x4*)&hn[(nodebase + k) * HID + c4 * 4] = *(bf16x4*)t;
      }
    }
  }
}

// ---------------------------------------------------------------------------
extern "C" void kernel_launch(void* const* d_in, const int* in_sizes, int n_in,
                              void* d_out, int out_size, void* d_ws, size_t ws_size,
                              hipStream_t stream) {
  const float* x     = (const float*)d_in[0];
  const int*   ei    = (const int*)d_in[1];
  const int*   pairs = (const int*)d_in[2];
  const float* bp    = (const float*)d_in[4];
  const float *lng[3], *lnb[3], *bl[3], *br[3], *att[3], *bias[3];
  const float *WlF[3], *WrF[3];
  for (int l = 0; l < 3; l++) {
    int base = 5 + l * 8;
    lng[l]  = (const float*)d_in[base + 0];
    lnb[l]  = (const float*)d_in[base + 1];
    WlF[l]  = (const float*)d_in[base + 2];
    bl[l]   = (const float*)d_in[base + 3];
    WrF[l]  = (const float*)d_in[base + 4];
    br[l]   = (const float*)d_in[base + 5];
    att[l]  = (const float*)d_in[base + 6];
    bias[l] = (const float*)d_in[base + 7];
  }
  const float* WmF[4] = {(const float*)d_in[29], (const float*)d_in[31],
                         (const float*)d_in[33], (const float*)d_in[35]};
  const float* bm[4] = {(const float*)d_in[30], (const float*)d_in[32],
                        (const float*)d_in[34], (const float*)d_in[36]};

  // workspace layout (float offsets)
  float* ws  = (float*)d_ws;
  float* h   = ws;                                           // [0, 7864320)
  __hip_bfloat16* hnb = (__hip_bfloat16*)(ws + 7864320);     // 3,932,160 bf
  __hip_bfloat16* xlcat = (__hip_bfloat16*)(ws + 11796480);  // xl-only: <= 23,592,960 bf
  float* logits0 = ws + 30000000;                            // 344,064 f (l=0)
  float* logits1 = logits0 + 344064;                         // 229,376 f (l=1)
  float* logits2 = logits1 + 229376;                         // 114,688 f (l=2)
  float* alphaG = ws + 35389440;                             // 344,064 f
  __hip_bfloat16* wbuf = (__hip_bfloat16*)(ws + 35733504);   // 999,424 bf
  int*   meta = (int*)(ws + 36233216);
  __hip_bfloat16* o1b = (__hip_bfloat16*)xlcat;              // pair out (xlcat dead then)
  float* out = (float*)d_out;

  // zero the logit accumulators (gemm_gat atomically adds into them)
  hipMemsetAsync(logits0, 0, (344064 + 229376 + 114688) * sizeof(float), stream);

  // bf16 transposed weight offsets (layouts unchanged from R0)
  const int oWp = 0, oWl0 = 32768, oWr0 = 229376, oWl1 = 425984, oWr1 = 557056;
  const int oWl2 = 688128, oWr2 = 753664, oWm0 = 819200, oWm1 = 950272, oWm2 = 983040;

  WtArgs wa;
  wa.j[0] = {(const float*)d_in[3], 128, 256,   0, oWp };
  wa.j[1] = {WlF[0],              256, 768,  32, oWl0};
  wa.j[2] = {WrF[0],              256, 768, 224, oWr0};
  wa.j[3] = {WlF[1],              256, 512, 416, oWl1};
  wa.j[4] = {WrF[1],              256, 512, 544, oWr1};
  wa.j[5] = {WlF[2],              256, 256, 672, oWl2};
  wa.j[6] = {WrF[2],              256, 256, 736, oWr2};
  wa.j[7] = {WmF[0],              512, 256, 800, oWm0};
  wa.j[8] = {WmF[1],              256, 128, 928, oWm1};
  wa.j[9] = {WmF[2],              128, 128, 960, oWm2};
  transpose_weights<<<977, 256, 0, stream>>>(wa, wbuf, ei, meta);  // block 976 = build_graph

  // h = x @ Wp + bp   (fp32 A staged with fused bf16 cast; fp32 out)
  gemm_mfma_f32a<0, 0><<<dim3(NTOT / 128, 2), 256, 0, stream>>>(x, wbuf + oWp, bp, h,
                                                                NTOT, 128, 256);

  layernorm<<<NTOT / 4, 256, 0, stream>>>(h, lng[0], lnb[0], hnb);

  const int Hs[3] = {3, 2, 1};
  const int oWl[3] = {oWl0, oWl1, oWl2};
  const int oWr[3] = {oWr0, oWr1, oWr2};
  float* logitsL[3] = {logits0, logits1, logits2};
  for (int l = 0; l < 3; l++) {
    int H = Hs[l];
    gemm_gat<<<dim3(NTOT / 120, H * 4), 256, 0, stream>>>(
        hnb, wbuf + oWl[l], wbuf + oWr[l], bl[l], br[l], att[l],
        xlcat, logitsL[l], meta, H);
    gat_softmax<<<dim3(B_GRAPH, H), 128, 0, stream>>>(logitsL[l], alphaG, meta, H);
    if (l < 2)
      gat_agg<1><<<B_GRAPH, 256, 0, stream>>>(xlcat, alphaG, bias[l], h,
                                              lng[l + 1], lnb[l + 1], hnb, meta, H);
    else
      gat_agg<0><<<B_GRAPH, 256, 0, stream>>>(xlcat, alphaG, bias[l], h,
                                              nullptr, nullptr, nullptr, meta, H);
  }

  gemm_mfma_pair<<<dim3(M_MLP / 128, 2), 256, 0, stream>>>(h, pairs, wbuf + oWm0, bm[0], o1b, 256);
  mlp_tail<<<M_MLP / 128, 256, 0, stream>>>(o1b, wbuf + oWm1, bm[1], wbuf + oWm2, bm[2],
                                            WmF[3], bm[3], out);
}

// Round 7
// 440.388 us; speedup vs baseline: 1.2209x; 1.0205x over previous
//
#include <hip/hip_runtime.h>
#include <hip/hip_bf16.h>
#include <math.h>

// Problem constants
#define N_NODES 30
#define E_BASE  82
#define E_TOT   112         // 82 edges + 30 self loops
#define B_GRAPH 1024
#define HID     256
#define NTOT    (B_GRAPH * N_NODES)   // 30720
#define MAXIN   32
#define N_EH    41
#define M_MLP   (B_GRAPH * N_EH)      // 41984

#define META_SRC  0
#define META_DST  E_TOT
#define META_CNT  (2 * E_TOT)
#define META_LIST 256
#define META_INTS 1216

typedef __attribute__((ext_vector_type(8))) short bf16x8;
typedef __attribute__((ext_vector_type(4))) short bf16x4;
typedef __attribute__((ext_vector_type(4))) float f32x4;
#define AS3 __attribute__((address_space(3)))
#define AS1 __attribute__((address_space(1)))

__device__ __forceinline__ void gload_lds16(const void* g, void* l) {
  __builtin_amdgcn_global_load_lds((const AS1 void*)g, (AS3 void*)l, 16, 0, 0);
}

// Bit-reinterpret ONLY — callers must pass raw bf16 bit patterns (short lanes
// of bf16x4/8 vectors). Never pass __hip_bfloat16 (would value-convert via
// float->short — the R3 NaN bug).
__device__ __forceinline__ float b2f(short s) {
  union { unsigned u; float f; } x;
  x.u = ((unsigned)(unsigned short)s) << 16;
  return x.f;
}

// float -> bf16 bit pattern (same rounding as __float2bfloat16; raw short out)
__device__ __forceinline__ short f2bf_bits(float f) {
  union { __hip_bfloat16 h; short s; } u;
  u.h = __float2bfloat16(f);
  return u.s;
}

// ---------------------------------------------------------------------------
// Transpose-cast all weights fp32 [K,N] -> bf16 [N,K]; block 976 instead
// builds the base-graph CSR (merged to save a launch).
// ---------------------------------------------------------------------------
struct WtJob { const float* in; int K, N, tstart, ooff; };
struct WtArgs { WtJob j[10]; };

__global__ __launch_bounds__(256)
void transpose_weights(WtArgs args, __hip_bfloat16* __restrict__ out,
                       const int* __restrict__ ei, int* __restrict__ meta) {
  int b = blockIdx.x;
  if (b == 976) {   // build_graph job
    __shared__ int cnt[N_NODES];
    int tid = threadIdx.x;
    if (tid < N_NODES) cnt[tid] = 0;
    __syncthreads();
    if (tid < E_TOT) {
      int s, d;
      if (tid < E_BASE) { s = ei[tid]; d = ei[B_GRAPH * E_BASE + tid]; }
      else              { s = tid - E_BASE; d = s; }
      meta[META_SRC + tid] = s;
      meta[META_DST + tid] = d;
      int pos = atomicAdd(&cnt[d], 1);
      if (pos < MAXIN) meta[META_LIST + d * MAXIN + pos] = tid;
    }
    __syncthreads();
    if (tid < N_NODES) meta[META_CNT + tid] = cnt[tid];
    return;
  }
  int ji = 0;
  #pragma unroll
  for (int i = 1; i < 10; i++) if (b >= args.j[i].tstart) ji = i;
  WtJob jb = args.j[ji];
  int t = b - jb.tstart;
  int ntn = jb.N >> 5;
  int tk = t / ntn, tn = t - tk * ntn;
  int k0 = tk * 32, n0 = tn * 32;
  __shared__ float s[32][33];
  int tx = threadIdx.x & 31, ty = threadIdx.x >> 5;
  #pragma unroll
  for (int p = 0; p < 4; p++)
    s[ty + p * 8][tx] = jb.in[(size_t)(k0 + ty + p * 8) * jb.N + n0 + tx];
  __syncthreads();
  __hip_bfloat16* o = out + jb.ooff;
  #pragma unroll
  for (int p = 0; p < 4; p++) {
    int n = ty + p * 8;
    o[(size_t)(n0 + n) * jb.K + k0 + tx] = __float2bfloat16(s[tx][n]);
  }
}

// ---------------------------------------------------------------------------
// R19 gemm_gat: layer GEMM with IN-KERNEL edge logits; xr never hits HBM.
// R19: TRANSPOSED-OPERAND epilogue — mfma(bfr,af) so each lane holds 4
// CONSECUTIVE columns per (i,j): epilogue LDS writes become 16x ds_write_b64
// (was 64x scalar ds_write_b16 — the R6-measured VALU-issue hog). With XP=132
// (66-word row stride) the 16 lanes' writes start at banks {0,2,..,30} and
// each 8B covers {2i,2i+1} -> all 32 banks exactly once: conflict-free.
// R1's swap regression was the GLOBAL store pattern (4x transactions); here
// the global store is cooperative-from-LDS, unaffected by the swap.
//
// Block (bm, bn): bn = h*4+cg covers head h, channel-group cg (64 ch).
//   cols 0-63  = xl channels [cg*64, +64)  (B rows from Wl)
//   cols 64-127= xr channels [cg*64, +64)  (B rows from Wr)
// M-tile = 120 rows = 4 WHOLE graphs (+8 pad rows, outputs discarded) so every
// edge's src/dst rows are in-block. Then a 28-pass edge pass computes the
// 64-channel partial logit and atomicAdds into zeroed logitsG (4 contenders).
// bf16 rounding points identical to the R0 path (logits read back bf16 values).
// ---------------------------------------------------------------------------
#define XP 132   // padded xlr row stride (shorts)
__global__ __launch_bounds__(256)
void gemm_gat(const __hip_bfloat16* __restrict__ A,      // hnb [NTOT][256]
              const __hip_bfloat16* __restrict__ Wl,     // [H*256][256] bf16 (transposed)
              const __hip_bfloat16* __restrict__ Wr,
              const float* __restrict__ blv, const float* __restrict__ brv,
              const float* __restrict__ att,             // [H][256]
              __hip_bfloat16* __restrict__ xlcat,        // [NTOT][H*256]
              float* __restrict__ logitsG,               // [B][H][E_TOT], pre-zeroed
              const int* __restrict__ meta, int H)
{
  union GatSmem {
    struct { short a[2][4096]; short b[2][4096]; } st;   // 32 KB staging
    short xlr[128 * XP];                                  // 33.8 KB epilogue
  };
  __shared__ GatSmem sm;
  __shared__ int ssrc[E_TOT], sdst[E_TOT];

  const int tid = threadIdx.x;
  const int lane = tid & 63, wave = tid >> 6;
  const int wx = wave & 1, wy = wave >> 1;
  const int bm = blockIdx.x, bn = blockIdx.y;
  const int mrow = lane & 15, quad = lane >> 4;
  const int hh = bn >> 2, cg = bn & 3;
  const int K = HID;

  if (tid < E_TOT) { ssrc[tid] = meta[META_SRC + tid]; sdst[tid] = meta[META_DST + tid]; }

  const int r0 = tid >> 2, kc0 = (tid & 3) * 8;
  const int Ra = bm * 120 + r0;                              // rows 0..63: real
  const int Rb = bm * 120 + (r0 + 64 > 119 ? 119 : r0 + 64); // clamp pad rows
  const __hip_bfloat16* Ag0 = A + (size_t)Ra * K + kc0;
  const __hip_bfloat16* Ag1 = A + (size_t)Rb * K + kc0;
  const int brow = hh * 256 + cg * 64 + r0;                  // r0 in 0..63
  const __hip_bfloat16* Bg0 = Wl + (size_t)brow * K + kc0;   // cols 0-63  = xl
  const __hip_bfloat16* Bg1 = Wr + (size_t)brow * K + kc0;   // cols 64-127= xr

  f32x4 acc[4][4];
  #pragma unroll
  for (int i = 0; i < 4; i++)
    #pragma unroll
    for (int j = 0; j < 4; j++)
      acc[i][j] = (f32x4){0.f, 0.f, 0.f, 0.f};

  for (int kt = 0; kt < K; kt += 64) {
    __syncthreads();
    #pragma unroll
    for (int s = 0; s < 2; s++) {
      gload_lds16(Ag0 + kt + s * 32, &sm.st.a[s][tid * 8]);
      gload_lds16(Ag1 + kt + s * 32, &sm.st.a[s][2048 + tid * 8]);
      gload_lds16(Bg0 + kt + s * 32, &sm.st.b[s][tid * 8]);
      gload_lds16(Bg1 + kt + s * 32, &sm.st.b[s][2048 + tid * 8]);
    }
    __syncthreads();

    #pragma unroll
    for (int s = 0; s < 2; s++) {
      bf16x8 af[4], bfr[4];
      #pragma unroll
      for (int i = 0; i < 4; i++) {
        af[i]  = *(const bf16x8*)&sm.st.a[s][(wy * 64 + i * 16 + mrow) * 32 + quad * 8];
        bfr[i] = *(const bf16x8*)&sm.st.b[s][(wx * 64 + i * 16 + mrow) * 32 + quad * 8];
      }
      #pragma unroll
      for (int i = 0; i < 4; i++)
        #pragma unroll
        for (int j = 0; j < 4; j++)
          acc[i][j] = __builtin_amdgcn_mfma_f32_16x16x32_bf16(bfr[j], af[i], acc[i][j], 0, 0, 0);
    }
  }

  __syncthreads();   // K-loop LDS reads done; safe to repurpose union as xlr

  // ---- epilogue (transposed fragment): bias + bf16 -> LDS, 16x ds_write_b64.
  // acc[i][j][r] = C[row = wy*64+i*16+mrow][col = wx*64+j*16+quad*4+r]
  const float* bb = wx ? brv : blv;
  #pragma unroll
  for (int i = 0; i < 4; i++) {
    int lrow = wy * 64 + i * 16 + mrow;
    #pragma unroll
    for (int j = 0; j < 4; j++) {
      int c0 = j * 16 + quad * 4;               // 0..63 within half
      float4 bc = *(const float4*)&bb[hh * 256 + cg * 64 + c0];
      short t[4];
      t[0] = f2bf_bits(acc[i][j][0] + bc.x);
      t[1] = f2bf_bits(acc[i][j][1] + bc.y);
      t[2] = f2bf_bits(acc[i][j][2] + bc.z);
      t[3] = f2bf_bits(acc[i][j][3] + bc.w);
      *(bf16x4*)&sm.xlr[lrow * XP + wx * 64 + c0] = *(bf16x4*)t;
    }
  }
  __syncthreads();

  // ---- cooperative vectorized store of the xl half (120 rows x 64 ch) ----
  // 960 16B chunks; chunk c -> row c>>3, part c&7. 128B contiguous per row.
  {
    const size_t SROW = (size_t)H * HID;
    #pragma unroll
    for (int p = 0; p < 4; p++) {
      int c = tid + p * 256;
      if (c < 960) {
        int row = c >> 3, part = c & 7;
        bf16x8 v = *(const bf16x8*)&sm.xlr[row * XP + part * 8];
        *(bf16x8*)&((short*)xlcat)[((size_t)bm * 120 + row) * SROW
                                   + hh * HID + cg * 64 + part * 8] = v;
      }
    }
  }

  // ---- logit partials: 448 edges (4 graphs x 112), 64 channels each ----
  const int slot = tid >> 4, chsub = tid & 15;   // 16 edges/pass, 16 lanes/edge
  float av[4];
  #pragma unroll
  for (int i = 0; i < 4; i++) av[i] = att[hh * HID + cg * 64 + chsub * 4 + i];
  for (int p = 0; p < 28; p++) {
    int eidx = p * 16 + slot;
    int gl = eidx / E_TOT, e = eidx - gl * E_TOT;
    int rs = gl * 30 + ssrc[e], rd = gl * 30 + sdst[e];
    bf16x4 xlv = *(const bf16x4*)&sm.xlr[rs * XP + chsub * 4];
    bf16x4 xrv = *(const bf16x4*)&sm.xlr[rd * XP + 64 + chsub * 4];
    float sum = 0.f;
    #pragma unroll
    for (int i = 0; i < 4; i++) {
      float s = b2f(xlv[i]) + b2f(xrv[i]);
      s = s > 0.f ? s : 0.2f * s;
      sum += s * av[i];
    }
    sum += __shfl_xor(sum, 1); sum += __shfl_xor(sum, 2);
    sum += __shfl_xor(sum, 4); sum += __shfl_xor(sum, 8);
    if (chsub == 0)
      atomicAdd(&logitsG[((size_t)(bm * 4 + gl) * H + hh) * E_TOT + e], sum);
  }
}

// ---------------------------------------------------------------------------
// MFMA GEMM with fp32 A staged via in-register bf16 cast (fused cast): proj.
// (EXACT R0 version.)
// ---------------------------------------------------------------------------
template<int ACT, int OUTBF>
__global__ __launch_bounds__(256)
void gemm_mfma_f32a(const float* __restrict__ A, const __hip_bfloat16* __restrict__ Bt,
                    const float* __restrict__ bias, void* __restrict__ Cv,
                    int M, int K, int N)
{
  __shared__ __hip_bfloat16 sA[128 * 32];
  __shared__ __hip_bfloat16 sB[128 * 32];
  const int tid = threadIdx.x;
  const int lane = tid & 63;
  const int wave = tid >> 6;
  const int wx = wave & 1, wy = wave >> 1;
  const int bm = blockIdx.x, bn = blockIdx.y;
  const int mrow = lane & 15, quad = lane >> 4;

  const int r0 = tid >> 2, kc0 = (tid & 3) * 8;
  const float* Ag0 = A + (size_t)(bm * 128 + r0) * K + kc0;
  const float* Ag1 = A + (size_t)(bm * 128 + r0 + 64) * K + kc0;
  const __hip_bfloat16* Bg0 = Bt + (size_t)(bn * 128 + r0) * K + kc0;
  const __hip_bfloat16* Bg1 = Bt + (size_t)(bn * 128 + r0 + 64) * K + kc0;

  f32x4 acc[4][4];
  #pragma unroll
  for (int i = 0; i < 4; i++)
    #pragma unroll
    for (int j = 0; j < 4; j++)
      acc[i][j] = (f32x4){0.f, 0.f, 0.f, 0.f};

  for (int kt = 0; kt < K; kt += 32) {
    float4 a00 = *(const float4*)(Ag0 + kt);
    float4 a01 = *(const float4*)(Ag0 + kt + 4);
    float4 a10 = *(const float4*)(Ag1 + kt);
    float4 a11 = *(const float4*)(Ag1 + kt + 4);
    __syncthreads();
    {
      __hip_bfloat16 t[8];
      t[0] = __float2bfloat16(a00.x); t[1] = __float2bfloat16(a00.y);
      t[2] = __float2bfloat16(a00.z); t[3] = __float2bfloat16(a00.w);
      t[4] = __float2bfloat16(a01.x); t[5] = __float2bfloat16(a01.y);
      t[6] = __float2bfloat16(a01.z); t[7] = __float2bfloat16(a01.w);
      *(bf16x8*)&sA[tid * 8] = *(bf16x8*)t;
      t[0] = __float2bfloat16(a10.x); t[1] = __float2bfloat16(a10.y);
      t[2] = __float2bfloat16(a10.z); t[3] = __float2bfloat16(a10.w);
      t[4] = __float2bfloat16(a11.x); t[5] = __float2bfloat16(a11.y);
      t[6] = __float2bfloat16(a11.z); t[7] = __float2bfloat16(a11.w);
      *(bf16x8*)&sA[2048 + tid * 8] = *(bf16x8*)t;
    }
    gload_lds16(Bg0 + kt, &sB[tid * 8]);
    gload_lds16(Bg1 + kt, &sB[2048 + tid * 8]);
    __syncthreads();

    bf16x8 af[4], bfr[4];
    #pragma unroll
    for (int i = 0; i < 4; i++) {
      af[i]  = *(const bf16x8*)&sA[(wy * 64 + i * 16 + mrow) * 32 + quad * 8];
      bfr[i] = *(const bf16x8*)&sB[(wx * 64 + i * 16 + mrow) * 32 + quad * 8];
    }
    #pragma unroll
    for (int i = 0; i < 4; i++)
      #pragma unroll
      for (int j = 0; j < 4; j++)
        acc[i][j] = __builtin_amdgcn_mfma_f32_16x16x32_bf16(af[i], bfr[j], acc[i][j], 0, 0, 0);
  }

  #pragma unroll
  for (int i = 0; i < 4; i++) {
    #pragma unroll
    for (int r = 0; r < 4; r++) {
      size_t row = (size_t)bm * 128 + wy * 64 + i * 16 + quad * 4 + r;
      #pragma unroll
      for (int j = 0; j < 4; j++) {
        int col = bn * 128 + wx * 64 + j * 16 + mrow;
        float v = acc[i][j][r] + bias[col];
        if (ACT) v = v > 0.f ? v : 0.01f * v;
        if (OUTBF) ((__hip_bfloat16*)Cv)[row * N + col] = __float2bfloat16(v);
        else       ((float*)Cv)[row * N + col] = v;
      }
    }
  }
}

// ---------------------------------------------------------------------------
// MFMA GEMM with fused edge-pair gather from fp32 h (EXACT R0 version).
// ---------------------------------------------------------------------------
__global__ __launch_bounds__(256)
void gemm_mfma_pair(const float* __restrict__ h, const int* __restrict__ pairs,
                    const __hip_bfloat16* __restrict__ Bt, const float* __restrict__ bias,
                    __hip_bfloat16* __restrict__ C, int N)
{
  const int K = 512;
  __shared__ __hip_bfloat16 sA[128 * 32];
  __shared__ __hip_bfloat16 sB[128 * 32];
  const int tid = threadIdx.x;
  const int lane = tid & 63;
  const int wave = tid >> 6;
  const int wx = wave & 1, wy = wave >> 1;
  const int bm = blockIdx.x, bn = blockIdx.y;
  const int mrow = lane & 15, quad = lane >> 4;

  const float* pu[2]; const float* pv[2]; int sub[2];
  #pragma unroll
  for (int cI = 0; cI < 2; cI++) {
    int c = tid + cI * 256;
    int r0 = c >> 2; sub[cI] = (c & 3) * 8;
    int R = bm * 128 + r0;
    int b = R / N_EH, p = R - b * N_EH;
    int u = pairs[p * 2], v = pairs[p * 2 + 1];
    pu[cI] = h + ((size_t)b * N_NODES + u) * HID;
    pv[cI] = h + ((size_t)b * N_NODES + v) * HID;
  }

  const int r0 = tid >> 2, kc0 = (tid & 3) * 8;
  const __hip_bfloat16* Bg0 = Bt + (size_t)(bn * 128 + r0) * K + kc0;
  const __hip_bfloat16* Bg1 = Bt + (size_t)(bn * 128 + r0 + 64) * K + kc0;

  f32x4 acc[4][4];
  #pragma unroll
  for (int i = 0; i < 4; i++)
    #pragma unroll
    for (int j = 0; j < 4; j++)
      acc[i][j] = (f32x4){0.f, 0.f, 0.f, 0.f};

  for (int kt = 0; kt < 512; kt += 32) {
    float4 av[2][2];
    #pragma unroll
    for (int cI = 0; cI < 2; cI++) {
      const float* src = (kt < 256 ? pu[cI] + kt : pv[cI] + kt - 256) + sub[cI];
      av[cI][0] = *(const float4*)src;
      av[cI][1] = *(const float4*)(src + 4);
    }
    __syncthreads();
    #pragma unroll
    for (int cI = 0; cI < 2; cI++) {
      __hip_bfloat16 t[8];
      t[0] = __float2bfloat16(av[cI][0].x); t[1] = __float2bfloat16(av[cI][0].y);
      t[2] = __float2bfloat16(av[cI][0].z); t[3] = __float2bfloat16(av[cI][0].w);
      t[4] = __float2bfloat16(av[cI][1].x); t[5] = __float2bfloat16(av[cI][1].y);
      t[6] = __float2bfloat16(av[cI][1].z); t[7] = __float2bfloat16(av[cI][1].w);
      *(bf16x8*)&sA[(tid + cI * 256) * 8] = *(bf16x8*)t;
    }
    gload_lds16(Bg0 + kt, &sB[tid * 8]);
    gload_lds16(Bg1 + kt, &sB[2048 + tid * 8]);
    __syncthreads();

    bf16x8 af[4], bfr[4];
    #pragma unroll
    for (int i = 0; i < 4; i++) {
      af[i]  = *(const bf16x8*)&sA[(wy * 64 + i * 16 + mrow) * 32 + quad * 8];
      bfr[i] = *(const bf16x8*)&sB[(wx * 64 + i * 16 + mrow) * 32 + quad * 8];
    }
    #pragma unroll
    for (int i = 0; i < 4; i++)
      #pragma unroll
      for (int j = 0; j < 4; j++)
        acc[i][j] = __builtin_amdgcn_mfma_f32_16x16x32_bf16(af[i], bfr[j], acc[i][j], 0, 0, 0);
  }

  #pragma unroll
  for (int i = 0; i < 4; i++) {
    #pragma unroll
    for (int r = 0; r < 4; r++) {
      size_t row = (size_t)bm * 128 + wy * 64 + i * 16 + quad * 4 + r;
      #pragma unroll
      for (int j = 0; j < 4; j++) {
        int col = bn * 128 + wx * 64 + j * 16 + mrow;
        float v = acc[i][j][r] + bias[col];
        v = v > 0.f ? v : 0.01f * v;
        C[row * N + col] = __float2bfloat16(v);
      }
    }
  }
}

// ---------------------------------------------------------------------------
// Fused MLP tail (R11 — proven win; EXACT R0 version).
// ---------------------------------------------------------------------------
#define O2P 136
__global__ __launch_bounds__(256)
void mlp_tail(const __hip_bfloat16* __restrict__ o1, const __hip_bfloat16* __restrict__ W1t,
              const float* __restrict__ b1, const __hip_bfloat16* __restrict__ W2t,
              const float* __restrict__ b2, const float* __restrict__ w3,
              const float* __restrict__ b3, float* __restrict__ out)
{
  __shared__ __hip_bfloat16 sA[128 * 32];
  __shared__ __hip_bfloat16 sB[128 * 32];
  __shared__ __hip_bfloat16 sO2[128 * O2P];
  __shared__ float spart[2][128];
  const int tid = threadIdx.x;
  const int lane = tid & 63;
  const int wave = tid >> 6;
  const int wx = wave & 1, wy = wave >> 1;
  const int bm = blockIdx.x;
  const int mrow = lane & 15, quad = lane >> 4;
  const int r0 = tid >> 2, kc0 = (tid & 3) * 8;

  const __hip_bfloat16* Ag0 = o1 + (size_t)(bm * 128 + r0) * 256 + kc0;
  const __hip_bfloat16* Ag1 = o1 + (size_t)(bm * 128 + r0 + 64) * 256 + kc0;
  const __hip_bfloat16* Bg0 = W1t + (size_t)r0 * 256 + kc0;
  const __hip_bfloat16* Bg1 = W1t + (size_t)(r0 + 64) * 256 + kc0;

  f32x4 acc[4][4];
  #pragma unroll
  for (int i = 0; i < 4; i++)
    #pragma unroll
    for (int j = 0; j < 4; j++)
      acc[i][j] = (f32x4){0.f, 0.f, 0.f, 0.f};

  for (int kt = 0; kt < 256; kt += 32) {
    __syncthreads();
    gload_lds16(Ag0 + kt, &sA[tid * 8]);
    gload_lds16(Ag1 + kt, &sA[2048 + tid * 8]);
    gload_lds16(Bg0 + kt, &sB[tid * 8]);
    gload_lds16(Bg1 + kt, &sB[2048 + tid * 8]);
    __syncthreads();

    bf16x8 af[4], bfr[4];
    #pragma unroll
    for (int i = 0; i < 4; i++) {
      af[i]  = *(const bf16x8*)&sA[(wy * 64 + i * 16 + mrow) * 32 + quad * 8];
      bfr[i] = *(const bf16x8*)&sB[(wx * 64 + i * 16 + mrow) * 32 + quad * 8];
    }
    #pragma unroll
    for (int i = 0; i < 4; i++)
      #pragma unroll
      for (int j = 0; j < 4; j++)
        acc[i][j] = __builtin_amdgcn_mfma_f32_16x16x32_bf16(af[i], bfr[j], acc[i][j], 0, 0, 0);
  }

  __syncthreads();
  #pragma unroll
  for (int i = 0; i < 4; i++) {
    #pragma unroll
    for (int r = 0; r < 4; r++) {
      int row = wy * 64 + i * 16 + quad * 4 + r;
      #pragma unroll
      for (int j = 0; j < 4; j++) {
        int col = wx * 64 + j * 16 + mrow;
        float v = acc[i][j][r] + b1[col];
        v = v > 0.f ? v : 0.01f * v;
        sO2[row * O2P + col] = __float2bfloat16(v);
      }
    }
  }

  f32x4 acc2[4][4];
  #pragma unroll
  for (int i = 0; i < 4; i++)
    #pragma unroll
    for (int j = 0; j < 4; j++)
      acc2[i][j] = (f32x4){0.f, 0.f, 0.f, 0.f};

  for (int kt = 0; kt < 128; kt += 32) {
    __syncthreads();
    gload_lds16(W2t + (size_t)r0 * 128 + kt + kc0, &sB[tid * 8]);
    gload_lds16(W2t + (size_t)(r0 + 64) * 128 + kt + kc0, &sB[2048 + tid * 8]);
    __syncthreads();

    bf16x8 af[4], bfr[4];
    #pragma unroll
    for (int i = 0; i < 4; i++) {
      af[i]  = *(const bf16x8*)&sO2[(wy * 64 + i * 16 + mrow) * O2P + kt + quad * 8];
      bfr[i] = *(const bf16x8*)&sB[(wx * 64 + i * 16 + mrow) * 32 + quad * 8];
    }
    #pragma unroll
    for (int i = 0; i < 4; i++)
      #pragma unroll
      for (int j = 0; j < 4; j++)
        acc2[i][j] = __builtin_amdgcn_mfma_f32_16x16x32_bf16(af[i], bfr[j], acc2[i][j], 0, 0, 0);
  }

  float w3v[4], b2v[4];
  #pragma unroll
  for (int j = 0; j < 4; j++) {
    int col = wx * 64 + j * 16 + mrow;
    w3v[j] = w3[col];
    b2v[j] = b2[col];
  }
  #pragma unroll
  for (int i = 0; i < 4; i++) {
    #pragma unroll
    for (int r = 0; r < 4; r++) {
      float s = 0.f;
      #pragma unroll
      for (int j = 0; j < 4; j++) {
        float v = acc2[i][j][r] + b2v[j];
        v = v > 0.f ? v : 0.01f * v;
        s += v * w3v[j];
      }
      #pragma unroll
      for (int off = 8; off; off >>= 1) s += __shfl_xor(s, off);
      if (mrow == 0) {
        int row = wy * 64 + i * 16 + quad * 4 + r;
        spart[wx][row] = s;
      }
    }
  }
  __syncthreads();
  if (tid < 128)
    out[(size_t)bm * 128 + tid] = spart[0][tid] + spart[1][tid] + b3[0];
}

// ---------------------------------------------------------------------------
// LayerNorm over HID=256; one wave per row; writes bf16. (Used once, after proj.)
// ---------------------------------------------------------------------------
__global__ __launch_bounds__(256)
void layernorm(const float* __restrict__ h, const float* __restrict__ g,
               const float* __restrict__ b, __hip_bfloat16* __restrict__ hn)
{
  const int wv = threadIdx.x >> 6, lane = threadIdx.x & 63;
  const size_t row = (size_t)blockIdx.x * 4 + wv;
  const float* hr = h + row * HID;
  float v[4];
  float sum = 0.f;
  #pragma unroll
  for (int j = 0; j < 4; j++) { v[j] = hr[lane + 64 * j]; sum += v[j]; }
  #pragma unroll
  for (int off = 32; off; off >>= 1) sum += __shfl_xor(sum, off);
  float mu = sum * (1.f / 256.f);
  float vs = 0.f;
  #pragma unroll
  for (int j = 0; j < 4; j++) { float d = v[j] - mu; vs += d * d; }
  #pragma unroll
  for (int off = 32; off; off >>= 1) vs += __shfl_xor(vs, off);
  float rs = rsqrtf(vs * (1.f / 256.f) + 1e-5f);
  __hip_bfloat16* outr = hn + row * HID;
  #pragma unroll
  for (int j = 0; j < 4; j++) {
    int c = lane + 64 * j;
    outr[c] = __float2bfloat16((v[j] - mu) * rs * g[c] + b[c]);
  }
}

// ---------------------------------------------------------------------------
// R19 gat_agg: aggregation + h update (+ optional fused next-layer LN), with
// the per-(graph,head) softmax FOLDED INTO THE PROLOGUE (computes alpha for
// all H heads from logitsG while the async xl staging is in flight) — deletes
// the 3 gat_softmax launches and their dependency gaps. Softmax body is the
// exact proven R0 gat_alpha tail. xcat is xl-only: row stride S = H*HID.
// One block per graph; thread = (channel-quad c4, node-group ng).
// ---------------------------------------------------------------------------
template<int DO_LN>
__global__ __launch_bounds__(256, 4)
void gat_agg(const __hip_bfloat16* __restrict__ xcat, const float* __restrict__ logitsG,
             const float* __restrict__ bias, float* __restrict__ h,
             const float* __restrict__ lnG, const float* __restrict__ lnB,
             __hip_bfloat16* __restrict__ hn, const int* __restrict__ meta, int H)
{
  __shared__ __hip_bfloat16 sxl[2][N_NODES * HID];   // 2 x 15 KB, head double-buffer
  __shared__ float salpha[3][E_TOT];                 // all heads (H <= 3)
  __shared__ float slog[E_TOT], smax[N_NODES], sden[N_NODES];
  __shared__ int ssrc[E_TOT], sdst[E_TOT], scnt[N_NODES], slist[N_NODES * MAXIN];

  const int tid = threadIdx.x;
  const int g = blockIdx.x;
  const size_t nodebase = (size_t)g * N_NODES;
  const int S = H * HID;                    // xl-only stride
  const int c4 = tid & 63;
  const int ng = tid >> 6;

  if (tid < E_TOT) { ssrc[tid] = meta[META_SRC + tid]; sdst[tid] = meta[META_DST + tid]; }
  if (tid < N_NODES) scnt[tid] = meta[META_CNT + tid];
  for (int i = tid; i < N_NODES * MAXIN; i += 256) slist[i] = meta[META_LIST + i];

  float4 hres[8];
  #pragma unroll
  for (int ki = 0; ki < 8; ki++) {
    int k = ng + ki * 4;
    if (k < N_NODES) hres[ki] = *(const float4*)&h[(nodebase + k) * HID + c4 * 4];
  }

  // issue stage of head 0's xl (async; overlaps with the softmax below)
  {
    int i = tid;
    #pragma unroll
    for (int p = 0; p < 4; p++, i += 256) {
      if (i < N_NODES * HID / 8) {
        int node = i >> 5, c = (i & 31) * 8;
        gload_lds16(&xcat[(nodebase + node) * S + 0 * HID + c], &sxl[0][(size_t)i * 8]);
      }
    }
  }

  // ---- in-block softmax for all H heads (proven gat_alpha tail) ----
  for (int hh = 0; hh < H; hh++) {
    if (tid < E_TOT) slog[tid] = logitsG[((size_t)g * H + hh) * E_TOT + tid];
    if (tid < N_NODES) sden[tid] = 0.f;
    __syncthreads();
    if (tid < N_NODES) {
      int cnt = scnt[tid];
      const int* lst = &slist[tid * MAXIN];
      float m = -1e30f;
      for (int i = 0; i < cnt; i++) m = fmaxf(m, slog[lst[i]]);
      smax[tid] = m;
    }
    __syncthreads();
    if (tid < E_TOT) {
      float ex = expf(slog[tid] - smax[sdst[tid]]);
      slog[tid] = ex;
      atomicAdd(&sden[sdst[tid]], ex);
    }
    __syncthreads();
    if (tid < E_TOT) salpha[hh][tid] = slog[tid] / sden[sdst[tid]];
  }

  float acc[8][4];
  #pragma unroll
  for (int ki = 0; ki < 8; ki++)
    #pragma unroll
    for (int j = 0; j < 4; j++) acc[ki][j] = 0.f;

  for (int hh = 0; hh < H; hh++) {
    const int buf = hh & 1;
    __syncthreads();   // staged loads drained; salpha ready (first iter)
    if (hh + 1 < H) {
      const int nb = buf ^ 1;
      int i = tid;
      #pragma unroll
      for (int p = 0; p < 4; p++, i += 256) {
        if (i < N_NODES * HID / 8) {
          int node = i >> 5, c = (i & 31) * 8;
          gload_lds16(&xcat[(nodebase + node) * S + (hh + 1) * HID + c], &sxl[nb][(size_t)i * 8]);
        }
      }
    }
    #pragma unroll
    for (int ki = 0; ki < 8; ki++) {
      int k = ng + ki * 4;
      if (k < N_NODES) {
        int cnt = scnt[k];
        const int* lst = &slist[k * MAXIN];
        for (int i = 0; i < cnt; i++) {
          int e = lst[i];                       // wave-uniform broadcast reads
          float al = salpha[hh][e];
          bf16x4 v = *(const bf16x4*)&sxl[buf][ssrc[e] * HID + c4 * 4];
          acc[ki][0] += al * b2f(v[0]);
          acc[ki][1] += al * b2f(v[1]);
          acc[ki][2] += al * b2f(v[2]);
          acc[ki][3] += al * b2f(v[3]);
        }
      }
    }
  }

  const float invH = 1.f / (float)H;
  const float4 bs = *(const float4*)&bias[c4 * 4];
  float4 gv, bv;
  if (DO_LN) {
    gv = *(const float4*)&lnG[c4 * 4];
    bv = *(const float4*)&lnB[c4 * 4];
  }
  #pragma unroll
  for (int ki = 0; ki < 8; ki++) {
    int k = ng + ki * 4;
    if (k < N_NODES) {
      float o0 = acc[ki][0] * invH + bs.x; o0 = o0 > 0.f ? o0 : 0.01f * o0; o0 += hres[ki].x;
      float o1 = acc[ki][1] * invH + bs.y; o1 = o1 > 0.f ? o1 : 0.01f * o1; o1 += hres[ki].y;
      float o2 = acc[ki][2] * invH + bs.z; o2 = o2 > 0.f ? o2 : 0.01f * o2; o2 += hres[ki].z;
      float o3 = acc[ki][3] * invH + bs.w; o3 = o3 > 0.f ? o3 : 0.01f * o3; o3 += hres[ki].w;
      float4 o4 = {o0, o1, o2, o3};
      *(float4*)&h[(nodebase + k) * HID + c4 * 4] = o4;
      if (DO_LN) {
        float sum = o0 + o1 + o2 + o3;
        #pragma unroll
        for (int off = 32; off; off >>= 1) sum += __shfl_xor(sum, off);
        float mu = sum * (1.f / 256.f);
        float d0 = o0 - mu, d1 = o1 - mu, d2 = o2 - mu, d3 = o3 - mu;
        float vs = d0 * d0 + d1 * d1 + d2 * d2 + d3 * d3;
        #pragma unroll
        for (int off = 32; off; off >>= 1) vs += __shfl_xor(vs, off);
        float rs = rsqrtf(vs * (1.f / 256.f) + 1e-5f);
        __hip_bfloat16 t[4];
        t[0] = __float2bfloat16(d0 * rs * gv.x + bv.x);
        t[1] = __float2bfloat16(d1 * rs * gv.y + bv.y);
        t[2] = __float2bfloat16(d2 * rs * gv.z + bv.z);
        t[3] = __float2bfloat16(d3 * rs * gv.w + bv.w);
        *(bf16x4*)&hn[(nodebase + k) * HID + c4 * 4] = *(bf16x4*)t;
      }
    }
  }
}

// ---------------------------------------------------------------------------
extern "C" void kernel_launch(void* const* d_in, const int* in_sizes, int n_in,
                              void* d_out, int out_size, void* d_ws, size_t ws_size,
                              hipStream_t stream) {
  const float* x     = (const float*)d_in[0];
  const int*   ei    = (const int*)d_in[1];
  const int*   pairs = (const int*)d_in[2];
  const float* bp    = (const float*)d_in[4];
  const float *lng[3], *lnb[3], *bl[3], *br[3], *att[3], *bias[3];
  const float *WlF[3], *WrF[3];
  for (int l = 0; l < 3; l++) {
    int base = 5 + l * 8;
    lng[l]  = (const float*)d_in[base + 0];
    lnb[l]  = (const float*)d_in[base + 1];
    WlF[l]  = (const float*)d_in[base + 2];
    bl[l]   = (const float*)d_in[base + 3];
    WrF[l]  = (const float*)d_in[base + 4];
    br[l]   = (const float*)d_in[base + 5];
    att[l]  = (const float*)d_in[base + 6];
    bias[l] = (const float*)d_in[base + 7];
  }
  const float* WmF[4] = {(const float*)d_in[29], (const float*)d_in[31],
                         (const float*)d_in[33], (const float*)d_in[35]};
  const float* bm[4] = {(const float*)d_in[30], (const float*)d_in[32],
                        (const float*)d_in[34], (const float*)d_in[36]};

  // workspace layout (float offsets)
  float* ws  = (float*)d_ws;
  float* h   = ws;                                           // [0, 7864320)
  __hip_bfloat16* hnb = (__hip_bfloat16*)(ws + 7864320);     // 3,932,160 bf
  __hip_bfloat16* xlcat = (__hip_bfloat16*)(ws + 11796480);  // xl-only: <= 23,592,960 bf
  float* logits0 = ws + 30000000;                            // 344,064 f (l=0)
  float* logits1 = logits0 + 344064;                         // 229,376 f (l=1)
  float* logits2 = logits1 + 229376;                         // 114,688 f (l=2)
  __hip_bfloat16* wbuf = (__hip_bfloat16*)(ws + 35733504);   // 999,424 bf
  int*   meta = (int*)(ws + 36233216);
  __hip_bfloat16* o1b = (__hip_bfloat16*)xlcat;              // pair out (xlcat dead then)
  float* out = (float*)d_out;

  // zero the logit accumulators (gemm_gat atomically adds into them)
  hipMemsetAsync(logits0, 0, (344064 + 229376 + 114688) * sizeof(float), stream);

  // bf16 transposed weight offsets (layouts unchanged from R0)
  const int oWp = 0, oWl0 = 32768, oWr0 = 229376, oWl1 = 425984, oWr1 = 557056;
  const int oWl2 = 688128, oWr2 = 753664, oWm0 = 819200, oWm1 = 950272, oWm2 = 983040;

  WtArgs wa;
  wa.j[0] = {(const float*)d_in[3], 128, 256,   0, oWp };
  wa.j[1] = {WlF[0],              256, 768,  32, oWl0};
  wa.j[2] = {WrF[0],              256, 768, 224, oWr0};
  wa.j[3] = {WlF[1],              256, 512, 416, oWl1};
  wa.j[4] = {WrF[1],              256, 512, 544, oWr1};
  wa.j[5] = {WlF[2],              256, 256, 672, oWl2};
  wa.j[6] = {WrF[2],              256, 256, 736, oWr2};
  wa.j[7] = {WmF[0],              512, 256, 800, oWm0};
  wa.j[8] = {WmF[1],              256, 128, 928, oWm1};
  wa.j[9] = {WmF[2],              128, 128, 960, oWm2};
  transpose_weights<<<977, 256, 0, stream>>>(wa, wbuf, ei, meta);  // block 976 = build_graph

  // h = x @ Wp + bp   (fp32 A staged with fused bf16 cast; fp32 out)
  gemm_mfma_f32a<0, 0><<<dim3(NTOT / 128, 2), 256, 0, stream>>>(x, wbuf + oWp, bp, h,
                                                                NTOT, 128, 256);

  layernorm<<<NTOT / 4, 256, 0, stream>>>(h, lng[0], lnb[0], hnb);

  const int Hs[3] = {3, 2, 1};
  const int oWl[3] = {oWl0, oWl1, oWl2};
  const int oWr[3] = {oWr0, oWr1, oWr2};
  float* logitsL[3] = {logits0, logits1, logits2};
  for (int l = 0; l < 3; l++) {
    int H = Hs[l];
    gemm_gat<<<dim3(NTOT / 120, H * 4), 256, 0, stream>>>(
        hnb, wbuf + oWl[l], wbuf + oWr[l], bl[l], br[l], att[l],
        xlcat, logitsL[l], meta, H);
    if (l < 2)
      gat_agg<1><<<B_GRAPH, 256, 0, stream>>>(xlcat, logitsL[l], bias[l], h,
                                              lng[l + 1], lnb[l + 1], hnb, meta, H);
    else
      gat_agg<0><<<B_GRAPH, 256, 0, stream>>>(xlcat, logitsL[l], bias[l], h,
                                              nullptr, nullptr, nullptr, meta, H);
  }

  gemm_mfma_pair<<<dim3(M_MLP / 128, 2), 256, 0, stream>>>(h, pairs, wbuf + oWm0, bm[0], o1b, 256);
  mlp_tail<<<M_MLP / 128, 256, 0, stream>>>(o1b, wbuf + oWm1, bm[1], wbuf + oWm2, bm[2],
                                            WmF[3], bm[3], out);
}

// Round 9
// 431.618 us; speedup vs baseline: 1.2457x; 1.0203x over previous
//
#include <hip/hip_runtime.h>
#include <hip/hip_bf16.h>
#include <math.h>

// Problem constants
#define N_NODES 30
#define E_BASE  82
#define E_TOT   112         // 82 edges + 30 self loops
#define B_GRAPH 1024
#define HID     256
#define NTOT    (B_GRAPH * N_NODES)   // 30720
#define MAXIN   32
#define N_EH    41
#define M_MLP   (B_GRAPH * N_EH)      // 41984

#define META_SRC  0
#define META_DST  E_TOT
#define META_CNT  (2 * E_TOT)
#define META_LIST 256
#define META_INTS 1216

typedef __attribute__((ext_vector_type(8))) short bf16x8;
typedef __attribute__((ext_vector_type(4))) short bf16x4;
typedef __attribute__((ext_vector_type(4))) float f32x4;
#define AS3 __attribute__((address_space(3)))
#define AS1 __attribute__((address_space(1)))

__device__ __forceinline__ void gload_lds16(const void* g, void* l) {
  __builtin_amdgcn_global_load_lds((const AS1 void*)g, (AS3 void*)l, 16, 0, 0);
}

// Bit-reinterpret ONLY — callers must pass raw bf16 bit patterns (short lanes
// of bf16x4/8 vectors). Never pass __hip_bfloat16 (would value-convert via
// float->short — the R3 NaN bug).
__device__ __forceinline__ float b2f(short s) {
  union { unsigned u; float f; } x;
  x.u = ((unsigned)(unsigned short)s) << 16;
  return x.f;
}

// float -> bf16 bit pattern (same rounding as __float2bfloat16; raw short out)
__device__ __forceinline__ short f2bf_bits(float f) {
  union { __hip_bfloat16 h; short s; } u;
  u.h = __float2bfloat16(f);
  return u.s;
}

// ---------------------------------------------------------------------------
// Transpose-cast all weights fp32 [K,N] -> bf16 [N,K]; block 976 instead
// builds the base-graph CSR (merged to save a launch).
// ---------------------------------------------------------------------------
struct WtJob { const float* in; int K, N, tstart, ooff; };
struct WtArgs { WtJob j[10]; };

__global__ __launch_bounds__(256)
void transpose_weights(WtArgs args, __hip_bfloat16* __restrict__ out,
                       const int* __restrict__ ei, int* __restrict__ meta) {
  int b = blockIdx.x;
  if (b == 976) {   // build_graph job
    __shared__ int cnt[N_NODES];
    int tid = threadIdx.x;
    if (tid < N_NODES) cnt[tid] = 0;
    __syncthreads();
    if (tid < E_TOT) {
      int s, d;
      if (tid < E_BASE) { s = ei[tid]; d = ei[B_GRAPH * E_BASE + tid]; }
      else              { s = tid - E_BASE; d = s; }
      meta[META_SRC + tid] = s;
      meta[META_DST + tid] = d;
      int pos = atomicAdd(&cnt[d], 1);
      if (pos < MAXIN) meta[META_LIST + d * MAXIN + pos] = tid;
    }
    __syncthreads();
    if (tid < N_NODES) meta[META_CNT + tid] = cnt[tid];
    return;
  }
  int ji = 0;
  #pragma unroll
  for (int i = 1; i < 10; i++) if (b >= args.j[i].tstart) ji = i;
  WtJob jb = args.j[ji];
  int t = b - jb.tstart;
  int ntn = jb.N >> 5;
  int tk = t / ntn, tn = t - tk * ntn;
  int k0 = tk * 32, n0 = tn * 32;
  __shared__ float s[32][33];
  int tx = threadIdx.x & 31, ty = threadIdx.x >> 5;
  #pragma unroll
  for (int p = 0; p < 4; p++)
    s[ty + p * 8][tx] = jb.in[(size_t)(k0 + ty + p * 8) * jb.N + n0 + tx];
  __syncthreads();
  __hip_bfloat16* o = out + jb.ooff;
  #pragma unroll
  for (int p = 0; p < 4; p++) {
    int n = ty + p * 8;
    o[(size_t)(n0 + n) * jb.K + k0 + tx] = __float2bfloat16(s[tx][n]);
  }
}

// ---------------------------------------------------------------------------
// R20 gemm_gat: layer GEMM with IN-KERNEL edge logits; xr never hits HBM.
// R20 logit-pass restructure (R7 falsified the epilogue theory — conflicts/
// VALU unchanged; the tail cost is the pass itself): 8 lanes/edge x 8 ch via
// ds_read_b128 (was 16 lanes x 4 ch, ds_read_b64); graph-outer loop so
// e = p*32+slot < 112 — NO integer division (was eidx/112 every pass);
// lrelu as fmax(z, 0.2z) (2 inst, identical values); 3 shfl (was 4).
// 16 predicated passes vs 28.
//
// Block (bm, bn): bn = h*4+cg covers head h, channel-group cg (64 ch).
//   cols 0-63  = xl channels (Wl rows), cols 64-127 = xr channels (Wr rows)
// M-tile = 120 rows = 4 WHOLE graphs (+8 pad rows, outputs discarded) so every
// edge's src/dst rows are in-block. atomicAdd partials into zeroed logitsG.
// bf16 rounding points identical to the R0 path (logits read back bf16 values).
// ---------------------------------------------------------------------------
#define XP 132   // padded xlr row stride (shorts)
__global__ __launch_bounds__(256)
void gemm_gat(const __hip_bfloat16* __restrict__ A,      // hnb [NTOT][256]
              const __hip_bfloat16* __restrict__ Wl,     // [H*256][256] bf16 (transposed)
              const __hip_bfloat16* __restrict__ Wr,
              const float* __restrict__ blv, const float* __restrict__ brv,
              const float* __restrict__ att,             // [H][256]
              __hip_bfloat16* __restrict__ xlcat,        // [NTOT][H*256]
              float* __restrict__ logitsG,               // [B][H][E_TOT], pre-zeroed
              const int* __restrict__ meta, int H)
{
  union GatSmem {
    struct { short a[2][4096]; short b[2][4096]; } st;   // 32 KB staging
    short xlr[128 * XP];                                  // 33.8 KB epilogue
  };
  __shared__ GatSmem sm;
  __shared__ int ssrc[E_TOT], sdst[E_TOT];

  const int tid = threadIdx.x;
  const int lane = tid & 63, wave = tid >> 6;
  const int wx = wave & 1, wy = wave >> 1;
  const int bm = blockIdx.x, bn = blockIdx.y;
  const int mrow = lane & 15, quad = lane >> 4;
  const int hh = bn >> 2, cg = bn & 3;
  const int K = HID;

  if (tid < E_TOT) { ssrc[tid] = meta[META_SRC + tid]; sdst[tid] = meta[META_DST + tid]; }

  const int r0 = tid >> 2, kc0 = (tid & 3) * 8;
  const int Ra = bm * 120 + r0;                              // rows 0..63: real
  const int Rb = bm * 120 + (r0 + 64 > 119 ? 119 : r0 + 64); // clamp pad rows
  const __hip_bfloat16* Ag0 = A + (size_t)Ra * K + kc0;
  const __hip_bfloat16* Ag1 = A + (size_t)Rb * K + kc0;
  const int brow = hh * 256 + cg * 64 + r0;                  // r0 in 0..63
  const __hip_bfloat16* Bg0 = Wl + (size_t)brow * K + kc0;   // cols 0-63  = xl
  const __hip_bfloat16* Bg1 = Wr + (size_t)brow * K + kc0;   // cols 64-127= xr

  f32x4 acc[4][4];
  #pragma unroll
  for (int i = 0; i < 4; i++)
    #pragma unroll
    for (int j = 0; j < 4; j++)
      acc[i][j] = (f32x4){0.f, 0.f, 0.f, 0.f};

  for (int kt = 0; kt < K; kt += 64) {
    __syncthreads();
    #pragma unroll
    for (int s = 0; s < 2; s++) {
      gload_lds16(Ag0 + kt + s * 32, &sm.st.a[s][tid * 8]);
      gload_lds16(Ag1 + kt + s * 32, &sm.st.a[s][2048 + tid * 8]);
      gload_lds16(Bg0 + kt + s * 32, &sm.st.b[s][tid * 8]);
      gload_lds16(Bg1 + kt + s * 32, &sm.st.b[s][2048 + tid * 8]);
    }
    __syncthreads();

    #pragma unroll
    for (int s = 0; s < 2; s++) {
      bf16x8 af[4], bfr[4];
      #pragma unroll
      for (int i = 0; i < 4; i++) {
        af[i]  = *(const bf16x8*)&sm.st.a[s][(wy * 64 + i * 16 + mrow) * 32 + quad * 8];
        bfr[i] = *(const bf16x8*)&sm.st.b[s][(wx * 64 + i * 16 + mrow) * 32 + quad * 8];
      }
      #pragma unroll
      for (int i = 0; i < 4; i++)
        #pragma unroll
        for (int j = 0; j < 4; j++)
          acc[i][j] = __builtin_amdgcn_mfma_f32_16x16x32_bf16(bfr[j], af[i], acc[i][j], 0, 0, 0);
    }
  }

  __syncthreads();   // K-loop LDS reads done; safe to repurpose union as xlr

  // ---- epilogue (transposed fragment): bias + bf16 -> LDS, 16x ds_write_b64.
  // acc[i][j][r] = C[row = wy*64+i*16+mrow][col = wx*64+j*16+quad*4+r]
  const float* bb = wx ? brv : blv;
  #pragma unroll
  for (int i = 0; i < 4; i++) {
    int lrow = wy * 64 + i * 16 + mrow;
    #pragma unroll
    for (int j = 0; j < 4; j++) {
      int c0 = j * 16 + quad * 4;               // 0..63 within half
      float4 bc = *(const float4*)&bb[hh * 256 + cg * 64 + c0];
      short t[4];
      t[0] = f2bf_bits(acc[i][j][0] + bc.x);
      t[1] = f2bf_bits(acc[i][j][1] + bc.y);
      t[2] = f2bf_bits(acc[i][j][2] + bc.z);
      t[3] = f2bf_bits(acc[i][j][3] + bc.w);
      *(bf16x4*)&sm.xlr[lrow * XP + wx * 64 + c0] = *(bf16x4*)t;
    }
  }
  __syncthreads();

  // ---- cooperative vectorized store of the xl half (120 rows x 64 ch) ----
  // 960 16B chunks; chunk c -> row c>>3, part c&7. 128B contiguous per row.
  {
    const size_t SROW = (size_t)H * HID;
    #pragma unroll
    for (int p = 0; p < 4; p++) {
      int c = tid + p * 256;
      if (c < 960) {
        int row = c >> 3, part = c & 7;
        bf16x8 v = *(const bf16x8*)&sm.xlr[row * XP + part * 8];
        *(bf16x8*)&((short*)xlcat)[((size_t)bm * 120 + row) * SROW
                                   + hh * HID + cg * 64 + part * 8] = v;
      }
    }
  }

  // ---- logit partials (R20): 8 lanes/edge x 8 ch; graph-outer, no division.
  const int slot = tid >> 3, esub = tid & 7;   // 32 edge-slots, 8 lanes/edge
  float av[8];
  #pragma unroll
  for (int i = 0; i < 8; i++) av[i] = att[hh * HID + cg * 64 + esub * 8 + i];
  #pragma unroll
  for (int gl = 0; gl < 4; gl++) {
    #pragma unroll
    for (int p = 0; p < 4; p++) {
      int e = p * 32 + slot;
      if (e < E_TOT) {
        int rs = gl * 30 + ssrc[e], rd = gl * 30 + sdst[e];
        bf16x8 xlv = *(const bf16x8*)&sm.xlr[rs * XP + esub * 8];
        bf16x8 xrv = *(const bf16x8*)&sm.xlr[rd * XP + 64 + esub * 8];
        float sum = 0.f;
        #pragma unroll
        for (int i = 0; i < 8; i++) {
          float z = b2f(xlv[i]) + b2f(xrv[i]);
          z = fmaxf(z, 0.2f * z);               // == lrelu(z,0.2), 2 inst
          sum = fmaf(z, av[i], sum);
        }
        sum += __shfl_xor(sum, 1);
        sum += __shfl_xor(sum, 2);
        sum += __shfl_xor(sum, 4);
        if (esub == 0)
          atomicAdd(&logitsG[((size_t)(bm * 4 + gl) * H + hh) * E_TOT + e], sum);
      }
    }
  }
}

// ---------------------------------------------------------------------------
// MFMA GEMM with fp32 A staged via in-register bf16 cast (fused cast): proj.
// (EXACT R0 version.)
// ---------------------------------------------------------------------------
template<int ACT, int OUTBF>
__global__ __launch_bounds__(256)
void gemm_mfma_f32a(const float* __restrict__ A, const __hip_bfloat16* __restrict__ Bt,
                    const float* __restrict__ bias, void* __restrict__ Cv,
                    int M, int K, int N)
{
  __shared__ __hip_bfloat16 sA[128 * 32];
  __shared__ __hip_bfloat16 sB[128 * 32];
  const int tid = threadIdx.x;
  const int lane = tid & 63;
  const int wave = tid >> 6;
  const int wx = wave & 1, wy = wave >> 1;
  const int bm = blockIdx.x, bn = blockIdx.y;
  const int mrow = lane & 15, quad = lane >> 4;

  const int r0 = tid >> 2, kc0 = (tid & 3) * 8;
  const float* Ag0 = A + (size_t)(bm * 128 + r0) * K + kc0;
  const float* Ag1 = A + (size_t)(bm * 128 + r0 + 64) * K + kc0;
  const __hip_bfloat16* Bg0 = Bt + (size_t)(bn * 128 + r0) * K + kc0;
  const __hip_bfloat16* Bg1 = Bt + (size_t)(bn * 128 + r0 + 64) * K + kc0;

  f32x4 acc[4][4];
  #pragma unroll
  for (int i = 0; i < 4; i++)
    #pragma unroll
    for (int j = 0; j < 4; j++)
      acc[i][j] = (f32x4){0.f, 0.f, 0.f, 0.f};

  for (int kt = 0; kt < K; kt += 32) {
    float4 a00 = *(const float4*)(Ag0 + kt);
    float4 a01 = *(const float4*)(Ag0 + kt + 4);
    float4 a10 = *(const float4*)(Ag1 + kt);
    float4 a11 = *(const float4*)(Ag1 + kt + 4);
    __syncthreads();
    {
      __hip_bfloat16 t[8];
      t[0] = __float2bfloat16(a00.x); t[1] = __float2bfloat16(a00.y);
      t[2] = __float2bfloat16(a00.z); t[3] = __float2bfloat16(a00.w);
      t[4] = __float2bfloat16(a01.x); t[5] = __float2bfloat16(a01.y);
      t[6] = __float2bfloat16(a01.z); t[7] = __float2bfloat16(a01.w);
      *(bf16x8*)&sA[tid * 8] = *(bf16x8*)t;
      t[0] = __float2bfloat16(a10.x); t[1] = __float2bfloat16(a10.y);
      t[2] = __float2bfloat16(a10.z); t[3] = __float2bfloat16(a10.w);
      t[4] = __float2bfloat16(a11.x); t[5] = __float2bfloat16(a11.y);
      t[6] = __float2bfloat16(a11.z); t[7] = __float2bfloat16(a11.w);
      *(bf16x8*)&sA[2048 + tid * 8] = *(bf16x8*)t;
    }
    gload_lds16(Bg0 + kt, &sB[tid * 8]);
    gload_lds16(Bg1 + kt, &sB[2048 + tid * 8]);
    __syncthreads();

    bf16x8 af[4], bfr[4];
    #pragma unroll
    for (int i = 0; i < 4; i++) {
      af[i]  = *(const bf16x8*)&sA[(wy * 64 + i * 16 + mrow) * 32 + quad * 8];
      bfr[i] = *(const bf16x8*)&sB[(wx * 64 + i * 16 + mrow) * 32 + quad * 8];
    }
    #pragma unroll
    for (int i = 0; i < 4; i++)
      #pragma unroll
      for (int j = 0; j < 4; j++)
        acc[i][j] = __builtin_amdgcn_mfma_f32_16x16x32_bf16(af[i], bfr[j], acc[i][j], 0, 0, 0);
  }

  #pragma unroll
  for (int i = 0; i < 4; i++) {
    #pragma unroll
    for (int r = 0; r < 4; r++) {
      size_t row = (size_t)bm * 128 + wy * 64 + i * 16 + quad * 4 + r;
      #pragma unroll
      for (int j = 0; j < 4; j++) {
        int col = bn * 128 + wx * 64 + j * 16 + mrow;
        float v = acc[i][j][r] + bias[col];
        if (ACT) v = v > 0.f ? v : 0.01f * v;
        if (OUTBF) ((__hip_bfloat16*)Cv)[row * N + col] = __float2bfloat16(v);
        else       ((float*)Cv)[row * N + col] = v;
      }
    }
  }
}

// ---------------------------------------------------------------------------
// R20 gemm_mfma_pair: fused edge-pair gather GEMM, A now read from the bf16
// h copy (hb, written by gat_agg l=2 with identical __float2bfloat16 rounding
// to the old in-register cast -> bit-identical A operand). A is staged by
// DIRECT per-lane global_load_lds (gather source addresses are per-lane legal;
// LDS dest is lane-linear) — halves the 86 MB A-fetch and deletes the
// float4-load + cast staging.
// A-row r = concat(hb[b,u], hb[b,v]) with b=r/41, (u,v)=pairs[r%41]; K=512.
// C = lrelu(A @ Bt + bias), bf16 out.
// ---------------------------------------------------------------------------
__global__ __launch_bounds__(256)
void gemm_mfma_pair(const __hip_bfloat16* __restrict__ hb, const int* __restrict__ pairs,
                    const __hip_bfloat16* __restrict__ Bt, const float* __restrict__ bias,
                    __hip_bfloat16* __restrict__ C, int N)
{
  const int K = 512;
  __shared__ __hip_bfloat16 sA[128 * 32];
  __shared__ __hip_bfloat16 sB[128 * 32];
  const int tid = threadIdx.x;
  const int lane = tid & 63;
  const int wave = tid >> 6;
  const int wx = wave & 1, wy = wave >> 1;
  const int bm = blockIdx.x, bn = blockIdx.y;
  const int mrow = lane & 15, quad = lane >> 4;

  const __hip_bfloat16* pu[2]; const __hip_bfloat16* pv[2]; int sub[2];
  #pragma unroll
  for (int cI = 0; cI < 2; cI++) {
    int c = tid + cI * 256;
    int rc = c >> 2; sub[cI] = (c & 3) * 8;        // 8-ch (16B) sub-chunk
    int R = bm * 128 + rc;
    int b = R / N_EH, p = R - b * N_EH;
    int u = pairs[p * 2], v = pairs[p * 2 + 1];
    pu[cI] = hb + ((size_t)b * N_NODES + u) * HID;
    pv[cI] = hb + ((size_t)b * N_NODES + v) * HID;
  }

  const int r0 = tid >> 2, kc0 = (tid & 3) * 8;
  const __hip_bfloat16* Bg0 = Bt + (size_t)(bn * 128 + r0) * K + kc0;
  const __hip_bfloat16* Bg1 = Bt + (size_t)(bn * 128 + r0 + 64) * K + kc0;

  f32x4 acc[4][4];
  #pragma unroll
  for (int i = 0; i < 4; i++)
    #pragma unroll
    for (int j = 0; j < 4; j++)
      acc[i][j] = (f32x4){0.f, 0.f, 0.f, 0.f};

  for (int kt = 0; kt < K; kt += 32) {
    __syncthreads();
    #pragma unroll
    for (int cI = 0; cI < 2; cI++) {
      const __hip_bfloat16* src = (kt < 256 ? pu[cI] + kt : pv[cI] + kt - 256) + sub[cI];
      gload_lds16(src, &sA[(size_t)(tid + cI * 256) * 8]);
    }
    gload_lds16(Bg0 + kt, &sB[tid * 8]);
    gload_lds16(Bg1 + kt, &sB[2048 + tid * 8]);
    __syncthreads();

    bf16x8 af[4], bfr[4];
    #pragma unroll
    for (int i = 0; i < 4; i++) {
      af[i]  = *(const bf16x8*)&sA[(wy * 64 + i * 16 + mrow) * 32 + quad * 8];
      bfr[i] = *(const bf16x8*)&sB[(wx * 64 + i * 16 + mrow) * 32 + quad * 8];
    }
    #pragma unroll
    for (int i = 0; i < 4; i++)
      #pragma unroll
      for (int j = 0; j < 4; j++)
        acc[i][j] = __builtin_amdgcn_mfma_f32_16x16x32_bf16(af[i], bfr[j], acc[i][j], 0, 0, 0);
  }

  #pragma unroll
  for (int i = 0; i < 4; i++) {
    #pragma unroll
    for (int r = 0; r < 4; r++) {
      size_t row = (size_t)bm * 128 + wy * 64 + i * 16 + quad * 4 + r;
      #pragma unroll
      for (int j = 0; j < 4; j++) {
        int col = bn * 128 + wx * 64 + j * 16 + mrow;
        float v = acc[i][j][r] + bias[col];
        v = v > 0.f ? v : 0.01f * v;
        C[row * N + col] = __float2bfloat16(v);
      }
    }
  }
}

// ---------------------------------------------------------------------------
// Fused MLP tail (R11 — proven win; EXACT R0 version).
// ---------------------------------------------------------------------------
#define O2P 136
__global__ __launch_bounds__(256)
void mlp_tail(const __hip_bfloat16* __restrict__ o1, const __hip_bfloat16* __restrict__ W1t,
              const float* __restrict__ b1, const __hip_bfloat16* __restrict__ W2t,
              const float* __restrict__ b2, const float* __restrict__ w3,
              const float* __restrict__ b3, float* __restrict__ out)
{
  __shared__ __hip_bfloat16 sA[128 * 32];
  __shared__ __hip_bfloat16 sB[128 * 32];
  __shared__ __hip_bfloat16 sO2[128 * O2P];
  __shared__ float spart[2][128];
  const int tid = threadIdx.x;
  const int lane = tid & 63;
  const int wave = tid >> 6;
  const int wx = wave & 1, wy = wave >> 1;
  const int bm = blockIdx.x;
  const int mrow = lane & 15, quad = lane >> 4;
  const int r0 = tid >> 2, kc0 = (tid & 3) * 8;

  const __hip_bfloat16* Ag0 = o1 + (size_t)(bm * 128 + r0) * 256 + kc0;
  const __hip_bfloat16* Ag1 = o1 + (size_t)(bm * 128 + r0 + 64) * 256 + kc0;
  const __hip_bfloat16* Bg0 = W1t + (size_t)r0 * 256 + kc0;
  const __hip_bfloat16* Bg1 = W1t + (size_t)(r0 + 64) * 256 + kc0;

  f32x4 acc[4][4];
  #pragma unroll
  for (int i = 0; i < 4; i++)
    #pragma unroll
    for (int j = 0; j < 4; j++)
      acc[i][j] = (f32x4){0.f, 0.f, 0.f, 0.f};

  for (int kt = 0; kt < 256; kt += 32) {
    __syncthreads();
    gload_lds16(Ag0 + kt, &sA[tid * 8]);
    gload_lds16(Ag1 + kt, &sA[2048 + tid * 8]);
    gload_lds16(Bg0 + kt, &sB[tid * 8]);
    gload_lds16(Bg1 + kt, &sB[2048 + tid * 8]);
    __syncthreads();

    bf16x8 af[4], bfr[4];
    #pragma unroll
    for (int i = 0; i < 4; i++) {
      af[i]  = *(const bf16x8*)&sA[(wy * 64 + i * 16 + mrow) * 32 + quad * 8];
      bfr[i] = *(const bf16x8*)&sB[(wx * 64 + i * 16 + mrow) * 32 + quad * 8];
    }
    #pragma unroll
    for (int i = 0; i < 4; i++)
      #pragma unroll
      for (int j = 0; j < 4; j++)
        acc[i][j] = __builtin_amdgcn_mfma_f32_16x16x32_bf16(af[i], bfr[j], acc[i][j], 0, 0, 0);
  }

  __syncthreads();
  #pragma unroll
  for (int i = 0; i < 4; i++) {
    #pragma unroll
    for (int r = 0; r < 4; r++) {
      int row = wy * 64 + i * 16 + quad * 4 + r;
      #pragma unroll
      for (int j = 0; j < 4; j++) {
        int col = wx * 64 + j * 16 + mrow;
        float v = acc[i][j][r] + b1[col];
        v = v > 0.f ? v : 0.01f * v;
        sO2[row * O2P + col] = __float2bfloat16(v);
      }
    }
  }

  f32x4 acc2[4][4];
  #pragma unroll
  for (int i = 0; i < 4; i++)
    #pragma unroll
    for (int j = 0; j < 4; j++)
      acc2[i][j] = (f32x4){0.f, 0.f, 0.f, 0.f};

  for (int kt = 0; kt < 128; kt += 32) {
    __syncthreads();
    gload_lds16(W2t + (size_t)r0 * 128 + kt + kc0, &sB[tid * 8]);
    gload_lds16(W2t + (size_t)(r0 + 64) * 128 + kt + kc0, &sB[2048 + tid * 8]);
    __syncthreads();

    bf16x8 af[4], bfr[4];
    #pragma unroll
    for (int i = 0; i < 4; i++) {
      af[i]  = *(const bf16x8*)&sO2[(wy * 64 + i * 16 + mrow) * O2P + kt + quad * 8];
      bfr[i] = *(const bf16x8*)&sB[(wx * 64 + i * 16 + mrow) * 32 + quad * 8];
    }
    #pragma unroll
    for (int i = 0; i < 4; i++)
      #pragma unroll
      for (int j = 0; j < 4; j++)
        acc2[i][j] = __builtin_amdgcn_mfma_f32_16x16x32_bf16(af[i], bfr[j], acc2[i][j], 0, 0, 0);
  }

  float w3v[4], b2v[4];
  #pragma unroll
  for (int j = 0; j < 4; j++) {
    int col = wx * 64 + j * 16 + mrow;
    w3v[j] = w3[col];
    b2v[j] = b2[col];
  }
  #pragma unroll
  for (int i = 0; i < 4; i++) {
    #pragma unroll
    for (int r = 0; r < 4; r++) {
      float s = 0.f;
      #pragma unroll
      for (int j = 0; j < 4; j++) {
        float v = acc2[i][j][r] + b2v[j];
        v = v > 0.f ? v : 0.01f * v;
        s += v * w3v[j];
      }
      #pragma unroll
      for (int off = 8; off; off >>= 1) s += __shfl_xor(s, off);
      if (mrow == 0) {
        int row = wy * 64 + i * 16 + quad * 4 + r;
        spart[wx][row] = s;
      }
    }
  }
  __syncthreads();
  if (tid < 128)
    out[(size_t)bm * 128 + tid] = spart[0][tid] + spart[1][tid] + b3[0];
}

// ---------------------------------------------------------------------------
// LayerNorm over HID=256; one wave per row; writes bf16. (Used once, after proj.)
// ---------------------------------------------------------------------------
__global__ __launch_bounds__(256)
void layernorm(const float* __restrict__ h, const float* __restrict__ g,
               const float* __restrict__ b, __hip_bfloat16* __restrict__ hn)
{
  const int wv = threadIdx.x >> 6, lane = threadIdx.x & 63;
  const size_t row = (size_t)blockIdx.x * 4 + wv;
  const float* hr = h + row * HID;
  float v[4];
  float sum = 0.f;
  #pragma unroll
  for (int j = 0; j < 4; j++) { v[j] = hr[lane + 64 * j]; sum += v[j]; }
  #pragma unroll
  for (int off = 32; off; off >>= 1) sum += __shfl_xor(sum, off);
  float mu = sum * (1.f / 256.f);
  float vs = 0.f;
  #pragma unroll
  for (int j = 0; j < 4; j++) { float d = v[j] - mu; vs += d * d; }
  #pragma unroll
  for (int off = 32; off; off >>= 1) vs += __shfl_xor(vs, off);
  float rs = rsqrtf(vs * (1.f / 256.f) + 1e-5f);
  __hip_bfloat16* outr = hn + row * HID;
  #pragma unroll
  for (int j = 0; j < 4; j++) {
    int c = lane + 64 * j;
    outr[c] = __float2bfloat16((v[j] - mu) * rs * g[c] + b[c]);
  }
}

// ---------------------------------------------------------------------------
// R20 gat_agg: aggregation + h update with folded per-head softmax (R19) and,
// for DO_LN==0 (last layer), a bf16 copy of the FINAL h written to hn (=hnb,
// dead after gemm_gat l=2) — feeds gemm_mfma_pair's bf16 gather. Rounding is
// the same __float2bfloat16(h) the pair kernel previously did in-register.
// xcat is xl-only: row stride S = H*HID.
// One block per graph; thread = (channel-quad c4, node-group ng).
// ---------------------------------------------------------------------------
template<int DO_LN>
__global__ __launch_bounds__(256, 4)
void gat_agg(const __hip_bfloat16* __restrict__ xcat, const float* __restrict__ logitsG,
             const float* __restrict__ bias, float* __restrict__ h,
             const float* __restrict__ lnG, const float* __restrict__ lnB,
             __hip_bfloat16* __restrict__ hn, const int* __restrict__ meta, int H)
{
  __shared__ __hip_bfloat16 sxl[2][N_NODES * HID];   // 2 x 15 KB, head double-buffer
  __shared__ float salpha[3][E_TOT];                 // all heads (H <= 3)
  __shared__ float slog[E_TOT], smax[N_NODES], sden[N_NODES];
  __shared__ int ssrc[E_TOT], sdst[E_TOT], scnt[N_NODES], slist[N_NODES * MAXIN];

  const int tid = threadIdx.x;
  const int g = blockIdx.x;
  const size_t nodebase = (size_t)g * N_NODES;
  const int S = H * HID;                    // xl-only stride
  const int c4 = tid & 63;
  const int ng = tid >> 6;

  if (tid < E_TOT) { ssrc[tid] = meta[META_SRC + tid]; sdst[tid] = meta[META_DST + tid]; }
  if (tid < N_NODES) scnt[tid] = meta[META_CNT + tid];
  for (int i = tid; i < N_NODES * MAXIN; i += 256) slist[i] = meta[META_LIST + i];

  float4 hres[8];
  #pragma unroll
  for (int ki = 0; ki < 8; ki++) {
    int k = ng + ki * 4;
    if (k < N_NODES) hres[ki] = *(const float4*)&h[(nodebase + k) * HID + c4 * 4];
  }

  // issue stage of head 0's xl (async; overlaps with the softmax below)
  {
    int i = tid;
    #pragma unroll
    for (int p = 0; p < 4; p++, i += 256) {
      if (i < N_NODES * HID / 8) {
        int node = i >> 5, c = (i & 31) * 8;
        gload_lds16(&xcat[(nodebase + node) * S + 0 * HID + c], &sxl[0][(size_t)i * 8]);
      }
    }
  }

  // ---- in-block softmax for all H heads (proven gat_alpha tail) ----
  for (int hh = 0; hh < H; hh++) {
    if (tid < E_TOT) slog[tid] = logitsG[((size_t)g * H + hh) * E_TOT + tid];
    if (tid < N_NODES) sden[tid] = 0.f;
    __syncthreads();
    if (tid < N_NODES) {
      int cnt = scnt[tid];
      const int* lst = &slist[tid * MAXIN];
      float m = -1e30f;
      for (int i = 0; i < cnt; i++) m = fmaxf(m, slog[lst[i]]);
      smax[tid] = m;
    }
    __syncthreads();
    if (tid < E_TOT) {
      float ex = expf(slog[tid] - smax[sdst[tid]]);
      slog[tid] = ex;
      atomicAdd(&sden[sdst[tid]], ex);
    }
    __syncthreads();
    if (tid < E_TOT) salpha[hh][tid] = slog[tid] / sden[sdst[tid]];
  }

  float acc[8][4];
  #pragma unroll
  for (int ki = 0; ki < 8; ki++)
    #pragma unroll
    for (int j = 0; j < 4; j++) acc[ki][j] = 0.f;

  for (int hh = 0; hh < H; hh++) {
    const int buf = hh & 1;
    __syncthreads();   // staged loads drained; salpha ready (first iter)
    if (hh + 1 < H) {
      const int nb = buf ^ 1;
      int i = tid;
      #pragma unroll
      for (int p = 0; p < 4; p++, i += 256) {
        if (i < N_NODES * HID / 8) {
          int node = i >> 5, c = (i & 31) * 8;
          gload_lds16(&xcat[(nodebase + node) * S + (hh + 1) * HID + c], &sxl[nb][(size_t)i * 8]);
        }
      }
    }
    #pragma unroll
    for (int ki = 0; ki < 8; ki++) {
      int k = ng + ki * 4;
      if (k < N_NODES) {
        int cnt = scnt[k];
        const int* lst = &slist[k * MAXIN];
        for (int i = 0; i < cnt; i++) {
          int e = lst[i];                       // wave-uniform broadcast reads
          float al = salpha[hh][e];
          bf16x4 v = *(const bf16x4*)&sxl[buf][ssrc[e] * HID + c4 * 4];
          acc[ki][0] += al * b2f(v[0]);
          acc[ki][1] += al * b2f(v[1]);
          acc[ki][2] += al * b2f(v[2]);
          acc[ki][3] += al * b2f(v[3]);
        }
      }
    }
  }

  const float invH = 1.f / (float)H;
  const float4 bs = *(const float4*)&bias[c4 * 4];
  float4 gv, bv;
  if (DO_LN) {
    gv = *(const float4*)&lnG[c4 * 4];
    bv = *(const float4*)&lnB[c4 * 4];
  }
  #pragma unroll
  for (int ki = 0; ki < 8; ki++) {
    int k = ng + ki * 4;
    if (k < N_NODES) {
      float o0 = acc[ki][0] * invH + bs.x; o0 = o0 > 0.f ? o0 : 0.01f * o0; o0 += hres[ki].x;
      float o1 = acc[ki][1] * invH + bs.y; o1 = o1 > 0.f ? o1 : 0.01f * o1; o1 += hres[ki].y;
      float o2 = acc[ki][2] * invH + bs.z; o2 = o2 > 0.f ? o2 : 0.01f * o2; o2 += hres[ki].z;
      float o3 = acc[ki][3] * invH + bs.w; o3 = o3 > 0.f ? o3 : 0.01f * o3; o3 += hres[ki].w;
      float4 o4 = {o0, o1, o2, o3};
      *(float4*)&h[(nodebase + k) * HID + c4 * 4] = o4;
      if (DO_LN) {
        float sum = o0 + o1 + o2 + o3;
        #pragma unroll
        for (int off = 32; off; off >>= 1) sum += __shfl_xor(sum, off);
        float mu = sum * (1.f / 256.f);
        float d0 = o0 - mu, d1 = o1 - mu, d2 = o2 - mu, d3 = o3 - mu;
        float vs = d0 * d0 + d1 * d1 + d2 * d2 + d3 * d3;
        #pragma unroll
        for (int off = 32; off; off >>= 1) vs += __shfl_xor(vs, off);
        float rs = rsqrtf(vs * (1.f / 256.f) + 1e-5f);
        __hip_bfloat16 t[4];
        t[0] = __float2bfloat16(d0 * rs * gv.x + bv.x);
        t[1] = __float2bfloat16(d1 * rs * gv.y + bv.y);
        t[2] = __float2bfloat16(d2 * rs * gv.z + bv.z);
        t[3] = __float2bfloat16(d3 * rs * gv.w + bv.w);
        *(bf16x4*)&hn[(nodebase + k) * HID + c4 * 4] = *(bf16x4*)t;
      } else {
        // bf16 copy of final h for the pair-GEMM gather (R20)
        short t[4];
        t[0] = f2bf_bits(o0); t[1] = f2bf_bits(o1);
        t[2] = f2bf_bits(o2); t[3] = f2bf_bits(o3);
        *(bf16x4*)&hn[(nodebase + k) * HID + c4 * 4] = *(bf16x4*)t;
      }
    }
  }
}

// ---------------------------------------------------------------------------
extern "C" void kernel_launch(void* const* d_in, const int* in_sizes, int n_in,
                              void* d_out, int out_size, void* d_ws, size_t ws_size,
                              hipStream_t stream) {
  const float* x     = (const float*)d_in[0];
  const int*   ei    = (const int*)d_in[1];
  const int*   pairs = (const int*)d_in[2];
  const float* bp    = (const float*)d_in[4];
  const float *lng[3], *lnb[3], *bl[3], *br[3], *att[3], *bias[3];
  const float *WlF[3], *WrF[3];
  for (int l = 0; l < 3; l++) {
    int base = 5 + l * 8;
    lng[l]  = (const float*)d_in[base + 0];
    lnb[l]  = (const float*)d_in[base + 1];
    WlF[l]  = (const float*)d_in[base + 2];
    bl[l]   = (const float*)d_in[base + 3];
    WrF[l]  = (const float*)d_in[base + 4];
    br[l]   = (const float*)d_in[base + 5];
    att[l]  = (const float*)d_in[base + 6];
    bias[l] = (const float*)d_in[base + 7];
  }
  const float* WmF[4] = {(const float*)d_in[29], (const float*)d_in[31],
                         (const float*)d_in[33], (const float*)d_in[35]};
  const float* bm[4] = {(const float*)d_in[30], (const float*)d_in[32],
                        (const float*)d_in[34], (const float*)d_in[36]};

  // workspace layout (float offsets)
  float* ws  = (float*)d_ws;
  float* h   = ws;                                           // [0, 7864320)
  __hip_bfloat16* hnb = (__hip_bfloat16*)(ws + 7864320);     // 3,932,160 bf
  __hip_bfloat16* xlcat = (__hip_bfloat16*)(ws + 11796480);  // xl-only: <= 23,592,960 bf
  float* logits0 = ws + 30000000;                            // 344,064 f (l=0)
  float* logits1 = logits0 + 344064;                         // 229,376 f (l=1)
  float* logits2 = logits1 + 229376;                         // 114,688 f (l=2)
  __hip_bfloat16* wbuf = (__hip_bfloat16*)(ws + 35733504);   // 999,424 bf
  int*   meta = (int*)(ws + 36233216);
  __hip_bfloat16* o1b = (__hip_bfloat16*)xlcat;              // pair out (xlcat dead then)
  float* out = (float*)d_out;

  // zero the logit accumulators (gemm_gat atomically adds into them)
  hipMemsetAsync(logits0, 0, (344064 + 229376 + 114688) * sizeof(float), stream);

  // bf16 transposed weight offsets (layouts unchanged from R0)
  const int oWp = 0, oWl0 = 32768, oWr0 = 229376, oWl1 = 425984, oWr1 = 557056;
  const int oWl2 = 688128, oWr2 = 753664, oWm0 = 819200, oWm1 = 950272, oWm2 = 983040;

  WtArgs wa;
  wa.j[0] = {(const float*)d_in[3], 128, 256,   0, oWp };
  wa.j[1] = {WlF[0],              256, 768,  32, oWl0};
  wa.j[2] = {WrF[0],              256, 768, 224, oWr0};
  wa.j[3] = {WlF[1],              256, 512, 416, oWl1};
  wa.j[4] = {WrF[1],              256, 512, 544, oWr1};
  wa.j[5] = {WlF[2],              256, 256, 672, oWl2};
  wa.j[6] = {WrF[2],              256, 256, 736, oWr2};
  wa.j[7] = {WmF[0],              512, 256, 800, oWm0};
  wa.j[8] = {WmF[1],              256, 128, 928, oWm1};
  wa.j[9] = {WmF[2],              128, 128, 960, oWm2};
  transpose_weights<<<977, 256, 0, stream>>>(wa, wbuf, ei, meta);  // block 976 = build_graph

  // h = x @ Wp + bp   (fp32 A staged with fused bf16 cast; fp32 out)
  gemm_mfma_f32a<0, 0><<<dim3(NTOT / 128, 2), 256, 0, stream>>>(x, wbuf + oWp, bp, h,
                                                                NTOT, 128, 256);

  layernorm<<<NTOT / 4, 256, 0, stream>>>(h, lng[0], lnb[0], hnb);

  const int Hs[3] = {3, 2, 1};
  const int oWl[3] = {oWl0, oWl1, oWl2};
  const int oWr[3] = {oWr0, oWr1, oWr2};
  float* logitsL[3] = {logits0, logits1, logits2};
  for (int l = 0; l < 3; l++) {
    int H = Hs[l];
    gemm_gat<<<dim3(NTOT / 120, H * 4), 256, 0, stream>>>(
        hnb, wbuf + oWl[l], wbuf + oWr[l], bl[l], br[l], att[l],
        xlcat, logitsL[l], meta, H);
    if (l < 2)
      gat_agg<1><<<B_GRAPH, 256, 0, stream>>>(xlcat, logitsL[l], bias[l], h,
                                              lng[l + 1], lnb[l + 1], hnb, meta, H);
    else
      gat_agg<0><<<B_GRAPH, 256, 0, stream>>>(xlcat, logitsL[l], bias[l], h,
                                              nullptr, nullptr, hnb, meta, H);
  }

  // pair-GEMM reads the bf16 h copy (hnb) written by gat_agg l=2
  gemm_mfma_pair<<<dim3(M_MLP / 128, 2), 256, 0, stream>>>(hnb, pairs, wbuf + oWm0, bm[0], o1b, 256);
  mlp_tail<<<M_MLP / 128, 256, 0, stream>>>(o1b, wbuf + oWm1, bm[1], wbuf + oWm2, bm[2],
                                            WmF[3], bm[3], out);
}

// Round 11
// 425.537 us; speedup vs baseline: 1.2635x; 1.0143x over previous
//
#include <hip/hip_runtime.h>
#include <hip/hip_bf16.h>
#include <math.h>

// Problem constants
#define N_NODES 30
#define E_BASE  82
#define E_TOT   112         // 82 edges + 30 self loops
#define B_GRAPH 1024
#define HID     256
#define NTOT    (B_GRAPH * N_NODES)   // 30720
#define MAXIN   32
#define N_EH    41
#define M_MLP   (B_GRAPH * N_EH)      // 41984

#define META_SRC  0
#define META_DST  E_TOT
#define META_CNT  (2 * E_TOT)
#define META_LIST 256
#define META_INTS 1216

typedef __attribute__((ext_vector_type(8))) short bf16x8;
typedef __attribute__((ext_vector_type(4))) short bf16x4;
typedef __attribute__((ext_vector_type(4))) float f32x4;
#define AS3 __attribute__((address_space(3)))
#define AS1 __attribute__((address_space(1)))

__device__ __forceinline__ void gload_lds16(const void* g, void* l) {
  __builtin_amdgcn_global_load_lds((const AS1 void*)g, (AS3 void*)l, 16, 0, 0);
}

// Bit-reinterpret ONLY — callers must pass raw bf16 bit patterns (short lanes
// of bf16x4/8 vectors). Never pass __hip_bfloat16 (would value-convert via
// float->short — the R3 NaN bug).
__device__ __forceinline__ float b2f(short s) {
  union { unsigned u; float f; } x;
  x.u = ((unsigned)(unsigned short)s) << 16;
  return x.f;
}

// float -> bf16 bit pattern (same rounding as __float2bfloat16; raw short out)
__device__ __forceinline__ short f2bf_bits(float f) {
  union { __hip_bfloat16 h; short s; } u;
  u.h = __float2bfloat16(f);
  return u.s;
}

// ---------------------------------------------------------------------------
// Transpose-cast all weights fp32 [K,N] -> bf16 [N,K]. Block 976 builds the
// base-graph CSR (R21: slist entries PACKED as (e<<8)|src — shortens gat_agg's
// LDS dependency chain by one level). Blocks 977+ zero the logit accumulators
// (replaces the hipMemsetAsync launch).
// ---------------------------------------------------------------------------
struct WtJob { const float* in; int K, N, tstart, ooff; };
struct WtArgs { WtJob j[10]; };

__global__ __launch_bounds__(256)
void transpose_weights(WtArgs args, __hip_bfloat16* __restrict__ out,
                       const int* __restrict__ ei, int* __restrict__ meta,
                       float* __restrict__ logitsZ) {
  int b = blockIdx.x;
  if (b >= 977) {   // zero logits: 168 blocks x 4096 floats = 688128
    int base = (b - 977) * 4096 + threadIdx.x * 4;
    *(float4*)&logitsZ[base] = (float4){0.f, 0.f, 0.f, 0.f};
    return;
  }
  if (b == 976) {   // build_graph job
    __shared__ int cnt[N_NODES];
    int tid = threadIdx.x;
    if (tid < N_NODES) cnt[tid] = 0;
    __syncthreads();
    if (tid < E_TOT) {
      int s, d;
      if (tid < E_BASE) { s = ei[tid]; d = ei[B_GRAPH * E_BASE + tid]; }
      else              { s = tid - E_BASE; d = s; }
      meta[META_SRC + tid] = s;
      meta[META_DST + tid] = d;
      int pos = atomicAdd(&cnt[d], 1);
      if (pos < MAXIN) meta[META_LIST + d * MAXIN + pos] = (tid << 8) | s;  // packed
    }
    __syncthreads();
    if (tid < N_NODES) meta[META_CNT + tid] = cnt[tid];
    return;
  }
  int ji = 0;
  #pragma unroll
  for (int i = 1; i < 10; i++) if (b >= args.j[i].tstart) ji = i;
  WtJob jb = args.j[ji];
  int t = b - jb.tstart;
  int ntn = jb.N >> 5;
  int tk = t / ntn, tn = t - tk * ntn;
  int k0 = tk * 32, n0 = tn * 32;
  __shared__ float s[32][33];
  int tx = threadIdx.x & 31, ty = threadIdx.x >> 5;
  #pragma unroll
  for (int p = 0; p < 4; p++)
    s[ty + p * 8][tx] = jb.in[(size_t)(k0 + ty + p * 8) * jb.N + n0 + tx];
  __syncthreads();
  __hip_bfloat16* o = out + jb.ooff;
  #pragma unroll
  for (int p = 0; p < 4; p++) {
    int n = ty + p * 8;
    o[(size_t)(n0 + n) * jb.K + k0 + tx] = __float2bfloat16(s[tx][n]);
  }
}

// ---------------------------------------------------------------------------
// R20/R21 gemm_gat: layer GEMM with IN-KERNEL edge logits; xr never hits HBM.
// R9 counters (VALU 47->34% but dur 90->86.8) proved the tail is latency/
// barrier-bound — structure frozen per the m97-ceiling lesson. R21: the
// cooperative global store is moved AFTER the logit pass (stores are
// fire-and-forget; the LDS-bound logit pass starts sooner).
//
// Block (bm, bn): bn = h*4+cg covers head h, channel-group cg (64 ch).
//   cols 0-63  = xl channels (Wl rows), cols 64-127 = xr channels (Wr rows)
// M-tile = 120 rows = 4 WHOLE graphs (+8 pad rows, outputs discarded) so every
// edge's src/dst rows are in-block. atomicAdd partials into zeroed logitsG.
// bf16 rounding points identical to the R0 path (logits read back bf16 values).
// ---------------------------------------------------------------------------
#define XP 132   // padded xlr row stride (shorts)
__global__ __launch_bounds__(256)
void gemm_gat(const __hip_bfloat16* __restrict__ A,      // hnb [NTOT][256]
              const __hip_bfloat16* __restrict__ Wl,     // [H*256][256] bf16 (transposed)
              const __hip_bfloat16* __restrict__ Wr,
              const float* __restrict__ blv, const float* __restrict__ brv,
              const float* __restrict__ att,             // [H][256]
              __hip_bfloat16* __restrict__ xlcat,        // [NTOT][H*256]
              float* __restrict__ logitsG,               // [B][H][E_TOT], pre-zeroed
              const int* __restrict__ meta, int H)
{
  union GatSmem {
    struct { short a[2][4096]; short b[2][4096]; } st;   // 32 KB staging
    short xlr[128 * XP];                                  // 33.8 KB epilogue
  };
  __shared__ GatSmem sm;
  __shared__ int ssrc[E_TOT], sdst[E_TOT];

  const int tid = threadIdx.x;
  const int lane = tid & 63, wave = tid >> 6;
  const int wx = wave & 1, wy = wave >> 1;
  const int bm = blockIdx.x, bn = blockIdx.y;
  const int mrow = lane & 15, quad = lane >> 4;
  const int hh = bn >> 2, cg = bn & 3;
  const int K = HID;

  if (tid < E_TOT) { ssrc[tid] = meta[META_SRC + tid]; sdst[tid] = meta[META_DST + tid]; }

  const int r0 = tid >> 2, kc0 = (tid & 3) * 8;
  const int Ra = bm * 120 + r0;                              // rows 0..63: real
  const int Rb = bm * 120 + (r0 + 64 > 119 ? 119 : r0 + 64); // clamp pad rows
  const __hip_bfloat16* Ag0 = A + (size_t)Ra * K + kc0;
  const __hip_bfloat16* Ag1 = A + (size_t)Rb * K + kc0;
  const int brow = hh * 256 + cg * 64 + r0;                  // r0 in 0..63
  const __hip_bfloat16* Bg0 = Wl + (size_t)brow * K + kc0;   // cols 0-63  = xl
  const __hip_bfloat16* Bg1 = Wr + (size_t)brow * K + kc0;   // cols 64-127= xr

  f32x4 acc[4][4];
  #pragma unroll
  for (int i = 0; i < 4; i++)
    #pragma unroll
    for (int j = 0; j < 4; j++)
      acc[i][j] = (f32x4){0.f, 0.f, 0.f, 0.f};

  for (int kt = 0; kt < K; kt += 64) {
    __syncthreads();
    #pragma unroll
    for (int s = 0; s < 2; s++) {
      gload_lds16(Ag0 + kt + s * 32, &sm.st.a[s][tid * 8]);
      gload_lds16(Ag1 + kt + s * 32, &sm.st.a[s][2048 + tid * 8]);
      gload_lds16(Bg0 + kt + s * 32, &sm.st.b[s][tid * 8]);
      gload_lds16(Bg1 + kt + s * 32, &sm.st.b[s][2048 + tid * 8]);
    }
    __syncthreads();

    #pragma unroll
    for (int s = 0; s < 2; s++) {
      bf16x8 af[4], bfr[4];
      #pragma unroll
      for (int i = 0; i < 4; i++) {
        af[i]  = *(const bf16x8*)&sm.st.a[s][(wy * 64 + i * 16 + mrow) * 32 + quad * 8];
        bfr[i] = *(const bf16x8*)&sm.st.b[s][(wx * 64 + i * 16 + mrow) * 32 + quad * 8];
      }
      #pragma unroll
      for (int i = 0; i < 4; i++)
        #pragma unroll
        for (int j = 0; j < 4; j++)
          acc[i][j] = __builtin_amdgcn_mfma_f32_16x16x32_bf16(bfr[j], af[i], acc[i][j], 0, 0, 0);
    }
  }

  __syncthreads();   // K-loop LDS reads done; safe to repurpose union as xlr

  // ---- epilogue (transposed fragment): bias + bf16 -> LDS, 16x ds_write_b64.
  // acc[i][j][r] = C[row = wy*64+i*16+mrow][col = wx*64+j*16+quad*4+r]
  const float* bb = wx ? brv : blv;
  #pragma unroll
  for (int i = 0; i < 4; i++) {
    int lrow = wy * 64 + i * 16 + mrow;
    #pragma unroll
    for (int j = 0; j < 4; j++) {
      int c0 = j * 16 + quad * 4;               // 0..63 within half
      float4 bc = *(const float4*)&bb[hh * 256 + cg * 64 + c0];
      short t[4];
      t[0] = f2bf_bits(acc[i][j][0] + bc.x);
      t[1] = f2bf_bits(acc[i][j][1] + bc.y);
      t[2] = f2bf_bits(acc[i][j][2] + bc.z);
      t[3] = f2bf_bits(acc[i][j][3] + bc.w);
      *(bf16x4*)&sm.xlr[lrow * XP + wx * 64 + c0] = *(bf16x4*)t;
    }
  }
  __syncthreads();

  // ---- logit partials: 8 lanes/edge x 8 ch; graph-outer, no division.
  const int slot = tid >> 3, esub = tid & 7;   // 32 edge-slots, 8 lanes/edge
  float av[8];
  #pragma unroll
  for (int i = 0; i < 8; i++) av[i] = att[hh * HID + cg * 64 + esub * 8 + i];
  #pragma unroll
  for (int gl = 0; gl < 4; gl++) {
    #pragma unroll
    for (int p = 0; p < 4; p++) {
      int e = p * 32 + slot;
      if (e < E_TOT) {
        int rs = gl * 30 + ssrc[e], rd = gl * 30 + sdst[e];
        bf16x8 xlv = *(const bf16x8*)&sm.xlr[rs * XP + esub * 8];
        bf16x8 xrv = *(const bf16x8*)&sm.xlr[rd * XP + 64 + esub * 8];
        float sum = 0.f;
        #pragma unroll
        for (int i = 0; i < 8; i++) {
          float z = b2f(xlv[i]) + b2f(xrv[i]);
          z = fmaxf(z, 0.2f * z);               // == lrelu(z,0.2), 2 inst
          sum = fmaf(z, av[i], sum);
        }
        sum += __shfl_xor(sum, 1);
        sum += __shfl_xor(sum, 2);
        sum += __shfl_xor(sum, 4);
        if (esub == 0)
          atomicAdd(&logitsG[((size_t)(bm * 4 + gl) * H + hh) * E_TOT + e], sum);
      }
    }
  }

  // ---- cooperative vectorized store of the xl half (120 rows x 64 ch) ----
  // (after the logit pass — fire-and-forget stores, R21)
  {
    const size_t SROW = (size_t)H * HID;
    #pragma unroll
    for (int p = 0; p < 4; p++) {
      int c = tid + p * 256;
      if (c < 960) {
        int row = c >> 3, part = c & 7;
        bf16x8 v = *(const bf16x8*)&sm.xlr[row * XP + part * 8];
        *(bf16x8*)&((short*)xlcat)[((size_t)bm * 120 + row) * SROW
                                   + hh * HID + cg * 64 + part * 8] = v;
      }
    }
  }
}

// ---------------------------------------------------------------------------
// MFMA GEMM with fp32 A staged via in-register bf16 cast (fused cast): proj.
// (EXACT R0 version.)
// ---------------------------------------------------------------------------
template<int ACT, int OUTBF>
__global__ __launch_bounds__(256)
void gemm_mfma_f32a(const float* __restrict__ A, const __hip_bfloat16* __restrict__ Bt,
                    const float* __restrict__ bias, void* __restrict__ Cv,
                    int M, int K, int N)
{
  __shared__ __hip_bfloat16 sA[128 * 32];
  __shared__ __hip_bfloat16 sB[128 * 32];
  const int tid = threadIdx.x;
  const int lane = tid & 63;
  const int wave = tid >> 6;
  const int wx = wave & 1, wy = wave >> 1;
  const int bm = blockIdx.x, bn = blockIdx.y;
  const int mrow = lane & 15, quad = lane >> 4;

  const int r0 = tid >> 2, kc0 = (tid & 3) * 8;
  const float* Ag0 = A + (size_t)(bm * 128 + r0) * K + kc0;
  const float* Ag1 = A + (size_t)(bm * 128 + r0 + 64) * K + kc0;
  const __hip_bfloat16* Bg0 = Bt + (size_t)(bn * 128 + r0) * K + kc0;
  const __hip_bfloat16* Bg1 = Bt + (size_t)(bn * 128 + r0 + 64) * K + kc0;

  f32x4 acc[4][4];
  #pragma unroll
  for (int i = 0; i < 4; i++)
    #pragma unroll
    for (int j = 0; j < 4; j++)
      acc[i][j] = (f32x4){0.f, 0.f, 0.f, 0.f};

  for (int kt = 0; kt < K; kt += 32) {
    float4 a00 = *(const float4*)(Ag0 + kt);
    float4 a01 = *(const float4*)(Ag0 + kt + 4);
    float4 a10 = *(const float4*)(Ag1 + kt);
    float4 a11 = *(const float4*)(Ag1 + kt + 4);
    __syncthreads();
    {
      __hip_bfloat16 t[8];
      t[0] = __float2bfloat16(a00.x); t[1] = __float2bfloat16(a00.y);
      t[2] = __float2bfloat16(a00.z); t[3] = __float2bfloat16(a00.w);
      t[4] = __float2bfloat16(a01.x); t[5] = __float2bfloat16(a01.y);
      t[6] = __float2bfloat16(a01.z); t[7] = __float2bfloat16(a01.w);
      *(bf16x8*)&sA[tid * 8] = *(bf16x8*)t;
      t[0] = __float2bfloat16(a10.x); t[1] = __float2bfloat16(a10.y);
      t[2] = __float2bfloat16(a10.z); t[3] = __float2bfloat16(a10.w);
      t[4] = __float2bfloat16(a11.x); t[5] = __float2bfloat16(a11.y);
      t[6] = __float2bfloat16(a11.z); t[7] = __float2bfloat16(a11.w);
      *(bf16x8*)&sA[2048 + tid * 8] = *(bf16x8*)t;
    }
    gload_lds16(Bg0 + kt, &sB[tid * 8]);
    gload_lds16(Bg1 + kt, &sB[2048 + tid * 8]);
    __syncthreads();

    bf16x8 af[4], bfr[4];
    #pragma unroll
    for (int i = 0; i < 4; i++) {
      af[i]  = *(const bf16x8*)&sA[(wy * 64 + i * 16 + mrow) * 32 + quad * 8];
      bfr[i] = *(const bf16x8*)&sB[(wx * 64 + i * 16 + mrow) * 32 + quad * 8];
    }
    #pragma unroll
    for (int i = 0; i < 4; i++)
      #pragma unroll
      for (int j = 0; j < 4; j++)
        acc[i][j] = __builtin_amdgcn_mfma_f32_16x16x32_bf16(af[i], bfr[j], acc[i][j], 0, 0, 0);
  }

  #pragma unroll
  for (int i = 0; i < 4; i++) {
    #pragma unroll
    for (int r = 0; r < 4; r++) {
      size_t row = (size_t)bm * 128 + wy * 64 + i * 16 + quad * 4 + r;
      #pragma unroll
      for (int j = 0; j < 4; j++) {
        int col = bn * 128 + wx * 64 + j * 16 + mrow;
        float v = acc[i][j][r] + bias[col];
        if (ACT) v = v > 0.f ? v : 0.01f * v;
        if (OUTBF) ((__hip_bfloat16*)Cv)[row * N + col] = __float2bfloat16(v);
        else       ((float*)Cv)[row * N + col] = v;
      }
    }
  }
}

// ---------------------------------------------------------------------------
// R20 gemm_mfma_pair: fused edge-pair gather GEMM, A read from the bf16 h copy
// (hb, written by gat_agg l=2 with identical __float2bfloat16 rounding).
// A staged by DIRECT per-lane global_load_lds.
// A-row r = concat(hb[b,u], hb[b,v]) with b=r/41, (u,v)=pairs[r%41]; K=512.
// C = lrelu(A @ Bt + bias), bf16 out.
// ---------------------------------------------------------------------------
__global__ __launch_bounds__(256)
void gemm_mfma_pair(const __hip_bfloat16* __restrict__ hb, const int* __restrict__ pairs,
                    const __hip_bfloat16* __restrict__ Bt, const float* __restrict__ bias,
                    __hip_bfloat16* __restrict__ C, int N)
{
  const int K = 512;
  __shared__ __hip_bfloat16 sA[128 * 32];
  __shared__ __hip_bfloat16 sB[128 * 32];
  const int tid = threadIdx.x;
  const int lane = tid & 63;
  const int wave = tid >> 6;
  const int wx = wave & 1, wy = wave >> 1;
  const int bm = blockIdx.x, bn = blockIdx.y;
  const int mrow = lane & 15, quad = lane >> 4;

  const __hip_bfloat16* pu[2]; const __hip_bfloat16* pv[2]; int sub[2];
  #pragma unroll
  for (int cI = 0; cI < 2; cI++) {
    int c = tid + cI * 256;
    int rc = c >> 2; sub[cI] = (c & 3) * 8;        // 8-ch (16B) sub-chunk
    int R = bm * 128 + rc;
    int b = R / N_EH, p = R - b * N_EH;
    int u = pairs[p * 2], v = pairs[p * 2 + 1];
    pu[cI] = hb + ((size_t)b * N_NODES + u) * HID;
    pv[cI] = hb + ((size_t)b * N_NODES + v) * HID;
  }

  const int r0 = tid >> 2, kc0 = (tid & 3) * 8;
  const __hip_bfloat16* Bg0 = Bt + (size_t)(bn * 128 + r0) * K + kc0;
  const __hip_bfloat16* Bg1 = Bt + (size_t)(bn * 128 + r0 + 64) * K + kc0;

  f32x4 acc[4][4];
  #pragma unroll
  for (int i = 0; i < 4; i++)
    #pragma unroll
    for (int j = 0; j < 4; j++)
      acc[i][j] = (f32x4){0.f, 0.f, 0.f, 0.f};

  for (int kt = 0; kt < K; kt += 32) {
    __syncthreads();
    #pragma unroll
    for (int cI = 0; cI < 2; cI++) {
      const __hip_bfloat16* src = (kt < 256 ? pu[cI] + kt : pv[cI] + kt - 256) + sub[cI];
      gload_lds16(src, &sA[(size_t)(tid + cI * 256) * 8]);
    }
    gload_lds16(Bg0 + kt, &sB[tid * 8]);
    gload_lds16(Bg1 + kt, &sB[2048 + tid * 8]);
    __syncthreads();

    bf16x8 af[4], bfr[4];
    #pragma unroll
    for (int i = 0; i < 4; i++) {
      af[i]  = *(const bf16x8*)&sA[(wy * 64 + i * 16 + mrow) * 32 + quad * 8];
      bfr[i] = *(const bf16x8*)&sB[(wx * 64 + i * 16 + mrow) * 32 + quad * 8];
    }
    #pragma unroll
    for (int i = 0; i < 4; i++)
      #pragma unroll
      for (int j = 0; j < 4; j++)
        acc[i][j] = __builtin_amdgcn_mfma_f32_16x16x32_bf16(af[i], bfr[j], acc[i][j], 0, 0, 0);
  }

  #pragma unroll
  for (int i = 0; i < 4; i++) {
    #pragma unroll
    for (int r = 0; r < 4; r++) {
      size_t row = (size_t)bm * 128 + wy * 64 + i * 16 + quad * 4 + r;
      #pragma unroll
      for (int j = 0; j < 4; j++) {
        int col = bn * 128 + wx * 64 + j * 16 + mrow;
        float v = acc[i][j][r] + bias[col];
        v = v > 0.f ? v : 0.01f * v;
        C[row * N + col] = __float2bfloat16(v);
      }
    }
  }
}

// ---------------------------------------------------------------------------
// Fused MLP tail (R11 — proven win; EXACT R0 version).
// ---------------------------------------------------------------------------
#define O2P 136
__global__ __launch_bounds__(256)
void mlp_tail(const __hip_bfloat16* __restrict__ o1, const __hip_bfloat16* __restrict__ W1t,
              const float* __restrict__ b1, const __hip_bfloat16* __restrict__ W2t,
              const float* __restrict__ b2, const float* __restrict__ w3,
              const float* __restrict__ b3, float* __restrict__ out)
{
  __shared__ __hip_bfloat16 sA[128 * 32];
  __shared__ __hip_bfloat16 sB[128 * 32];
  __shared__ __hip_bfloat16 sO2[128 * O2P];
  __shared__ float spart[2][128];
  const int tid = threadIdx.x;
  const int lane = tid & 63;
  const int wave = tid >> 6;
  const int wx = wave & 1, wy = wave >> 1;
  const int bm = blockIdx.x;
  const int mrow = lane & 15, quad = lane >> 4;
  const int r0 = tid >> 2, kc0 = (tid & 3) * 8;

  const __hip_bfloat16* Ag0 = o1 + (size_t)(bm * 128 + r0) * 256 + kc0;
  const __hip_bfloat16* Ag1 = o1 + (size_t)(bm * 128 + r0 + 64) * 256 + kc0;
  const __hip_bfloat16* Bg0 = W1t + (size_t)r0 * 256 + kc0;
  const __hip_bfloat16* Bg1 = W1t + (size_t)(r0 + 64) * 256 + kc0;

  f32x4 acc[4][4];
  #pragma unroll
  for (int i = 0; i < 4; i++)
    #pragma unroll
    for (int j = 0; j < 4; j++)
      acc[i][j] = (f32x4){0.f, 0.f, 0.f, 0.f};

  for (int kt = 0; kt < 256; kt += 32) {
    __syncthreads();
    gload_lds16(Ag0 + kt, &sA[tid * 8]);
    gload_lds16(Ag1 + kt, &sA[2048 + tid * 8]);
    gload_lds16(Bg0 + kt, &sB[tid * 8]);
    gload_lds16(Bg1 + kt, &sB[2048 + tid * 8]);
    __syncthreads();

    bf16x8 af[4], bfr[4];
    #pragma unroll
    for (int i = 0; i < 4; i++) {
      af[i]  = *(const bf16x8*)&sA[(wy * 64 + i * 16 + mrow) * 32 + quad * 8];
      bfr[i] = *(const bf16x8*)&sB[(wx * 64 + i * 16 + mrow) * 32 + quad * 8];
    }
    #pragma unroll
    for (int i = 0; i < 4; i++)
      #pragma unroll
      for (int j = 0; j < 4; j++)
        acc[i][j] = __builtin_amdgcn_mfma_f32_16x16x32_bf16(af[i], bfr[j], acc[i][j], 0, 0, 0);
  }

  __syncthreads();
  #pragma unroll
  for (int i = 0; i < 4; i++) {
    #pragma unroll
    for (int r = 0; r < 4; r++) {
      int row = wy * 64 + i * 16 + quad * 4 + r;
      #pragma unroll
      for (int j = 0; j < 4; j++) {
        int col = wx * 64 + j * 16 + mrow;
        float v = acc[i][j][r] + b1[col];
        v = v > 0.f ? v : 0.01f * v;
        sO2[row * O2P + col] = __float2bfloat16(v);
      }
    }
  }

  f32x4 acc2[4][4];
  #pragma unroll
  for (int i = 0; i < 4; i++)
    #pragma unroll
    for (int j = 0; j < 4; j++)
      acc2[i][j] = (f32x4){0.f, 0.f, 0.f, 0.f};

  for (int kt = 0; kt < 128; kt += 32) {
    __syncthreads();
    gload_lds16(W2t + (size_t)r0 * 128 + kt + kc0, &sB[tid * 8]);
    gload_lds16(W2t + (size_t)(r0 + 64) * 128 + kt + kc0, &sB[2048 + tid * 8]);
    __syncthreads();

    bf16x8 af[4], bfr[4];
    #pragma unroll
    for (int i = 0; i < 4; i++) {
      af[i]  = *(const bf16x8*)&sO2[(wy * 64 + i * 16 + mrow) * O2P + kt + quad * 8];
      bfr[i] = *(const bf16x8*)&sB[(wx * 64 + i * 16 + mrow) * 32 + quad * 8];
    }
    #pragma unroll
    for (int i = 0; i < 4; i++)
      #pragma unroll
      for (int j = 0; j < 4; j++)
        acc2[i][j] = __builtin_amdgcn_mfma_f32_16x16x32_bf16(af[i], bfr[j], acc2[i][j], 0, 0, 0);
  }

  float w3v[4], b2v[4];
  #pragma unroll
  for (int j = 0; j < 4; j++) {
    int col = wx * 64 + j * 16 + mrow;
    w3v[j] = w3[col];
    b2v[j] = b2[col];
  }
  #pragma unroll
  for (int i = 0; i < 4; i++) {
    #pragma unroll
    for (int r = 0; r < 4; r++) {
      float s = 0.f;
      #pragma unroll
      for (int j = 0; j < 4; j++) {
        float v = acc2[i][j][r] + b2v[j];
        v = v > 0.f ? v : 0.01f * v;
        s += v * w3v[j];
      }
      #pragma unroll
      for (int off = 8; off; off >>= 1) s += __shfl_xor(s, off);
      if (mrow == 0) {
        int row = wy * 64 + i * 16 + quad * 4 + r;
        spart[wx][row] = s;
      }
    }
  }
  __syncthreads();
  if (tid < 128)
    out[(size_t)bm * 128 + tid] = spart[0][tid] + spart[1][tid] + b3[0];
}

// ---------------------------------------------------------------------------
// LayerNorm over HID=256; one wave per row; R21: float4 (16B) loads/stores —
// lane covers channels [lane*4, lane*4+4). Reduction order change is within
// fp32 rounding noise (order was already non-reference).
// ---------------------------------------------------------------------------
__global__ __launch_bounds__(256)
void layernorm(const float* __restrict__ h, const float* __restrict__ g,
               const float* __restrict__ b, __hip_bfloat16* __restrict__ hn)
{
  const int wv = threadIdx.x >> 6, lane = threadIdx.x & 63;
  const size_t row = (size_t)blockIdx.x * 4 + wv;
  const float* hr = h + row * HID;
  float4 v = *(const float4*)&hr[lane * 4];
  float sum = v.x + v.y + v.z + v.w;
  #pragma unroll
  for (int off = 32; off; off >>= 1) sum += __shfl_xor(sum, off);
  float mu = sum * (1.f / 256.f);
  float d0 = v.x - mu, d1 = v.y - mu, d2 = v.z - mu, d3 = v.w - mu;
  float vs = d0 * d0 + d1 * d1 + d2 * d2 + d3 * d3;
  #pragma unroll
  for (int off = 32; off; off >>= 1) vs += __shfl_xor(vs, off);
  float rs = rsqrtf(vs * (1.f / 256.f) + 1e-5f);
  float4 gv = *(const float4*)&g[lane * 4];
  float4 bv = *(const float4*)&b[lane * 4];
  short t[4];
  t[0] = f2bf_bits(d0 * rs * gv.x + bv.x);
  t[1] = f2bf_bits(d1 * rs * gv.y + bv.y);
  t[2] = f2bf_bits(d2 * rs * gv.z + bv.z);
  t[3] = f2bf_bits(d3 * rs * gv.w + bv.w);
  *(bf16x4*)&hn[row * HID + lane * 4] = *(bf16x4*)t;
}

// ---------------------------------------------------------------------------
// R21 gat_agg: aggregation + h update with CONCURRENT all-head softmax (3
// barriers instead of 3*H — logits padded to [hh*128+e] so all H*112 entries
// process in one 256-thread sweep; per-(head,node) max as tid=(hh<<5)|node).
// Agg inner loop uses the PACKED slist ((e<<8)|src): the 3-level LDS chain
// lst->ssrc->sxl becomes 2-level lst->{salpha, sxl}. ssrc staging removed.
// For DO_LN==0 (last layer) writes a bf16 copy of the final h to hn (=hnb)
// for gemm_mfma_pair's gather. xcat is xl-only: row stride S = H*HID.
// One block per graph; thread = (channel-quad c4, node-group ng).
// ---------------------------------------------------------------------------
template<int DO_LN>
__global__ __launch_bounds__(256, 4)
void gat_agg(const __hip_bfloat16* __restrict__ xcat, const float* __restrict__ logitsG,
             const float* __restrict__ bias, float* __restrict__ h,
             const float* __restrict__ lnG, const float* __restrict__ lnB,
             __hip_bfloat16* __restrict__ hn, const int* __restrict__ meta, int H)
{
  __shared__ __hip_bfloat16 sxl[2][N_NODES * HID];   // 2 x 15 KB, head double-buffer
  __shared__ float slogA[3 * 128], salphaA[3 * 128]; // [hh*128 + e]
  __shared__ float smaxA[3 * 32], sdenA[3 * 32];     // [hh*32 + node]
  __shared__ int sdst[E_TOT], scnt[N_NODES], slist[N_NODES * MAXIN];

  const int tid = threadIdx.x;
  const int g = blockIdx.x;
  const size_t nodebase = (size_t)g * N_NODES;
  const int S = H * HID;                    // xl-only stride
  const int c4 = tid & 63;
  const int ng = tid >> 6;

  if (tid < E_TOT) sdst[tid] = meta[META_DST + tid];
  if (tid < N_NODES) scnt[tid] = meta[META_CNT + tid];
  for (int i = tid; i < N_NODES * MAXIN; i += 256) slist[i] = meta[META_LIST + i];

  float4 hres[8];
  #pragma unroll
  for (int ki = 0; ki < 8; ki++) {
    int k = ng + ki * 4;
    if (k < N_NODES) hres[ki] = *(const float4*)&h[(nodebase + k) * HID + c4 * 4];
  }

  // issue stage of head 0's xl (async; overlaps with the softmax below)
  {
    int i = tid;
    #pragma unroll
    for (int p = 0; p < 4; p++, i += 256) {
      if (i < N_NODES * HID / 8) {
        int node = i >> 5, c = (i & 31) * 8;
        gload_lds16(&xcat[(nodebase + node) * S + 0 * HID + c], &sxl[0][(size_t)i * 8]);
      }
    }
  }

  // ---- concurrent all-head softmax (3 barriers total) ----
  for (int i = tid; i < H * 128; i += 256) {
    int hh = i >> 7, e = i & 127;
    if (e < E_TOT) slogA[i] = logitsG[((size_t)g * H + hh) * E_TOT + e];
  }
  if (tid < H * 32) sdenA[tid] = 0.f;
  __syncthreads();
  {
    int hh = tid >> 5, node = tid & 31;
    if (hh < H && node < N_NODES) {
      int cnt = scnt[node];
      const int* lst = &slist[node * MAXIN];
      float m = -1e30f;
      for (int i = 0; i < cnt; i++) m = fmaxf(m, slogA[(hh << 7) + (lst[i] >> 8)]);
      smaxA[tid] = m;
    }
  }
  __syncthreads();
  for (int i = tid; i < H * 128; i += 256) {
    int hh = i >> 7, e = i & 127;
    if (e < E_TOT) {
      float ex = expf(slogA[i] - smaxA[(hh << 5) + sdst[e]]);
      slogA[i] = ex;
      atomicAdd(&sdenA[(hh << 5) + sdst[e]], ex);
    }
  }
  __syncthreads();
  for (int i = tid; i < H * 128; i += 256) {
    int hh = i >> 7, e = i & 127;
    if (e < E_TOT) salphaA[i] = slogA[i] / sdenA[(hh << 5) + sdst[e]];
  }
  // first agg loop-head barrier covers salphaA visibility + xl[0] drain

  float acc[8][4];
  #pragma unroll
  for (int ki = 0; ki < 8; ki++)
    #pragma unroll
    for (int j = 0; j < 4; j++) acc[ki][j] = 0.f;

  for (int hh = 0; hh < H; hh++) {
    const int buf = hh & 1;
    __syncthreads();   // staged loads drained; salphaA ready (first iter)
    if (hh + 1 < H) {
      const int nb = buf ^ 1;
      int i = tid;
      #pragma unroll
      for (int p = 0; p < 4; p++, i += 256) {
        if (i < N_NODES * HID / 8) {
          int node = i >> 5, c = (i & 31) * 8;
          gload_lds16(&xcat[(nodebase + node) * S + (hh + 1) * HID + c], &sxl[nb][(size_t)i * 8]);
        }
      }
    }
    #pragma unroll
    for (int ki = 0; ki < 8; ki++) {
      int k = ng + ki * 4;
      if (k < N_NODES) {
        int cnt = scnt[k];
        const int* lst = &slist[k * MAXIN];
        for (int i = 0; i < cnt; i++) {
          int pk = lst[i];                      // packed (e<<8)|src, wave-uniform
          float al = salphaA[(hh << 7) + (pk >> 8)];
          bf16x4 v = *(const bf16x4*)&sxl[buf][(pk & 255) * HID + c4 * 4];
          acc[ki][0] += al * b2f(v[0]);
          acc[ki][1] += al * b2f(v[1]);
          acc[ki][2] += al * b2f(v[2]);
          acc[ki][3] += al * b2f(v[3]);
        }
      }
    }
  }

  const float invH = 1.f / (float)H;
  const float4 bs = *(const float4*)&bias[c4 * 4];
  float4 gv, bv;
  if (DO_LN) {
    gv = *(const float4*)&lnG[c4 * 4];
    bv = *(const float4*)&lnB[c4 * 4];
  }
  #pragma unroll
  for (int ki = 0; ki < 8; ki++) {
    int k = ng + ki * 4;
    if (k < N_NODES) {
      float o0 = acc[ki][0] * invH + bs.x; o0 = o0 > 0.f ? o0 : 0.01f * o0; o0 += hres[ki].x;
      float o1 = acc[ki][1] * invH + bs.y; o1 = o1 > 0.f ? o1 : 0.01f * o1; o1 += hres[ki].y;
      float o2 = acc[ki][2] * invH + bs.z; o2 = o2 > 0.f ? o2 : 0.01f * o2; o2 += hres[ki].z;
      float o3 = acc[ki][3] * invH + bs.w; o3 = o3 > 0.f ? o3 : 0.01f * o3; o3 += hres[ki].w;
      float4 o4 = {o0, o1, o2, o3};
      *(float4*)&h[(nodebase + k) * HID + c4 * 4] = o4;
      if (DO_LN) {
        float sum = o0 + o1 + o2 + o3;
        #pragma unroll
        for (int off = 32; off; off >>= 1) sum += __shfl_xor(sum, off);
        float mu = sum * (1.f / 256.f);
        float d0 = o0 - mu, d1 = o1 - mu, d2 = o2 - mu, d3 = o3 - mu;
        float vs = d0 * d0 + d1 * d1 + d2 * d2 + d3 * d3;
        #pragma unroll
        for (int off = 32; off; off >>= 1) vs += __shfl_xor(vs, off);
        float rs = rsqrtf(vs * (1.f / 256.f) + 1e-5f);
        __hip_bfloat16 t[4];
        t[0] = __float2bfloat16(d0 * rs * gv.x + bv.x);
        t[1] = __float2bfloat16(d1 * rs * gv.y + bv.y);
        t[2] = __float2bfloat16(d2 * rs * gv.z + bv.z);
        t[3] = __float2bfloat16(d3 * rs * gv.w + bv.w);
        *(bf16x4*)&hn[(nodebase + k) * HID + c4 * 4] = *(bf16x4*)t;
      } else {
        // bf16 copy of final h for the pair-GEMM gather (R20)
        short t[4];
        t[0] = f2bf_bits(o0); t[1] = f2bf_bits(o1);
        t[2] = f2bf_bits(o2); t[3] = f2bf_bits(o3);
        *(bf16x4*)&hn[(nodebase + k) * HID + c4 * 4] = *(bf16x4*)t;
      }
    }
  }
}

// ---------------------------------------------------------------------------
extern "C" void kernel_launch(void* const* d_in, const int* in_sizes, int n_in,
                              void* d_out, int out_size, void* d_ws, size_t ws_size,
                              hipStream_t stream) {
  const float* x     = (const float*)d_in[0];
  const int*   ei    = (const int*)d_in[1];
  const int*   pairs = (const int*)d_in[2];
  const float* bp    = (const float*)d_in[4];
  const float *lng[3], *lnb[3], *bl[3], *br[3], *att[3], *bias[3];
  const float *WlF[3], *WrF[3];
  for (int l = 0; l < 3; l++) {
    int base = 5 + l * 8;
    lng[l]  = (const float*)d_in[base + 0];
    lnb[l]  = (const float*)d_in[base + 1];
    WlF[l]  = (const float*)d_in[base + 2];
    bl[l]   = (const float*)d_in[base + 3];
    WrF[l]  = (const float*)d_in[base + 4];
    br[l]   = (const float*)d_in[base + 5];
    att[l]  = (const float*)d_in[base + 6];
    bias[l] = (const float*)d_in[base + 7];
  }
  const float* WmF[4] = {(const float*)d_in[29], (const float*)d_in[31],
                         (const float*)d_in[33], (const float*)d_in[35]};
  const float* bm[4] = {(const float*)d_in[30], (const float*)d_in[32],
                        (const float*)d_in[34], (const float*)d_in[36]};

  // workspace layout (float offsets)
  float* ws  = (float*)d_ws;
  float* h   = ws;                                           // [0, 7864320)
  __hip_bfloat16* hnb = (__hip_bfloat16*)(ws + 7864320);     // 3,932,160 bf
  __hip_bfloat16* xlcat = (__hip_bfloat16*)(ws + 11796480);  // xl-only: <= 23,592,960 bf
  float* logits0 = ws + 30000000;                            // 344,064 f (l=0)
  float* logits1 = logits0 + 344064;                         // 229,376 f (l=1)
  float* logits2 = logits1 + 229376;                         // 114,688 f (l=2)
  __hip_bfloat16* wbuf = (__hip_bfloat16*)(ws + 35733504);   // 999,424 bf
  int*   meta = (int*)(ws + 36233216);
  __hip_bfloat16* o1b = (__hip_bfloat16*)xlcat;              // pair out (xlcat dead then)
  float* out = (float*)d_out;

  // bf16 transposed weight offsets (layouts unchanged from R0)
  const int oWp = 0, oWl0 = 32768, oWr0 = 229376, oWl1 = 425984, oWr1 = 557056;
  const int oWl2 = 688128, oWr2 = 753664, oWm0 = 819200, oWm1 = 950272, oWm2 = 983040;

  WtArgs wa;
  wa.j[0] = {(const float*)d_in[3], 128, 256,   0, oWp };
  wa.j[1] = {WlF[0],              256, 768,  32, oWl0};
  wa.j[2] = {WrF[0],              256, 768, 224, oWr0};
  wa.j[3] = {WlF[1],              256, 512, 416, oWl1};
  wa.j[4] = {WrF[1],              256, 512, 544, oWr1};
  wa.j[5] = {WlF[2],              256, 256, 672, oWl2};
  wa.j[6] = {WrF[2],              256, 256, 736, oWr2};
  wa.j[7] = {WmF[0],              512, 256, 800, oWm0};
  wa.j[8] = {WmF[1],              256, 128, 928, oWm1};
  wa.j[9] = {WmF[2],              128, 128, 960, oWm2};
  // blocks 0-975: transpose jobs; 976: build_graph; 977-1144: zero logits
  transpose_weights<<<1145, 256, 0, stream>>>(wa, wbuf, ei, meta, logits0);

  // h = x @ Wp + bp   (fp32 A staged with fused bf16 cast; fp32 out)
  gemm_mfma_f32a<0, 0><<<dim3(NTOT / 128, 2), 256, 0, stream>>>(x, wbuf + oWp, bp, h,
                                                                NTOT, 128, 256);

  layernorm<<<NTOT / 4, 256, 0, stream>>>(h, lng[0], lnb[0], hnb);

  const int Hs[3] = {3, 2, 1};
  const int oWl[3] = {oWl0, oWl1, oWl2};
  const int oWr[3] = {oWr0, oWr1, oWr2};
  float* logitsL[3] = {logits0, logits1, logits2};
  for (int l = 0; l < 3; l++) {
    int H = Hs[l];
    gemm_gat<<<dim3(NTOT / 120, H * 4), 256, 0, stream>>>(
        hnb, wbuf + oWl[l], wbuf + oWr[l], bl[l], br[l], att[l],
        xlcat, logitsL[l], meta, H);
    if (l < 2)
      gat_agg<1><<<B_GRAPH, 256, 0, stream>>>(xlcat, logitsL[l], bias[l], h,
                                              lng[l + 1], lnb[l + 1], hnb, meta, H);
    else
      gat_agg<0><<<B_GRAPH, 256, 0, stream>>>(xlcat, logitsL[l], bias[l], h,
                                              nullptr, nullptr, hnb, meta, H);
  }

  // pair-GEMM reads the bf16 h copy (hnb) written by gat_agg l=2
  gemm_mfma_pair<<<dim3(M_MLP / 128, 2), 256, 0, stream>>>(hnb, pairs, wbuf + oWm0, bm[0], o1b, 256);
  mlp_tail<<<M_MLP / 128, 256, 0, stream>>>(o1b, wbuf + oWm1, bm[1], wbuf + oWm2, bm[2],
                                            WmF[3], bm[3], out);
}